// Round 1
// baseline (4098.301 us; speedup 1.0000x reference)
//
#include <hip/hip_runtime.h>
#include <hip/hip_bf16.h>

// Problem constants (from reference): B=2, S=2048, D_IN=1024, D_OUT=1024, H=16, Dh=64
#define B 2
#define S 2048
#define DIN 1024
#define DOUT 1024
#define NH 16
#define DH 64
#define M_TOT (B * S)   // 4096

// ---------------------------------------------------------------------------
// Projection GEMM: out[b][h][s][dh] = sum_k x[b*s][k] * W[k][h*64+dh]
// Tile: 64(M) x 64(N) x 16(K), 256 threads, 4x4 acc per thread.
// BN=64 == DH, so blockIdx.y is exactly the head index.
// ---------------------------------------------------------------------------
__global__ __launch_bounds__(256) void proj_kernel(const float* __restrict__ A,
                                                   const float* __restrict__ W,
                                                   float* __restrict__ out) {
    __shared__ float As[16][68];  // transposed: As[k][m], 68 pad keeps 16B align + breaks conflicts
    __shared__ float Bs[16][68];  // Bs[k][n]

    const int tid = threadIdx.x;
    const int m0 = blockIdx.x * 64;
    const int n0 = blockIdx.y * 64;

    const int tm = tid >> 4;        // 0..15
    const int tn = tid & 15;        // 0..15

    // global-load indices
    const int la_r = tid >> 2;          // 0..63 (row within A tile)
    const int la_c = (tid & 3) << 2;    // 0,4,8,12 (k within tile)
    const int lb_r = tid >> 4;          // 0..15  (k within tile)
    const int lb_c = (tid & 15) << 2;   // 0..60  (n within tile)

    float acc[4][4];
#pragma unroll
    for (int i = 0; i < 4; ++i)
#pragma unroll
        for (int j = 0; j < 4; ++j) acc[i][j] = 0.f;

    for (int k0 = 0; k0 < DIN; k0 += 16) {
        const float4 av = *reinterpret_cast<const float4*>(&A[(size_t)(m0 + la_r) * DIN + k0 + la_c]);
        const float4 bv = *reinterpret_cast<const float4*>(&W[(size_t)(k0 + lb_r) * DOUT + n0 + lb_c]);

        __syncthreads();  // previous iteration's compute done before overwrite
        As[la_c + 0][la_r] = av.x;
        As[la_c + 1][la_r] = av.y;
        As[la_c + 2][la_r] = av.z;
        As[la_c + 3][la_r] = av.w;
        *reinterpret_cast<float4*>(&Bs[lb_r][lb_c]) = bv;
        __syncthreads();

#pragma unroll
        for (int kk = 0; kk < 16; ++kk) {
            const float4 a = *reinterpret_cast<const float4*>(&As[kk][tm << 2]);
            const float4 b = *reinterpret_cast<const float4*>(&Bs[kk][tn << 2]);
            const float aa[4] = {a.x, a.y, a.z, a.w};
            const float bb[4] = {b.x, b.y, b.z, b.w};
#pragma unroll
            for (int i = 0; i < 4; ++i)
#pragma unroll
                for (int j = 0; j < 4; ++j) acc[i][j] += aa[i] * bb[j];
        }
    }

    // Epilogue: write to [b][h][s][dh] layout. Tile rows stay within one batch
    // (m0 is a multiple of 64, batch boundary at 2048).
    const int b = m0 >> 11;            // m0 / 2048
    const int s_base = (m0 & (S - 1)) + (tm << 2);
    const int h = n0 >> 6;             // == blockIdx.y
    const int dh = tn << 2;
    float* obase = out + (((size_t)(b * NH + h)) * S) * DH;
#pragma unroll
    for (int i = 0; i < 4; ++i) {
        float4 v;
        v.x = acc[i][0]; v.y = acc[i][1]; v.z = acc[i][2]; v.w = acc[i][3];
        *reinterpret_cast<float4*>(&obase[(size_t)(s_base + i) * DH + dh]) = v;
    }
}

// ---------------------------------------------------------------------------
// Flash-style causal attention, one thread per (b,h,q) row.
// Q/K/V in [b*H+h][S][64] layout. All lanes of a wave share the same k row at
// each iteration -> broadcast L2 loads.
// ---------------------------------------------------------------------------
__global__ __launch_bounds__(256) void attn_kernel(const float* __restrict__ Q,
                                                   const float* __restrict__ K,
                                                   const float* __restrict__ V,
                                                   float* __restrict__ out) {
    const int tid = threadIdx.x;
    const int bh = blockIdx.x >> 3;                  // 0..31
    const int q  = ((blockIdx.x & 7) << 8) + tid;    // 0..2047

    const float* qp = Q + ((size_t)bh * S + q) * DH;
    float qf[DH];
#pragma unroll
    for (int d4 = 0; d4 < 16; ++d4) {
        const float4 v = *reinterpret_cast<const float4*>(&qp[d4 << 2]);
        qf[(d4 << 2) + 0] = v.x; qf[(d4 << 2) + 1] = v.y;
        qf[(d4 << 2) + 2] = v.z; qf[(d4 << 2) + 3] = v.w;
    }

    float o[DH];
#pragma unroll
    for (int d = 0; d < DH; ++d) o[d] = 0.f;
    float m = -INFINITY, l = 0.f;

    const float* kbase = K + (size_t)bh * S * DH;
    const float* vbase = V + (size_t)bh * S * DH;

    for (int k = 0; k <= q; ++k) {
        const float* kr = kbase + (size_t)k * DH;
        float s0 = 0.f, s1 = 0.f, s2 = 0.f, s3 = 0.f;
#pragma unroll
        for (int d4 = 0; d4 < 16; ++d4) {
            const float4 kv = *reinterpret_cast<const float4*>(&kr[d4 << 2]);
            s0 += qf[(d4 << 2) + 0] * kv.x;
            s1 += qf[(d4 << 2) + 1] * kv.y;
            s2 += qf[(d4 << 2) + 2] * kv.z;
            s3 += qf[(d4 << 2) + 3] * kv.w;
        }
        const float s = ((s0 + s1) + (s2 + s3)) * 0.125f;  // 1/sqrt(64)

        const float nm    = fmaxf(m, s);
        const float scale = __expf(m - nm);   // first iter: exp(-inf)=0
        const float p     = __expf(s - nm);
        l = l * scale + p;

        const float* vr = vbase + (size_t)k * DH;
#pragma unroll
        for (int d4 = 0; d4 < 16; ++d4) {
            const float4 vv = *reinterpret_cast<const float4*>(&vr[d4 << 2]);
            o[(d4 << 2) + 0] = o[(d4 << 2) + 0] * scale + p * vv.x;
            o[(d4 << 2) + 1] = o[(d4 << 2) + 1] * scale + p * vv.y;
            o[(d4 << 2) + 2] = o[(d4 << 2) + 2] * scale + p * vv.z;
            o[(d4 << 2) + 3] = o[(d4 << 2) + 3] * scale + p * vv.w;
        }
        m = nm;
    }

    const float inv = 1.f / l;
    const int b = bh >> 4, h = bh & (NH - 1);
    float* op = out + ((size_t)(b * S + q)) * DOUT + h * DH;
#pragma unroll
    for (int d4 = 0; d4 < 16; ++d4) {
        float4 v;
        v.x = o[(d4 << 2) + 0] * inv; v.y = o[(d4 << 2) + 1] * inv;
        v.z = o[(d4 << 2) + 2] * inv; v.w = o[(d4 << 2) + 3] * inv;
        *reinterpret_cast<float4*>(&op[d4 << 2]) = v;
    }
}

// ---------------------------------------------------------------------------
extern "C" void kernel_launch(void* const* d_in, const int* in_sizes, int n_in,
                              void* d_out, int out_size, void* d_ws, size_t ws_size,
                              hipStream_t stream) {
    const float* x  = (const float*)d_in[0];
    const float* Wq = (const float*)d_in[1];
    const float* Wk = (const float*)d_in[2];
    const float* Wv = (const float*)d_in[3];
    float* out = (float*)d_out;

    // workspace: Q, K, V in [B*H][S][DH] layout, 16 MiB each
    float* qws = (float*)d_ws;
    float* kws = qws + (size_t)M_TOT * DOUT;
    float* vws = kws + (size_t)M_TOT * DOUT;

    dim3 pgrid(M_TOT / 64, DOUT / 64);  // 64 x 16
    proj_kernel<<<pgrid, 256, 0, stream>>>(x, Wq, qws);
    proj_kernel<<<pgrid, 256, 0, stream>>>(x, Wk, kws);
    proj_kernel<<<pgrid, 256, 0, stream>>>(x, Wv, vws);

    attn_kernel<<<B * NH * S / 256, 256, 0, stream>>>(qws, kws, vws, out);
}

// Round 2
// 671.617 us; speedup vs baseline: 6.1021x; 6.1021x over previous
//
#include <hip/hip_runtime.h>
#include <hip/hip_bf16.h>

// Problem constants: B=2, S=2048, D_IN=1024, D_OUT=1024, H=16, Dh=64
#define B 2
#define S 2048
#define DIN 1024
#define DOUT 1024
#define NH 16
#define DH 64
#define M_TOT (B * S)   // 4096

// ---------------------------------------------------------------------------
// Projection GEMM (unchanged from round 1): 64x64x16 tile, 4x4 acc/thread.
// Writes into [b][h][s][dh] layout.
// ---------------------------------------------------------------------------
__global__ __launch_bounds__(256) void proj_kernel(const float* __restrict__ A,
                                                   const float* __restrict__ W,
                                                   float* __restrict__ out) {
    __shared__ float As[16][68];
    __shared__ float Bs[16][68];

    const int tid = threadIdx.x;
    const int m0 = blockIdx.x * 64;
    const int n0 = blockIdx.y * 64;

    const int tm = tid >> 4;
    const int tn = tid & 15;

    const int la_r = tid >> 2;
    const int la_c = (tid & 3) << 2;
    const int lb_r = tid >> 4;
    const int lb_c = (tid & 15) << 2;

    float acc[4][4];
#pragma unroll
    for (int i = 0; i < 4; ++i)
#pragma unroll
        for (int j = 0; j < 4; ++j) acc[i][j] = 0.f;

    for (int k0 = 0; k0 < DIN; k0 += 16) {
        const float4 av = *reinterpret_cast<const float4*>(&A[(size_t)(m0 + la_r) * DIN + k0 + la_c]);
        const float4 bv = *reinterpret_cast<const float4*>(&W[(size_t)(k0 + lb_r) * DOUT + n0 + lb_c]);

        __syncthreads();
        As[la_c + 0][la_r] = av.x;
        As[la_c + 1][la_r] = av.y;
        As[la_c + 2][la_r] = av.z;
        As[la_c + 3][la_r] = av.w;
        *reinterpret_cast<float4*>(&Bs[lb_r][lb_c]) = bv;
        __syncthreads();

#pragma unroll
        for (int kk = 0; kk < 16; ++kk) {
            const float4 a = *reinterpret_cast<const float4*>(&As[kk][tm << 2]);
            const float4 b = *reinterpret_cast<const float4*>(&Bs[kk][tn << 2]);
            const float aa[4] = {a.x, a.y, a.z, a.w};
            const float bb[4] = {b.x, b.y, b.z, b.w};
#pragma unroll
            for (int i = 0; i < 4; ++i)
#pragma unroll
                for (int j = 0; j < 4; ++j) acc[i][j] += aa[i] * bb[j];
        }
    }

    const int b = m0 >> 11;
    const int s_base = (m0 & (S - 1)) + (tm << 2);
    const int h = n0 >> 6;
    const int dh = tn << 2;
    float* obase = out + (((size_t)(b * NH + h)) * S) * DH;
#pragma unroll
    for (int i = 0; i < 4; ++i) {
        float4 v;
        v.x = acc[i][0]; v.y = acc[i][1]; v.z = acc[i][2]; v.w = acc[i][3];
        *reinterpret_cast<float4*>(&obase[(size_t)(s_base + i) * DH + dh]) = v;
    }
}

// ---------------------------------------------------------------------------
// Tiled flash attention (fp32 VALU).
// Block = one (b,h) x one 64-row q-tile. 256 threads as 16(q-groups) x 16.
// Per k-tile (64 rows): stage K^T and V in LDS; S=Q K^T via 4x4 register
// tiles; online softmax with 16-lane shuffle row-reduce; P staged row-major
// in LDS; PV via kc-blocked 4x4 tiles. All LDS reads <=2-way conflicts.
// ---------------------------------------------------------------------------
__global__ __launch_bounds__(256) void attn_kernel(const float* __restrict__ Q,
                                                   const float* __restrict__ K,
                                                   const float* __restrict__ V,
                                                   float* __restrict__ out) {
    __shared__ float Qs[64][68];   // Q^T: Qs[d][q]
    __shared__ float Ks[64][68];   // K^T: Ks[d][k]
    __shared__ float Vs[64][68];   // V:   Vs[k][d]
    __shared__ float Ps[64][68];   // P:   Ps[q][k] (row-major)

    const int tid = threadIdx.x;
    const int bh = blockIdx.x & 31;                // 0..31
    const int qt = 31 - (blockIdx.x >> 5);         // big q-tiles scheduled first
    const int q0 = qt << 6;

    const int tq = tid >> 4;   // 0..15 -> q rows tq*4..+3
    const int tk = tid & 15;   // 0..15 -> k cols / d cols tk*4..+3

    // cooperative staging indices: 64 rows x 64 cols, float4 granularity
    const int sr = tid >> 2;           // 0..63
    const int sc = (tid & 3) << 2;     // 0,4,8,12 (+16 per it)

    const float* qbase = Q + ((size_t)bh * S + q0) * DH;
    const float* kbase = K + (size_t)bh * S * DH;
    const float* vbase = V + (size_t)bh * S * DH;

    // stage Q transposed (once)
#pragma unroll
    for (int it = 0; it < 4; ++it) {
        const int d0 = sc + (it << 4);
        const float4 v = *reinterpret_cast<const float4*>(&qbase[(size_t)sr * DH + d0]);
        Qs[d0 + 0][sr] = v.x; Qs[d0 + 1][sr] = v.y;
        Qs[d0 + 2][sr] = v.z; Qs[d0 + 3][sr] = v.w;
    }

    float C[4][4];
#pragma unroll
    for (int i = 0; i < 4; ++i)
#pragma unroll
        for (int j = 0; j < 4; ++j) C[i][j] = 0.f;
    float m[4] = {-1e30f, -1e30f, -1e30f, -1e30f};
    float l[4] = {0.f, 0.f, 0.f, 0.f};

    for (int kt = 0; kt <= qt; ++kt) {
        const int k0 = kt << 6;

        // global loads first (latency overlaps the barrier wait)
        float4 kv[4], vv[4];
#pragma unroll
        for (int it = 0; it < 4; ++it) {
            const int d0 = sc + (it << 4);
            kv[it] = *reinterpret_cast<const float4*>(&kbase[(size_t)(k0 + sr) * DH + d0]);
            vv[it] = *reinterpret_cast<const float4*>(&vbase[(size_t)(k0 + sr) * DH + d0]);
        }
        __syncthreads();   // previous iteration's PV reads (Vs/Ps) done; Qs ready (it==0)
#pragma unroll
        for (int it = 0; it < 4; ++it) {
            const int d0 = sc + (it << 4);
            Ks[d0 + 0][sr] = kv[it].x; Ks[d0 + 1][sr] = kv[it].y;
            Ks[d0 + 2][sr] = kv[it].z; Ks[d0 + 3][sr] = kv[it].w;
            *reinterpret_cast<float4*>(&Vs[sr][d0]) = vv[it];
        }
        __syncthreads();

        // ---- S = Q K^T (4q x 4k per thread) ----
        float s[4][4];
#pragma unroll
        for (int i = 0; i < 4; ++i)
#pragma unroll
            for (int j = 0; j < 4; ++j) s[i][j] = 0.f;
#pragma unroll 16
        for (int d = 0; d < 64; ++d) {
            const float4 qf = *reinterpret_cast<const float4*>(&Qs[d][tq << 2]);
            const float4 kf = *reinterpret_cast<const float4*>(&Ks[d][tk << 2]);
            const float qa[4] = {qf.x, qf.y, qf.z, qf.w};
            const float ka[4] = {kf.x, kf.y, kf.z, kf.w};
#pragma unroll
            for (int i = 0; i < 4; ++i)
#pragma unroll
                for (int j = 0; j < 4; ++j) s[i][j] += qa[i] * ka[j];
        }

        // scale + causal mask (only the diagonal tile is partial)
        if (kt == qt) {
#pragma unroll
            for (int i = 0; i < 4; ++i) {
                const int qg = q0 + (tq << 2) + i;
#pragma unroll
                for (int j = 0; j < 4; ++j) {
                    const int kg = k0 + (tk << 2) + j;
                    s[i][j] = (kg <= qg) ? s[i][j] * 0.125f : -1e30f;
                }
            }
        } else {
#pragma unroll
            for (int i = 0; i < 4; ++i)
#pragma unroll
                for (int j = 0; j < 4; ++j) s[i][j] *= 0.125f;
        }

        // ---- online softmax (row stats across the 16 tk lanes) ----
#pragma unroll
        for (int i = 0; i < 4; ++i) {
            float rm = fmaxf(fmaxf(s[i][0], s[i][1]), fmaxf(s[i][2], s[i][3]));
#pragma unroll
            for (int off = 1; off < 16; off <<= 1) rm = fmaxf(rm, __shfl_xor(rm, off));
            const float mn = fmaxf(m[i], rm);
            const float scale = __expf(m[i] - mn);
            float rs = 0.f;
#pragma unroll
            for (int j = 0; j < 4; ++j) {
                s[i][j] = __expf(s[i][j] - mn);
                rs += s[i][j];
            }
#pragma unroll
            for (int off = 1; off < 16; off <<= 1) rs += __shfl_xor(rs, off);
            l[i] = l[i] * scale + rs;
            m[i] = mn;
#pragma unroll
            for (int j = 0; j < 4; ++j) C[i][j] *= scale;
            // store P row-major (float4: 4 consecutive k)
            *reinterpret_cast<float4*>(&Ps[(tq << 2) + i][tk << 2]) =
                make_float4(s[i][0], s[i][1], s[i][2], s[i][3]);
        }
        __syncthreads();   // Ps ready

        // ---- C += P V (kc-blocked: 4 k per step, 4q x 4d per thread) ----
#pragma unroll 4
        for (int kc = 0; kc < 16; ++kc) {
            float4 pf[4], vf[4];
#pragma unroll
            for (int i = 0; i < 4; ++i)
                pf[i] = *reinterpret_cast<const float4*>(&Ps[(tq << 2) + i][kc << 2]);
#pragma unroll
            for (int j = 0; j < 4; ++j)
                vf[j] = *reinterpret_cast<const float4*>(&Vs[(kc << 2) + j][tk << 2]);
#pragma unroll
            for (int i = 0; i < 4; ++i) {
                const float pa[4] = {pf[i].x, pf[i].y, pf[i].z, pf[i].w};
#pragma unroll
                for (int j = 0; j < 4; ++j) {
                    const float va[4] = {vf[0].x, vf[1].x, vf[2].x, vf[3].x};
                    // expand per component to keep everything in registers
                    C[i][j] += pa[0] * ((const float*)&vf[0])[j]
                             + pa[1] * ((const float*)&vf[1])[j]
                             + pa[2] * ((const float*)&vf[2])[j]
                             + pa[3] * ((const float*)&vf[3])[j];
                    (void)va;
                }
            }
        }
        __syncthreads();   // PV reads done before next tile's stores (top of loop)
    }

    // ---- epilogue: normalize + write [b][s][h*64+d] ----
    const int b = bh >> 4, h = bh & (NH - 1);
#pragma unroll
    for (int i = 0; i < 4; ++i) {
        const int qg = q0 + (tq << 2) + i;
        const float inv = 1.f / l[i];
        float4 v;
        v.x = C[i][0] * inv; v.y = C[i][1] * inv;
        v.z = C[i][2] * inv; v.w = C[i][3] * inv;
        *reinterpret_cast<float4*>(&out[((size_t)(b * S + qg)) * DOUT + h * DH + (tk << 2)]) = v;
    }
}

// ---------------------------------------------------------------------------
extern "C" void kernel_launch(void* const* d_in, const int* in_sizes, int n_in,
                              void* d_out, int out_size, void* d_ws, size_t ws_size,
                              hipStream_t stream) {
    const float* x  = (const float*)d_in[0];
    const float* Wq = (const float*)d_in[1];
    const float* Wk = (const float*)d_in[2];
    const float* Wv = (const float*)d_in[3];
    float* out = (float*)d_out;

    float* qws = (float*)d_ws;
    float* kws = qws + (size_t)M_TOT * DOUT;
    float* vws = kws + (size_t)M_TOT * DOUT;

    dim3 pgrid(M_TOT / 64, DOUT / 64);
    proj_kernel<<<pgrid, 256, 0, stream>>>(x, Wq, qws);
    proj_kernel<<<pgrid, 256, 0, stream>>>(x, Wk, kws);
    proj_kernel<<<pgrid, 256, 0, stream>>>(x, Wv, vws);

    // 32 q-tiles x 32 (b,h) pairs
    attn_kernel<<<32 * 32, 256, 0, stream>>>(qws, kws, vws, out);
}

// Round 3
// 618.588 us; speedup vs baseline: 6.6253x; 1.0857x over previous
//
#include <hip/hip_runtime.h>
#include <hip/hip_bf16.h>

// Problem constants: B=2, S=2048, D_IN=1024, D_OUT=1024, H=16, Dh=64
#define B 2
#define S 2048
#define DIN 1024
#define DOUT 1024
#define NH 16
#define DH 64
#define M_TOT (B * S)   // 4096

typedef __attribute__((ext_vector_type(8))) short bf16x8;
typedef __attribute__((ext_vector_type(4))) float f32x4;

__device__ __forceinline__ ushort f2bf(float x) {
    union { float f; unsigned u; } c; c.f = x;
    unsigned r = (c.u + 0x7FFFu + ((c.u >> 16) & 1u)) >> 16;
    return (ushort)r;
}
__device__ __forceinline__ float bf2f(ushort h) {
    union { unsigned u; float f; } c; c.u = ((unsigned)h) << 16;
    return c.f;
}

__device__ __forceinline__ f32x4 mfma16(bf16x8 a, bf16x8 b, f32x4 c) {
    return __builtin_amdgcn_mfma_f32_16x16x32_bf16(a, b, c, 0, 0, 0);
}

// ---------------------------------------------------------------------------
// Projection GEMM: 64x64x16 tile, 4x4 acc/thread.
// MODE 0: fp32 out [bh][s][d]
// MODE 1: 3-way bf16 split out (o0,o1,o2) [bh][s][d]   (for K)
// MODE 2: 2-way bf16 split out, TRANSPOSED (o0,o1) [bh][d][s]  (for V)
// ---------------------------------------------------------------------------
template <int MODE>
__global__ __launch_bounds__(256) void proj_kernel(const float* __restrict__ A,
                                                   const float* __restrict__ W,
                                                   float* __restrict__ outf,
                                                   ushort* __restrict__ o0,
                                                   ushort* __restrict__ o1,
                                                   ushort* __restrict__ o2) {
    __shared__ float As[16][68];
    __shared__ float Bs[16][68];

    const int tid = threadIdx.x;
    const int m0 = blockIdx.x * 64;
    const int n0 = blockIdx.y * 64;

    const int tm = tid >> 4;
    const int tn = tid & 15;

    const int la_r = tid >> 2;
    const int la_c = (tid & 3) << 2;
    const int lb_r = tid >> 4;
    const int lb_c = (tid & 15) << 2;

    float acc[4][4];
#pragma unroll
    for (int i = 0; i < 4; ++i)
#pragma unroll
        for (int j = 0; j < 4; ++j) acc[i][j] = 0.f;

    for (int k0 = 0; k0 < DIN; k0 += 16) {
        const float4 av = *reinterpret_cast<const float4*>(&A[(size_t)(m0 + la_r) * DIN + k0 + la_c]);
        const float4 bv = *reinterpret_cast<const float4*>(&W[(size_t)(k0 + lb_r) * DOUT + n0 + lb_c]);

        __syncthreads();
        As[la_c + 0][la_r] = av.x;
        As[la_c + 1][la_r] = av.y;
        As[la_c + 2][la_r] = av.z;
        As[la_c + 3][la_r] = av.w;
        *reinterpret_cast<float4*>(&Bs[lb_r][lb_c]) = bv;
        __syncthreads();

#pragma unroll
        for (int kk = 0; kk < 16; ++kk) {
            const float4 a = *reinterpret_cast<const float4*>(&As[kk][tm << 2]);
            const float4 b = *reinterpret_cast<const float4*>(&Bs[kk][tn << 2]);
            const float aa[4] = {a.x, a.y, a.z, a.w};
            const float bb[4] = {b.x, b.y, b.z, b.w};
#pragma unroll
            for (int i = 0; i < 4; ++i)
#pragma unroll
                for (int j = 0; j < 4; ++j) acc[i][j] += aa[i] * bb[j];
        }
    }

    const int b = m0 >> 11;
    const int s_base = (m0 & (S - 1)) + (tm << 2);
    const int h = n0 >> 6;
    const int dh = tn << 2;
    const int bh = b * NH + h;

    if (MODE == 0) {
        float* obase = outf + ((size_t)bh * S) * DH;
#pragma unroll
        for (int i = 0; i < 4; ++i) {
            float4 v;
            v.x = acc[i][0]; v.y = acc[i][1]; v.z = acc[i][2]; v.w = acc[i][3];
            *reinterpret_cast<float4*>(&obase[(size_t)(s_base + i) * DH + dh]) = v;
        }
    } else if (MODE == 1) {
#pragma unroll
        for (int i = 0; i < 4; ++i) {
            ushort h0[4], h1[4], h2[4];
#pragma unroll
            for (int j = 0; j < 4; ++j) {
                const float x = acc[i][j];
                h0[j] = f2bf(x);
                const float r1 = x - bf2f(h0[j]);
                h1[j] = f2bf(r1);
                h2[j] = f2bf(r1 - bf2f(h1[j]));
            }
            const size_t base = ((size_t)bh * S + s_base + i) * DH + dh;
            *reinterpret_cast<ushort4*>(o0 + base) = ushort4{h0[0], h0[1], h0[2], h0[3]};
            *reinterpret_cast<ushort4*>(o1 + base) = ushort4{h1[0], h1[1], h1[2], h1[3]};
            *reinterpret_cast<ushort4*>(o2 + base) = ushort4{h2[0], h2[1], h2[2], h2[3]};
        }
    } else {
#pragma unroll
        for (int j = 0; j < 4; ++j) {
            ushort h0[4], h1[4];
#pragma unroll
            for (int i = 0; i < 4; ++i) {
                const float x = acc[i][j];
                h0[i] = f2bf(x);
                h1[i] = f2bf(x - bf2f(h0[i]));
            }
            const size_t base = ((size_t)bh * DH + dh + j) * S + s_base;
            *reinterpret_cast<ushort4*>(o0 + base) = ushort4{h0[0], h0[1], h0[2], h0[3]};
            *reinterpret_cast<ushort4*>(o1 + base) = ushort4{h1[0], h1[1], h1[2], h1[3]};
        }
    }
}

// ---------------------------------------------------------------------------
// MFMA flash attention.
// Block = (bh, 64-row q-tile), 256 threads = 4 waves; wave w owns q rows
// 16w..16w+15 of the tile. QK^T: 3x3 split (6 MFMA terms) for ~fp32 accuracy;
// PV: bf16 P x 2-split V. K tiles row-major [k][d], V tiles pre-transposed
// [d][k], P wave-private [q][k]; all LDS slots XOR-swizzled (slot ^= row&7).
// ---------------------------------------------------------------------------
__global__ __launch_bounds__(256) void attn_mfma(const float* __restrict__ Qf,
                                                 const ushort* __restrict__ K0,
                                                 const ushort* __restrict__ K1,
                                                 const ushort* __restrict__ K2,
                                                 const ushort* __restrict__ V0,
                                                 const ushort* __restrict__ V1,
                                                 float* __restrict__ out) {
    __shared__ __align__(16) ushort KtL[3][64 * 64];
    __shared__ __align__(16) ushort VtL[2][64 * 64];
    __shared__ __align__(16) ushort PsL[64 * 64];

    const int tid = threadIdx.x;
    const int lane = tid & 63;
    const int w = tid >> 6;                      // wave 0..3
    const int bh = blockIdx.x & 31;
    const int qt = 31 - (blockIdx.x >> 5);       // big q-tiles first
    const int q0 = qt << 6;
    const int col = lane & 15;
    const int g = lane >> 4;                     // 0..3

    // ---- Q fragments: 3 splits x 2 k-steps, from fp32, once per block ----
    bf16x8 qfrag[3][2];
    {
        const int qrow = q0 + (w << 4) + col;
        const float* qp = Qf + ((size_t)bh * S + qrow) * DH + (g << 3);
#pragma unroll
        for (int st = 0; st < 2; ++st) {
            const float4 f0 = *reinterpret_cast<const float4*>(qp + 32 * st);
            const float4 f1 = *reinterpret_cast<const float4*>(qp + 32 * st + 4);
            const float xs[8] = {f0.x, f0.y, f0.z, f0.w, f1.x, f1.y, f1.z, f1.w};
#pragma unroll
            for (int e = 0; e < 8; ++e) {
                const float x = xs[e];
                const ushort h0 = f2bf(x);
                const float r1 = x - bf2f(h0);
                const ushort h1 = f2bf(r1);
                const ushort h2 = f2bf(r1 - bf2f(h1));
                qfrag[0][st][e] = (short)h0;
                qfrag[1][st][e] = (short)h1;
                qfrag[2][st][e] = (short)h2;
            }
        }
    }

    f32x4 O[4];
#pragma unroll
    for (int j = 0; j < 4; ++j) O[j] = f32x4{0.f, 0.f, 0.f, 0.f};
    float m_[4] = {-INFINITY, -INFINITY, -INFINITY, -INFINITY};
    float l_[4] = {0.f, 0.f, 0.f, 0.f};

    // staging indices: thread handles row sr, 16 elements (2 swizzled 16B slots)
    const int sr = tid >> 2;            // 0..63
    const int ss = (tid & 3) << 1;      // base slot 0,2,4,6
    const size_t kgbase = (size_t)bh * S * DH;   // K splits: [bh][s][d]
    const size_t vgbase = (size_t)bh * DH * S;   // V splits: [bh][d][s]

    for (int kt = 0; kt <= qt; ++kt) {
        const int k0 = kt << 6;

        // global loads (issued before barrier; latency overlaps barrier wait)
        uint4 gk[3][2], gv[2][2];
        {
            const size_t ko = kgbase + (size_t)(k0 + sr) * DH + (ss << 3);
            gk[0][0] = *reinterpret_cast<const uint4*>(K0 + ko);
            gk[0][1] = *reinterpret_cast<const uint4*>(K0 + ko + 8);
            gk[1][0] = *reinterpret_cast<const uint4*>(K1 + ko);
            gk[1][1] = *reinterpret_cast<const uint4*>(K1 + ko + 8);
            gk[2][0] = *reinterpret_cast<const uint4*>(K2 + ko);
            gk[2][1] = *reinterpret_cast<const uint4*>(K2 + ko + 8);
            const size_t vo = vgbase + (size_t)sr * S + k0 + (ss << 3);
            gv[0][0] = *reinterpret_cast<const uint4*>(V0 + vo);
            gv[0][1] = *reinterpret_cast<const uint4*>(V0 + vo + 8);
            gv[1][0] = *reinterpret_cast<const uint4*>(V1 + vo);
            gv[1][1] = *reinterpret_cast<const uint4*>(V1 + vo + 8);
        }
        __syncthreads();   // previous tile's LDS reads complete
        {
            const int e0 = sr * 64 + (((ss + 0) ^ (sr & 7)) << 3);
            const int e1 = sr * 64 + (((ss + 1) ^ (sr & 7)) << 3);
            *reinterpret_cast<uint4*>(&KtL[0][e0]) = gk[0][0];
            *reinterpret_cast<uint4*>(&KtL[0][e1]) = gk[0][1];
            *reinterpret_cast<uint4*>(&KtL[1][e0]) = gk[1][0];
            *reinterpret_cast<uint4*>(&KtL[1][e1]) = gk[1][1];
            *reinterpret_cast<uint4*>(&KtL[2][e0]) = gk[2][0];
            *reinterpret_cast<uint4*>(&KtL[2][e1]) = gk[2][1];
            *reinterpret_cast<uint4*>(&VtL[0][e0]) = gv[0][0];
            *reinterpret_cast<uint4*>(&VtL[0][e1]) = gv[0][1];
            *reinterpret_cast<uint4*>(&VtL[1][e0]) = gv[1][0];
            *reinterpret_cast<uint4*>(&VtL[1][e1]) = gv[1][1];
        }
        __syncthreads();   // staging visible

        // ---- S = Q K^T : 16q x 64k strip per wave ----
        f32x4 Sf[4];
#pragma unroll
        for (int j = 0; j < 4; ++j) Sf[j] = f32x4{0.f, 0.f, 0.f, 0.f};
#pragma unroll
        for (int st = 0; st < 2; ++st) {
#pragma unroll
            for (int j = 0; j < 4; ++j) {
                const int krow = (j << 4) + col;
                const int eo = krow * 64 + (((g + (st << 2)) ^ (krow & 7)) << 3);
                const bf16x8 kb0 = *reinterpret_cast<const bf16x8*>(&KtL[0][eo]);
                const bf16x8 kb1 = *reinterpret_cast<const bf16x8*>(&KtL[1][eo]);
                const bf16x8 kb2 = *reinterpret_cast<const bf16x8*>(&KtL[2][eo]);
                Sf[j] = mfma16(qfrag[0][st], kb0, Sf[j]);
                Sf[j] = mfma16(qfrag[0][st], kb1, Sf[j]);
                Sf[j] = mfma16(qfrag[1][st], kb0, Sf[j]);
                Sf[j] = mfma16(qfrag[1][st], kb1, Sf[j]);
                Sf[j] = mfma16(qfrag[0][st], kb2, Sf[j]);
                Sf[j] = mfma16(qfrag[2][st], kb0, Sf[j]);
            }
        }

        // ---- online softmax (rows = 4g+r within wave strip) ----
        const bool diag = (kt == qt);
#pragma unroll
        for (int r = 0; r < 4; ++r) {
            float s0 = Sf[0][r] * 0.125f;
            float s1 = Sf[1][r] * 0.125f;
            float s2 = Sf[2][r] * 0.125f;
            float s3 = Sf[3][r] * 0.125f;
            if (diag) {
                const int qg = q0 + (w << 4) + (g << 2) + r;
                s0 = (k0 +  0 + col <= qg) ? s0 : -INFINITY;
                s1 = (k0 + 16 + col <= qg) ? s1 : -INFINITY;
                s2 = (k0 + 32 + col <= qg) ? s2 : -INFINITY;
                s3 = (k0 + 48 + col <= qg) ? s3 : -INFINITY;
            }
            float rm = fmaxf(fmaxf(s0, s1), fmaxf(s2, s3));
#pragma unroll
            for (int off = 1; off < 16; off <<= 1) rm = fmaxf(rm, __shfl_xor(rm, off));
            const float mn = fmaxf(m_[r], rm);
            const float scale = __expf(m_[r] - mn);
            const float p0 = __expf(s0 - mn);
            const float p1 = __expf(s1 - mn);
            const float p2 = __expf(s2 - mn);
            const float p3 = __expf(s3 - mn);
            float rs = (p0 + p1) + (p2 + p3);
#pragma unroll
            for (int off = 1; off < 16; off <<= 1) rs += __shfl_xor(rs, off);
            l_[r] = l_[r] * scale + rs;
            m_[r] = mn;
#pragma unroll
            for (int j = 0; j < 4; ++j) O[j][r] *= scale;

            // store P (bf16) into wave-private LDS rows, swizzled
            const int prow = (w << 4) + (g << 2) + r;
            const int rsw = prow & 7;
            PsL[prow * 64 + (((0 + (col >> 3)) ^ rsw) << 3) + (col & 7)] = f2bf(p0);
            PsL[prow * 64 + (((2 + (col >> 3)) ^ rsw) << 3) + (col & 7)] = f2bf(p1);
            PsL[prow * 64 + (((4 + (col >> 3)) ^ rsw) << 3) + (col & 7)] = f2bf(p2);
            PsL[prow * 64 + (((6 + (col >> 3)) ^ rsw) << 3) + (col & 7)] = f2bf(p3);
        }

        // ---- O += P V (wave-private P; no barrier needed) ----
#pragma unroll
        for (int st = 0; st < 2; ++st) {
            const int prow = (w << 4) + col;
            const int po = prow * 64 + (((g + (st << 2)) ^ (prow & 7)) << 3);
            const bf16x8 pa = *reinterpret_cast<const bf16x8*>(&PsL[po]);
#pragma unroll
            for (int j = 0; j < 4; ++j) {
                const int vrow = (j << 4) + col;
                const int vo = vrow * 64 + (((g + (st << 2)) ^ (vrow & 7)) << 3);
                const bf16x8 vb0 = *reinterpret_cast<const bf16x8*>(&VtL[0][vo]);
                const bf16x8 vb1 = *reinterpret_cast<const bf16x8*>(&VtL[1][vo]);
                O[j] = mfma16(pa, vb0, O[j]);
                O[j] = mfma16(pa, vb1, O[j]);
            }
        }
    }

    // ---- epilogue ----
    const int b = bh >> 4, h = bh & (NH - 1);
#pragma unroll
    for (int r = 0; r < 4; ++r) {
        const int qg = q0 + (w << 4) + (g << 2) + r;
        const float inv = 1.f / l_[r];
        float* op = out + ((size_t)(b * S + qg)) * DOUT + h * DH;
#pragma unroll
        for (int j = 0; j < 4; ++j) op[(j << 4) + col] = O[j][r] * inv;
    }
}

// ---------------------------------------------------------------------------
// Fallback fp32 attention (round-2 path), used only if ws_size < 56 MiB.
// ---------------------------------------------------------------------------
__global__ __launch_bounds__(256) void attn_kernel(const float* __restrict__ Q,
                                                   const float* __restrict__ K,
                                                   const float* __restrict__ V,
                                                   float* __restrict__ out) {
    __shared__ float Qs[64][68];
    __shared__ float Ks[64][68];
    __shared__ float Vs[64][68];
    __shared__ float Ps[64][68];

    const int tid = threadIdx.x;
    const int bh = blockIdx.x & 31;
    const int qt = 31 - (blockIdx.x >> 5);
    const int q0 = qt << 6;

    const int tq = tid >> 4;
    const int tk = tid & 15;
    const int sr = tid >> 2;
    const int sc = (tid & 3) << 2;

    const float* qbase = Q + ((size_t)bh * S + q0) * DH;
    const float* kbase = K + (size_t)bh * S * DH;
    const float* vbase = V + (size_t)bh * S * DH;

#pragma unroll
    for (int it = 0; it < 4; ++it) {
        const int d0 = sc + (it << 4);
        const float4 v = *reinterpret_cast<const float4*>(&qbase[(size_t)sr * DH + d0]);
        Qs[d0 + 0][sr] = v.x; Qs[d0 + 1][sr] = v.y;
        Qs[d0 + 2][sr] = v.z; Qs[d0 + 3][sr] = v.w;
    }

    float C[4][4];
#pragma unroll
    for (int i = 0; i < 4; ++i)
#pragma unroll
        for (int j = 0; j < 4; ++j) C[i][j] = 0.f;
    float m[4] = {-1e30f, -1e30f, -1e30f, -1e30f};
    float l[4] = {0.f, 0.f, 0.f, 0.f};

    for (int kt = 0; kt <= qt; ++kt) {
        const int k0 = kt << 6;
        float4 kv[4], vv[4];
#pragma unroll
        for (int it = 0; it < 4; ++it) {
            const int d0 = sc + (it << 4);
            kv[it] = *reinterpret_cast<const float4*>(&kbase[(size_t)(k0 + sr) * DH + d0]);
            vv[it] = *reinterpret_cast<const float4*>(&vbase[(size_t)(k0 + sr) * DH + d0]);
        }
        __syncthreads();
#pragma unroll
        for (int it = 0; it < 4; ++it) {
            const int d0 = sc + (it << 4);
            Ks[d0 + 0][sr] = kv[it].x; Ks[d0 + 1][sr] = kv[it].y;
            Ks[d0 + 2][sr] = kv[it].z; Ks[d0 + 3][sr] = kv[it].w;
            *reinterpret_cast<float4*>(&Vs[sr][d0]) = vv[it];
        }
        __syncthreads();

        float s[4][4];
#pragma unroll
        for (int i = 0; i < 4; ++i)
#pragma unroll
            for (int j = 0; j < 4; ++j) s[i][j] = 0.f;
#pragma unroll 16
        for (int d = 0; d < 64; ++d) {
            const float4 qf = *reinterpret_cast<const float4*>(&Qs[d][tq << 2]);
            const float4 kf = *reinterpret_cast<const float4*>(&Ks[d][tk << 2]);
            const float qa[4] = {qf.x, qf.y, qf.z, qf.w};
            const float ka[4] = {kf.x, kf.y, kf.z, kf.w};
#pragma unroll
            for (int i = 0; i < 4; ++i)
#pragma unroll
                for (int j = 0; j < 4; ++j) s[i][j] += qa[i] * ka[j];
        }

        if (kt == qt) {
#pragma unroll
            for (int i = 0; i < 4; ++i) {
                const int qg = q0 + (tq << 2) + i;
#pragma unroll
                for (int j = 0; j < 4; ++j) {
                    const int kg = k0 + (tk << 2) + j;
                    s[i][j] = (kg <= qg) ? s[i][j] * 0.125f : -1e30f;
                }
            }
        } else {
#pragma unroll
            for (int i = 0; i < 4; ++i)
#pragma unroll
                for (int j = 0; j < 4; ++j) s[i][j] *= 0.125f;
        }

#pragma unroll
        for (int i = 0; i < 4; ++i) {
            float rm = fmaxf(fmaxf(s[i][0], s[i][1]), fmaxf(s[i][2], s[i][3]));
#pragma unroll
            for (int off = 1; off < 16; off <<= 1) rm = fmaxf(rm, __shfl_xor(rm, off));
            const float mn = fmaxf(m[i], rm);
            const float scale = __expf(m[i] - mn);
            float rs = 0.f;
#pragma unroll
            for (int j = 0; j < 4; ++j) {
                s[i][j] = __expf(s[i][j] - mn);
                rs += s[i][j];
            }
#pragma unroll
            for (int off = 1; off < 16; off <<= 1) rs += __shfl_xor(rs, off);
            l[i] = l[i] * scale + rs;
            m[i] = mn;
#pragma unroll
            for (int j = 0; j < 4; ++j) C[i][j] *= scale;
            *reinterpret_cast<float4*>(&Ps[(tq << 2) + i][tk << 2]) =
                make_float4(s[i][0], s[i][1], s[i][2], s[i][3]);
        }
        __syncthreads();

#pragma unroll 4
        for (int kc = 0; kc < 16; ++kc) {
            float4 pf[4], vf[4];
#pragma unroll
            for (int i = 0; i < 4; ++i)
                pf[i] = *reinterpret_cast<const float4*>(&Ps[(tq << 2) + i][kc << 2]);
#pragma unroll
            for (int j = 0; j < 4; ++j)
                vf[j] = *reinterpret_cast<const float4*>(&Vs[(kc << 2) + j][tk << 2]);
#pragma unroll
            for (int i = 0; i < 4; ++i) {
                const float pa[4] = {pf[i].x, pf[i].y, pf[i].z, pf[i].w};
#pragma unroll
                for (int j = 0; j < 4; ++j) {
                    C[i][j] += pa[0] * ((const float*)&vf[0])[j]
                             + pa[1] * ((const float*)&vf[1])[j]
                             + pa[2] * ((const float*)&vf[2])[j]
                             + pa[3] * ((const float*)&vf[3])[j];
                }
            }
        }
        __syncthreads();
    }

    const int b = bh >> 4, h = bh & (NH - 1);
#pragma unroll
    for (int i = 0; i < 4; ++i) {
        const int qg = q0 + (tq << 2) + i;
        const float inv = 1.f / l[i];
        float4 v;
        v.x = C[i][0] * inv; v.y = C[i][1] * inv;
        v.z = C[i][2] * inv; v.w = C[i][3] * inv;
        *reinterpret_cast<float4*>(&out[((size_t)(b * S + qg)) * DOUT + h * DH + (tk << 2)]) = v;
    }
}

// ---------------------------------------------------------------------------
extern "C" void kernel_launch(void* const* d_in, const int* in_sizes, int n_in,
                              void* d_out, int out_size, void* d_ws, size_t ws_size,
                              hipStream_t stream) {
    const float* x  = (const float*)d_in[0];
    const float* Wq = (const float*)d_in[1];
    const float* Wk = (const float*)d_in[2];
    const float* Wv = (const float*)d_in[3];
    float* out = (float*)d_out;

    char* ws = (char*)d_ws;
    const size_t MB = 1024 * 1024;
    dim3 pgrid(M_TOT / 64, DOUT / 64);

    if (ws_size >= 56 * MB) {
        // new path: Q fp32 + K 3-split bf16 + V 2-split transposed bf16
        float*  qf  = (float*)(ws);                 // 16 MB
        ushort* ks0 = (ushort*)(ws + 16 * MB);      // 8 MB each
        ushort* ks1 = (ushort*)(ws + 24 * MB);
        ushort* ks2 = (ushort*)(ws + 32 * MB);
        ushort* vt0 = (ushort*)(ws + 40 * MB);
        ushort* vt1 = (ushort*)(ws + 48 * MB);

        proj_kernel<0><<<pgrid, 256, 0, stream>>>(x, Wq, qf, nullptr, nullptr, nullptr);
        proj_kernel<1><<<pgrid, 256, 0, stream>>>(x, Wk, nullptr, ks0, ks1, ks2);
        proj_kernel<2><<<pgrid, 256, 0, stream>>>(x, Wv, nullptr, vt0, vt1, nullptr);

        attn_mfma<<<32 * 32, 256, 0, stream>>>(qf, ks0, ks1, ks2, vt0, vt1, out);
    } else {
        // fallback: round-2 fp32 path (needs 48 MB)
        float* qws = (float*)d_ws;
        float* kws = qws + (size_t)M_TOT * DOUT;
        float* vws = kws + (size_t)M_TOT * DOUT;

        proj_kernel<0><<<pgrid, 256, 0, stream>>>(x, Wq, qws, nullptr, nullptr, nullptr);
        proj_kernel<0><<<pgrid, 256, 0, stream>>>(x, Wk, kws, nullptr, nullptr, nullptr);
        proj_kernel<0><<<pgrid, 256, 0, stream>>>(x, Wv, vws, nullptr, nullptr, nullptr);

        attn_kernel<<<32 * 32, 256, 0, stream>>>(qws, kws, vws, out);
    }
}

// Round 4
// 280.720 us; speedup vs baseline: 14.5992x; 2.2036x over previous
//
#include <hip/hip_runtime.h>
#include <hip/hip_bf16.h>

// Problem constants: B=2, S=2048, D_IN=1024, D_OUT=1024, H=16, Dh=64
#define B 2
#define S 2048
#define DIN 1024
#define DOUT 1024
#define NH 16
#define DH 64
#define M_TOT (B * S)   // 4096

typedef __attribute__((ext_vector_type(8))) short bf16x8;
typedef __attribute__((ext_vector_type(8))) unsigned short u16x8;
typedef __attribute__((ext_vector_type(4))) float f32x4;

#define ASTRIDE 4194304   // elements per 4096x1024 split array
#define WSTRIDE 1048576   // elements per 1024x1024 split array

__device__ __forceinline__ ushort f2bf(float x) {
    union { float f; unsigned u; } c; c.f = x;
    unsigned r = (c.u + 0x7FFFu + ((c.u >> 16) & 1u)) >> 16;
    return (ushort)r;
}
__device__ __forceinline__ float bf2f(ushort h) {
    union { unsigned u; float f; } c; c.u = ((unsigned)h) << 16;
    return c.f;
}
__device__ __forceinline__ f32x4 mfma16(bf16x8 a, bf16x8 b, f32x4 c) {
    return __builtin_amdgcn_mfma_f32_16x16x32_bf16(a, b, c, 0, 0, 0);
}

// ===========================================================================
// NEW PATH (ws >= 84 MB)
// ===========================================================================

// ---- prepass: x (fp32 [4096][1024]) -> 3-way bf16 splits (same layout) ----
__global__ __launch_bounds__(256) void split_x(const float* __restrict__ x,
                                               ushort* __restrict__ xs) {
    const size_t gid = (size_t)blockIdx.x * 256 + threadIdx.x;
    const float4 v = *reinterpret_cast<const float4*>(x + gid * 4);
    const float in[4] = {v.x, v.y, v.z, v.w};
    ushort h0[4], h1[4], h2[4];
#pragma unroll
    for (int e = 0; e < 4; ++e) {
        h0[e] = f2bf(in[e]);
        const float r1 = in[e] - bf2f(h0[e]);
        h1[e] = f2bf(r1);
        h2[e] = f2bf(r1 - bf2f(h1[e]));
    }
    const size_t o = gid * 4;
    *reinterpret_cast<ushort4*>(xs + o)               = ushort4{h0[0], h0[1], h0[2], h0[3]};
    *reinterpret_cast<ushort4*>(xs + ASTRIDE + o)     = ushort4{h1[0], h1[1], h1[2], h1[3]};
    *reinterpret_cast<ushort4*>(xs + 2 * ASTRIDE + o) = ushort4{h2[0], h2[1], h2[2], h2[3]};
}

// ---- prepass: W (fp32 [1024 k][1024 n]) -> W^T 2-way bf16 splits [n][k] ----
__global__ __launch_bounds__(256) void split_wT(const float* __restrict__ W,
                                                ushort* __restrict__ wt) {
    __shared__ float Ws[64][68];
    const int tid = threadIdx.x;
    const int k0 = blockIdx.x << 6;
    const int n0 = blockIdx.y << 6;
    const int r = tid >> 2;
    const int cb = (tid & 3) << 2;
#pragma unroll
    for (int it = 0; it < 4; ++it) {
        const int c = cb + (it << 4);
        *reinterpret_cast<float4*>(&Ws[r][c]) =
            *reinterpret_cast<const float4*>(&W[(size_t)(k0 + r) * 1024 + n0 + c]);
    }
    __syncthreads();
    const int rn = tid >> 2;           // local n row
    const int kc = (tid & 3) << 4;     // local k chunk of 16
    u16x8 o0[2], o1[2];
#pragma unroll
    for (int half = 0; half < 2; ++half)
#pragma unroll
        for (int i = 0; i < 8; ++i) {
            const float x = Ws[kc + (half << 3) + i][rn];
            const ushort a = f2bf(x);
            o0[half][i] = a;
            o1[half][i] = f2bf(x - bf2f(a));
        }
    const size_t base = (size_t)(n0 + rn) * 1024 + k0 + kc;
    *reinterpret_cast<u16x8*>(wt + base)               = o0[0];
    *reinterpret_cast<u16x8*>(wt + base + 8)           = o0[1];
    *reinterpret_cast<u16x8*>(wt + WSTRIDE + base)     = o1[0];
    *reinterpret_cast<u16x8*>(wt + WSTRIDE + base + 8) = o1[1];
}

// ---------------------------------------------------------------------------
// MFMA projection: C = x @ W via 5-term split product (a0b0+a1b0+a2b0+a0b1+a1b1).
// Tile 128(M)x64(N), BK=64, 4 waves (2x2), wave owns 64x32. LDS = 64 KB:
// A splits 3x[128][64] bf16 + B splits 2x[64][64] bf16, 128B rows,
// slot ^ (row&7) swizzle, staged via global_load_lds (linear dest,
// source slot pre-swizzled per lane). 2 blocks/CU.
// MODE 0: fp32 out [bh][s][d]; MODE 1: 3-split out; MODE 2: 2-split out.
// ---------------------------------------------------------------------------
template <int MODE>
__global__ __launch_bounds__(256, 2) void proj_mfma(const ushort* __restrict__ asp,
                                                    const ushort* __restrict__ wtsp,
                                                    float* __restrict__ outf,
                                                    ushort* __restrict__ outs) {
    __shared__ __align__(16) ushort SL[32768];   // 64 KB total

    const int tid = threadIdx.x;
    const int lane = tid & 63;
    const int w = tid >> 6;
    const int wr = w >> 1, wc = w & 1;
    // XCD-aware swizzle: 512 blocks, 8 XCDs -> contiguous 64-block chunks
    const int swz = (blockIdx.x & 7) * 64 + (blockIdx.x >> 3);
    const int m0 = (swz & 31) << 7;   // 32 m-tiles
    const int n0 = (swz >> 5) << 6;   // 16 n-tiles
    const int col = lane & 15;
    const int glane = lane >> 4;

    const int lrow = lane >> 3;                  // 0..7
    const int sl8 = ((lane & 7) ^ lrow) << 3;    // pre-swizzled source slot

    f32x4 acc[4][2];
#pragma unroll
    for (int mi = 0; mi < 4; ++mi)
#pragma unroll
        for (int nj = 0; nj < 2; ++nj) acc[mi][nj] = f32x4{0.f, 0.f, 0.f, 0.f};

    for (int k0 = 0; k0 < DIN; k0 += 64) {
        __syncthreads();   // previous step's LDS reads done
#pragma unroll
        for (int i = 0; i < 16; ++i) {
            const int u = (i << 2) | w;          // 0..63
            const int a = u >> 4;                // 0..3
            const ushort* g;
            if (a < 3) {
                const int rb = u & 15;
                g = asp + (size_t)a * ASTRIDE + (size_t)(m0 + (rb << 3) + lrow) * 1024 + k0 + sl8;
            } else {
                const int sub = u & 15;          // 0..15
                const int sp = sub >> 3;
                const int rb = sub & 7;
                g = wtsp + (size_t)sp * WSTRIDE + (size_t)(n0 + (rb << 3) + lrow) * 1024 + k0 + sl8;
            }
            __builtin_amdgcn_global_load_lds(g, &SL[u * 512], 16, 0, 0);
        }
        __syncthreads();   // staging drained (vmcnt(0)) + visible

#pragma unroll
        for (int st = 0; st < 2; ++st) {
            bf16x8 af[3][4];
#pragma unroll
            for (int s = 0; s < 3; ++s)
#pragma unroll
                for (int mi = 0; mi < 4; ++mi) {
                    const int arow = (wr << 6) + (mi << 4) + col;
                    af[s][mi] = *reinterpret_cast<const bf16x8*>(
                        &SL[s * 8192 + arow * 64 + (((glane + (st << 2)) ^ (col & 7)) << 3)]);
                }
#pragma unroll
            for (int nj = 0; nj < 2; ++nj) {
                const int brow = (wc << 5) + (nj << 4) + col;
                const int bo = 24576 + brow * 64 + (((glane + (st << 2)) ^ (col & 7)) << 3);
                const bf16x8 b0 = *reinterpret_cast<const bf16x8*>(&SL[bo]);
                const bf16x8 b1 = *reinterpret_cast<const bf16x8*>(&SL[bo + 4096]);
#pragma unroll
                for (int mi = 0; mi < 4; ++mi) {
                    acc[mi][nj] = mfma16(af[0][mi], b0, acc[mi][nj]);
                    acc[mi][nj] = mfma16(af[1][mi], b0, acc[mi][nj]);
                    acc[mi][nj] = mfma16(af[0][mi], b1, acc[mi][nj]);
                    acc[mi][nj] = mfma16(af[1][mi], b1, acc[mi][nj]);
                    acc[mi][nj] = mfma16(af[2][mi], b0, acc[mi][nj]);
                }
            }
        }
    }

    // epilogue: [bh][s][d]
    const int b = m0 >> 11;
    const int h = n0 >> 6;                 // BN=64 == head width
    const size_t bh_off = (size_t)(b * NH + h) * S * DH;
#pragma unroll
    for (int mi = 0; mi < 4; ++mi)
#pragma unroll
        for (int r = 0; r < 4; ++r) {
            const int srow = (m0 & (S - 1)) + (wr << 6) + (mi << 4) + (glane << 2) + r;
#pragma unroll
            for (int nj = 0; nj < 2; ++nj) {
                const float xv = acc[mi][nj][r];
                const size_t o = bh_off + (size_t)srow * DH + (wc << 5) + (nj << 4) + col;
                if (MODE == 0) {
                    outf[o] = xv;
                } else {
                    const ushort h0 = f2bf(xv);
                    const float r1 = xv - bf2f(h0);
                    const ushort h1 = f2bf(r1);
                    outs[o] = h0;
                    outs[ASTRIDE + o] = h1;
                    if (MODE == 1) outs[2 * ASTRIDE + o] = f2bf(r1 - bf2f(h1));
                }
            }
        }
}

// ---- V transpose: 2-split [bh][s][64] -> 2-split [bh][64][s] ----
__global__ __launch_bounds__(256) void transpose_v(const ushort* __restrict__ v,
                                                   ushort* __restrict__ vt) {
    __shared__ ushort Ts[2][64][72];
    const int tid = threadIdx.x;
    const int bh = blockIdx.x & 31;
    const int s0 = (blockIdx.x >> 5) << 6;
    const int r = tid >> 2;
    const int c16 = (tid & 3) << 4;
#pragma unroll
    for (int sp = 0; sp < 2; ++sp)
#pragma unroll
        for (int e = 0; e < 2; ++e) {
            *reinterpret_cast<u16x8*>(&Ts[sp][r][c16 + (e << 3)]) =
                *reinterpret_cast<const u16x8*>(
                    &v[(size_t)sp * ASTRIDE + ((size_t)bh * S + s0 + r) * DH + c16 + (e << 3)]);
        }
    __syncthreads();
    const int dr = tid >> 2;
    const int sc = (tid & 3) << 4;
#pragma unroll
    for (int sp = 0; sp < 2; ++sp) {
        u16x8 o0, o1;
#pragma unroll
        for (int i = 0; i < 8; ++i) {
            o0[i] = Ts[sp][sc + i][dr];
            o1[i] = Ts[sp][sc + 8 + i][dr];
        }
        const size_t base = (size_t)sp * ASTRIDE + ((size_t)bh * DH + dr) * S + s0 + sc;
        *reinterpret_cast<u16x8*>(vt + base) = o0;
        *reinterpret_cast<u16x8*>(vt + base + 8) = o1;
    }
}

// ---------------------------------------------------------------------------
// MFMA flash attention v2: K/V staged via global_load_lds (no reg staging).
// Math identical to round 3: Q 3-split (in-kernel from fp32), K 3-split,
// 6-term QK; P bf16; V 2-split (pre-transposed), 2-term PV.
// LDS: 5 arrays [64][64] bf16 (K0,K1,K2,VT0,VT1) + P [64][64]. 48 KB.
// ---------------------------------------------------------------------------
__global__ __launch_bounds__(256, 3) void attn_mfma2(const float* __restrict__ Qf,
                                                     const ushort* __restrict__ ksp,
                                                     const ushort* __restrict__ vtsp,
                                                     float* __restrict__ out) {
    __shared__ __align__(16) ushort KVL[5 * 4096];
    __shared__ __align__(16) ushort PL[4096];

    const int tid = threadIdx.x;
    const int lane = tid & 63;
    const int w = tid >> 6;
    // XCD swizzle: 1024 blocks -> XCD x gets bh in [4x, 4x+4)
    const int swz = (blockIdx.x & 7) * 128 + (blockIdx.x >> 3);
    const int bh = swz >> 5;
    const int qt = 31 - (swz & 31);        // big q-tiles first
    const int q0 = qt << 6;
    const int col = lane & 15;
    const int g = lane >> 4;

    // ---- Q fragments: 3 splits x 2 k-steps, from fp32, once per block ----
    bf16x8 qfrag[3][2];
    {
        const int qrow = q0 + (w << 4) + col;
        const float* qp = Qf + ((size_t)bh * S + qrow) * DH + (g << 3);
#pragma unroll
        for (int st = 0; st < 2; ++st) {
            const float4 f0 = *reinterpret_cast<const float4*>(qp + 32 * st);
            const float4 f1 = *reinterpret_cast<const float4*>(qp + 32 * st + 4);
            const float xs[8] = {f0.x, f0.y, f0.z, f0.w, f1.x, f1.y, f1.z, f1.w};
#pragma unroll
            for (int e = 0; e < 8; ++e) {
                const float x = xs[e];
                const ushort h0 = f2bf(x);
                const float r1 = x - bf2f(h0);
                const ushort h1 = f2bf(r1);
                qfrag[0][st][e] = (short)h0;
                qfrag[1][st][e] = (short)h1;
                qfrag[2][st][e] = (short)f2bf(r1 - bf2f(h1));
            }
        }
    }

    f32x4 O[4];
#pragma unroll
    for (int j = 0; j < 4; ++j) O[j] = f32x4{0.f, 0.f, 0.f, 0.f};
    float m_[4] = {-INFINITY, -INFINITY, -INFINITY, -INFINITY};
    float l_[4] = {0.f, 0.f, 0.f, 0.f};

    const int lrow = lane >> 3;
    const int sl8 = ((lane & 7) ^ lrow) << 3;

    for (int kt = 0; kt <= qt; ++kt) {
        const int k0 = kt << 6;

        __syncthreads();   // previous tile's LDS reads complete
#pragma unroll
        for (int i = 0; i < 10; ++i) {
            const int u = (i << 2) | w;        // 0..39
            const int a = u >> 3;              // 0..4
            const int rb = u & 7;
            const ushort* gp;
            if (a < 3)
                gp = ksp + (size_t)a * ASTRIDE +
                     ((size_t)bh * S + k0 + (rb << 3) + lrow) * DH + sl8;
            else
                gp = vtsp + (size_t)(a - 3) * ASTRIDE +
                     ((size_t)bh * DH + (rb << 3) + lrow) * S + k0 + sl8;
            __builtin_amdgcn_global_load_lds(gp, &KVL[u * 512], 16, 0, 0);
        }
        __syncthreads();   // staging drained + visible

        // ---- S = Q K^T : 16q x 64k strip per wave (6 split terms) ----
        f32x4 Sf[4];
#pragma unroll
        for (int j = 0; j < 4; ++j) Sf[j] = f32x4{0.f, 0.f, 0.f, 0.f};
#pragma unroll
        for (int st = 0; st < 2; ++st) {
#pragma unroll
            for (int j = 0; j < 4; ++j) {
                const int krow = (j << 4) + col;
                const int eo = krow * 64 + (((g + (st << 2)) ^ (krow & 7)) << 3);
                const bf16x8 kb0 = *reinterpret_cast<const bf16x8*>(&KVL[eo]);
                const bf16x8 kb1 = *reinterpret_cast<const bf16x8*>(&KVL[4096 + eo]);
                const bf16x8 kb2 = *reinterpret_cast<const bf16x8*>(&KVL[8192 + eo]);
                Sf[j] = mfma16(qfrag[0][st], kb0, Sf[j]);
                Sf[j] = mfma16(qfrag[0][st], kb1, Sf[j]);
                Sf[j] = mfma16(qfrag[1][st], kb0, Sf[j]);
                Sf[j] = mfma16(qfrag[1][st], kb1, Sf[j]);
                Sf[j] = mfma16(qfrag[0][st], kb2, Sf[j]);
                Sf[j] = mfma16(qfrag[2][st], kb0, Sf[j]);
            }
        }

        // ---- online softmax (rows = 4g+r within wave strip) ----
        const bool diag = (kt == qt);
#pragma unroll
        for (int r = 0; r < 4; ++r) {
            float s0 = Sf[0][r] * 0.125f;
            float s1 = Sf[1][r] * 0.125f;
            float s2 = Sf[2][r] * 0.125f;
            float s3 = Sf[3][r] * 0.125f;
            if (diag) {
                const int qg = q0 + (w << 4) + (g << 2) + r;
                s0 = (k0 +  0 + col <= qg) ? s0 : -INFINITY;
                s1 = (k0 + 16 + col <= qg) ? s1 : -INFINITY;
                s2 = (k0 + 32 + col <= qg) ? s2 : -INFINITY;
                s3 = (k0 + 48 + col <= qg) ? s3 : -INFINITY;
            }
            float rm = fmaxf(fmaxf(s0, s1), fmaxf(s2, s3));
#pragma unroll
            for (int off = 1; off < 16; off <<= 1) rm = fmaxf(rm, __shfl_xor(rm, off));
            const float mn = fmaxf(m_[r], rm);
            const float scale = __expf(m_[r] - mn);
            const float p0 = __expf(s0 - mn);
            const float p1 = __expf(s1 - mn);
            const float p2 = __expf(s2 - mn);
            const float p3 = __expf(s3 - mn);
            float rs = (p0 + p1) + (p2 + p3);
#pragma unroll
            for (int off = 1; off < 16; off <<= 1) rs += __shfl_xor(rs, off);
            l_[r] = l_[r] * scale + rs;
            m_[r] = mn;
#pragma unroll
            for (int j = 0; j < 4; ++j) O[j][r] *= scale;

            const int prow = (w << 4) + (g << 2) + r;
            const int rsw = prow & 7;
            PL[prow * 64 + (((0 + (col >> 3)) ^ rsw) << 3) + (col & 7)] = f2bf(p0);
            PL[prow * 64 + (((2 + (col >> 3)) ^ rsw) << 3) + (col & 7)] = f2bf(p1);
            PL[prow * 64 + (((4 + (col >> 3)) ^ rsw) << 3) + (col & 7)] = f2bf(p2);
            PL[prow * 64 + (((6 + (col >> 3)) ^ rsw) << 3) + (col & 7)] = f2bf(p3);
        }

        // ---- O += P V (wave-private P; no barrier needed) ----
#pragma unroll
        for (int st = 0; st < 2; ++st) {
            const int prow = (w << 4) + col;
            const int po = prow * 64 + (((g + (st << 2)) ^ (prow & 7)) << 3);
            const bf16x8 pa = *reinterpret_cast<const bf16x8*>(&PL[po]);
#pragma unroll
            for (int j = 0; j < 4; ++j) {
                const int vrow = (j << 4) + col;
                const int vo = vrow * 64 + (((g + (st << 2)) ^ (vrow & 7)) << 3);
                const bf16x8 vb0 = *reinterpret_cast<const bf16x8*>(&KVL[3 * 4096 + vo]);
                const bf16x8 vb1 = *reinterpret_cast<const bf16x8*>(&KVL[4 * 4096 + vo]);
                O[j] = mfma16(pa, vb0, O[j]);
                O[j] = mfma16(pa, vb1, O[j]);
            }
        }
    }

    // ---- epilogue ----
    const int b = bh >> 4, h = bh & (NH - 1);
#pragma unroll
    for (int r = 0; r < 4; ++r) {
        const int qg = q0 + (w << 4) + (g << 2) + r;
        const float inv = 1.f / l_[r];
        float* op = out + ((size_t)(b * S + qg)) * DOUT + h * DH;
#pragma unroll
        for (int j = 0; j < 4; ++j) op[(j << 4) + col] = O[j][r] * inv;
    }
}

// ===========================================================================
// FALLBACK TIER 2 (round-3 path, ws >= 56 MB): old proj + reg-staged attn
// ===========================================================================
template <int MODE>
__global__ __launch_bounds__(256) void proj_kernel(const float* __restrict__ A,
                                                   const float* __restrict__ W,
                                                   float* __restrict__ outf,
                                                   ushort* __restrict__ o0,
                                                   ushort* __restrict__ o1,
                                                   ushort* __restrict__ o2) {
    __shared__ float As[16][68];
    __shared__ float Bs[16][68];

    const int tid = threadIdx.x;
    const int m0 = blockIdx.x * 64;
    const int n0 = blockIdx.y * 64;
    const int tm = tid >> 4;
    const int tn = tid & 15;
    const int la_r = tid >> 2;
    const int la_c = (tid & 3) << 2;
    const int lb_r = tid >> 4;
    const int lb_c = (tid & 15) << 2;

    float acc[4][4];
#pragma unroll
    for (int i = 0; i < 4; ++i)
#pragma unroll
        for (int j = 0; j < 4; ++j) acc[i][j] = 0.f;

    for (int k0 = 0; k0 < DIN; k0 += 16) {
        const float4 av = *reinterpret_cast<const float4*>(&A[(size_t)(m0 + la_r) * DIN + k0 + la_c]);
        const float4 bv = *reinterpret_cast<const float4*>(&W[(size_t)(k0 + lb_r) * DOUT + n0 + lb_c]);
        __syncthreads();
        As[la_c + 0][la_r] = av.x;
        As[la_c + 1][la_r] = av.y;
        As[la_c + 2][la_r] = av.z;
        As[la_c + 3][la_r] = av.w;
        *reinterpret_cast<float4*>(&Bs[lb_r][lb_c]) = bv;
        __syncthreads();
#pragma unroll
        for (int kk = 0; kk < 16; ++kk) {
            const float4 a = *reinterpret_cast<const float4*>(&As[kk][tm << 2]);
            const float4 b = *reinterpret_cast<const float4*>(&Bs[kk][tn << 2]);
            const float aa[4] = {a.x, a.y, a.z, a.w};
            const float bb[4] = {b.x, b.y, b.z, b.w};
#pragma unroll
            for (int i = 0; i < 4; ++i)
#pragma unroll
                for (int j = 0; j < 4; ++j) acc[i][j] += aa[i] * bb[j];
        }
    }

    const int b = m0 >> 11;
    const int s_base = (m0 & (S - 1)) + (tm << 2);
    const int h = n0 >> 6;
    const int dh = tn << 2;
    const int bh = b * NH + h;

    if (MODE == 0) {
        float* obase = outf + ((size_t)bh * S) * DH;
#pragma unroll
        for (int i = 0; i < 4; ++i) {
            float4 v;
            v.x = acc[i][0]; v.y = acc[i][1]; v.z = acc[i][2]; v.w = acc[i][3];
            *reinterpret_cast<float4*>(&obase[(size_t)(s_base + i) * DH + dh]) = v;
        }
    } else if (MODE == 1) {
#pragma unroll
        for (int i = 0; i < 4; ++i) {
            ushort h0[4], h1[4], h2[4];
#pragma unroll
            for (int j = 0; j < 4; ++j) {
                const float x = acc[i][j];
                h0[j] = f2bf(x);
                const float r1 = x - bf2f(h0[j]);
                h1[j] = f2bf(r1);
                h2[j] = f2bf(r1 - bf2f(h1[j]));
            }
            const size_t base = ((size_t)bh * S + s_base + i) * DH + dh;
            *reinterpret_cast<ushort4*>(o0 + base) = ushort4{h0[0], h0[1], h0[2], h0[3]};
            *reinterpret_cast<ushort4*>(o1 + base) = ushort4{h1[0], h1[1], h1[2], h1[3]};
            *reinterpret_cast<ushort4*>(o2 + base) = ushort4{h2[0], h2[1], h2[2], h2[3]};
        }
    } else {
#pragma unroll
        for (int j = 0; j < 4; ++j) {
            ushort h0[4], h1[4];
#pragma unroll
            for (int i = 0; i < 4; ++i) {
                const float x = acc[i][j];
                h0[i] = f2bf(x);
                h1[i] = f2bf(x - bf2f(h0[i]));
            }
            const size_t base = ((size_t)bh * DH + dh + j) * S + s_base;
            *reinterpret_cast<ushort4*>(o0 + base) = ushort4{h0[0], h0[1], h0[2], h0[3]};
            *reinterpret_cast<ushort4*>(o1 + base) = ushort4{h1[0], h1[1], h1[2], h1[3]};
        }
    }
}

__global__ __launch_bounds__(256) void attn_mfma(const float* __restrict__ Qf,
                                                 const ushort* __restrict__ K0,
                                                 const ushort* __restrict__ K1,
                                                 const ushort* __restrict__ K2,
                                                 const ushort* __restrict__ V0,
                                                 const ushort* __restrict__ V1,
                                                 float* __restrict__ out) {
    __shared__ __align__(16) ushort KtL[3][64 * 64];
    __shared__ __align__(16) ushort VtL[2][64 * 64];
    __shared__ __align__(16) ushort PsL[64 * 64];

    const int tid = threadIdx.x;
    const int lane = tid & 63;
    const int w = tid >> 6;
    const int bh = blockIdx.x & 31;
    const int qt = 31 - (blockIdx.x >> 5);
    const int q0 = qt << 6;
    const int col = lane & 15;
    const int g = lane >> 4;

    bf16x8 qfrag[3][2];
    {
        const int qrow = q0 + (w << 4) + col;
        const float* qp = Qf + ((size_t)bh * S + qrow) * DH + (g << 3);
#pragma unroll
        for (int st = 0; st < 2; ++st) {
            const float4 f0 = *reinterpret_cast<const float4*>(qp + 32 * st);
            const float4 f1 = *reinterpret_cast<const float4*>(qp + 32 * st + 4);
            const float xs[8] = {f0.x, f0.y, f0.z, f0.w, f1.x, f1.y, f1.z, f1.w};
#pragma unroll
            for (int e = 0; e < 8; ++e) {
                const float x = xs[e];
                const ushort h0 = f2bf(x);
                const float r1 = x - bf2f(h0);
                const ushort h1 = f2bf(r1);
                const ushort h2 = f2bf(r1 - bf2f(h1));
                qfrag[0][st][e] = (short)h0;
                qfrag[1][st][e] = (short)h1;
                qfrag[2][st][e] = (short)h2;
            }
        }
    }

    f32x4 O[4];
#pragma unroll
    for (int j = 0; j < 4; ++j) O[j] = f32x4{0.f, 0.f, 0.f, 0.f};
    float m_[4] = {-INFINITY, -INFINITY, -INFINITY, -INFINITY};
    float l_[4] = {0.f, 0.f, 0.f, 0.f};

    const int sr = tid >> 2;
    const int ss = (tid & 3) << 1;
    const size_t kgbase = (size_t)bh * S * DH;
    const size_t vgbase = (size_t)bh * DH * S;

    for (int kt = 0; kt <= qt; ++kt) {
        const int k0 = kt << 6;
        uint4 gk[3][2], gv[2][2];
        {
            const size_t ko = kgbase + (size_t)(k0 + sr) * DH + (ss << 3);
            gk[0][0] = *reinterpret_cast<const uint4*>(K0 + ko);
            gk[0][1] = *reinterpret_cast<const uint4*>(K0 + ko + 8);
            gk[1][0] = *reinterpret_cast<const uint4*>(K1 + ko);
            gk[1][1] = *reinterpret_cast<const uint4*>(K1 + ko + 8);
            gk[2][0] = *reinterpret_cast<const uint4*>(K2 + ko);
            gk[2][1] = *reinterpret_cast<const uint4*>(K2 + ko + 8);
            const size_t vo = vgbase + (size_t)sr * S + k0 + (ss << 3);
            gv[0][0] = *reinterpret_cast<const uint4*>(V0 + vo);
            gv[0][1] = *reinterpret_cast<const uint4*>(V0 + vo + 8);
            gv[1][0] = *reinterpret_cast<const uint4*>(V1 + vo);
            gv[1][1] = *reinterpret_cast<const uint4*>(V1 + vo + 8);
        }
        __syncthreads();
        {
            const int e0 = sr * 64 + (((ss + 0) ^ (sr & 7)) << 3);
            const int e1 = sr * 64 + (((ss + 1) ^ (sr & 7)) << 3);
            *reinterpret_cast<uint4*>(&KtL[0][e0]) = gk[0][0];
            *reinterpret_cast<uint4*>(&KtL[0][e1]) = gk[0][1];
            *reinterpret_cast<uint4*>(&KtL[1][e0]) = gk[1][0];
            *reinterpret_cast<uint4*>(&KtL[1][e1]) = gk[1][1];
            *reinterpret_cast<uint4*>(&KtL[2][e0]) = gk[2][0];
            *reinterpret_cast<uint4*>(&KtL[2][e1]) = gk[2][1];
            *reinterpret_cast<uint4*>(&VtL[0][e0]) = gv[0][0];
            *reinterpret_cast<uint4*>(&VtL[0][e1]) = gv[0][1];
            *reinterpret_cast<uint4*>(&VtL[1][e0]) = gv[1][0];
            *reinterpret_cast<uint4*>(&VtL[1][e1]) = gv[1][1];
        }
        __syncthreads();

        f32x4 Sf[4];
#pragma unroll
        for (int j = 0; j < 4; ++j) Sf[j] = f32x4{0.f, 0.f, 0.f, 0.f};
#pragma unroll
        for (int st = 0; st < 2; ++st) {
#pragma unroll
            for (int j = 0; j < 4; ++j) {
                const int krow = (j << 4) + col;
                const int eo = krow * 64 + (((g + (st << 2)) ^ (krow & 7)) << 3);
                const bf16x8 kb0 = *reinterpret_cast<const bf16x8*>(&KtL[0][eo]);
                const bf16x8 kb1 = *reinterpret_cast<const bf16x8*>(&KtL[1][eo]);
                const bf16x8 kb2 = *reinterpret_cast<const bf16x8*>(&KtL[2][eo]);
                Sf[j] = mfma16(qfrag[0][st], kb0, Sf[j]);
                Sf[j] = mfma16(qfrag[0][st], kb1, Sf[j]);
                Sf[j] = mfma16(qfrag[1][st], kb0, Sf[j]);
                Sf[j] = mfma16(qfrag[1][st], kb1, Sf[j]);
                Sf[j] = mfma16(qfrag[0][st], kb2, Sf[j]);
                Sf[j] = mfma16(qfrag[2][st], kb0, Sf[j]);
            }
        }

        const bool diag = (kt == qt);
#pragma unroll
        for (int r = 0; r < 4; ++r) {
            float s0 = Sf[0][r] * 0.125f;
            float s1 = Sf[1][r] * 0.125f;
            float s2 = Sf[2][r] * 0.125f;
            float s3 = Sf[3][r] * 0.125f;
            if (diag) {
                const int qg = q0 + (w << 4) + (g << 2) + r;
                s0 = (k0 +  0 + col <= qg) ? s0 : -INFINITY;
                s1 = (k0 + 16 + col <= qg) ? s1 : -INFINITY;
                s2 = (k0 + 32 + col <= qg) ? s2 : -INFINITY;
                s3 = (k0 + 48 + col <= qg) ? s3 : -INFINITY;
            }
            float rm = fmaxf(fmaxf(s0, s1), fmaxf(s2, s3));
#pragma unroll
            for (int off = 1; off < 16; off <<= 1) rm = fmaxf(rm, __shfl_xor(rm, off));
            const float mn = fmaxf(m_[r], rm);
            const float scale = __expf(m_[r] - mn);
            const float p0 = __expf(s0 - mn);
            const float p1 = __expf(s1 - mn);
            const float p2 = __expf(s2 - mn);
            const float p3 = __expf(s3 - mn);
            float rs = (p0 + p1) + (p2 + p3);
#pragma unroll
            for (int off = 1; off < 16; off <<= 1) rs += __shfl_xor(rs, off);
            l_[r] = l_[r] * scale + rs;
            m_[r] = mn;
#pragma unroll
            for (int j = 0; j < 4; ++j) O[j][r] *= scale;
            const int prow = (w << 4) + (g << 2) + r;
            const int rsw = prow & 7;
            PsL[prow * 64 + (((0 + (col >> 3)) ^ rsw) << 3) + (col & 7)] = f2bf(p0);
            PsL[prow * 64 + (((2 + (col >> 3)) ^ rsw) << 3) + (col & 7)] = f2bf(p1);
            PsL[prow * 64 + (((4 + (col >> 3)) ^ rsw) << 3) + (col & 7)] = f2bf(p2);
            PsL[prow * 64 + (((6 + (col >> 3)) ^ rsw) << 3) + (col & 7)] = f2bf(p3);
        }

#pragma unroll
        for (int st = 0; st < 2; ++st) {
            const int prow = (w << 4) + col;
            const int po = prow * 64 + (((g + (st << 2)) ^ (prow & 7)) << 3);
            const bf16x8 pa = *reinterpret_cast<const bf16x8*>(&PsL[po]);
#pragma unroll
            for (int j = 0; j < 4; ++j) {
                const int vrow = (j << 4) + col;
                const int vo = vrow * 64 + (((g + (st << 2)) ^ (vrow & 7)) << 3);
                const bf16x8 vb0 = *reinterpret_cast<const bf16x8*>(&VtL[0][vo]);
                const bf16x8 vb1 = *reinterpret_cast<const bf16x8*>(&VtL[1][vo]);
                O[j] = mfma16(pa, vb0, O[j]);
                O[j] = mfma16(pa, vb1, O[j]);
            }
        }
    }

    const int b = bh >> 4, h = bh & (NH - 1);
#pragma unroll
    for (int r = 0; r < 4; ++r) {
        const int qg = q0 + (w << 4) + (g << 2) + r;
        const float inv = 1.f / l_[r];
        float* op = out + ((size_t)(b * S + qg)) * DOUT + h * DH;
#pragma unroll
        for (int j = 0; j < 4; ++j) op[(j << 4) + col] = O[j][r] * inv;
    }
}

// ===========================================================================
// FALLBACK TIER 3 (fp32 attention, ws >= 48 MB)
// ===========================================================================
__global__ __launch_bounds__(256) void attn_kernel(const float* __restrict__ Q,
                                                   const float* __restrict__ K,
                                                   const float* __restrict__ V,
                                                   float* __restrict__ out) {
    __shared__ float Qs[64][68];
    __shared__ float Ks[64][68];
    __shared__ float Vs[64][68];
    __shared__ float Ps[64][68];

    const int tid = threadIdx.x;
    const int bh = blockIdx.x & 31;
    const int qt = 31 - (blockIdx.x >> 5);
    const int q0 = qt << 6;
    const int tq = tid >> 4;
    const int tk = tid & 15;
    const int sr = tid >> 2;
    const int sc = (tid & 3) << 2;

    const float* qbase = Q + ((size_t)bh * S + q0) * DH;
    const float* kbase = K + (size_t)bh * S * DH;
    const float* vbase = V + (size_t)bh * S * DH;

#pragma unroll
    for (int it = 0; it < 4; ++it) {
        const int d0 = sc + (it << 4);
        const float4 v = *reinterpret_cast<const float4*>(&qbase[(size_t)sr * DH + d0]);
        Qs[d0 + 0][sr] = v.x; Qs[d0 + 1][sr] = v.y;
        Qs[d0 + 2][sr] = v.z; Qs[d0 + 3][sr] = v.w;
    }

    float C[4][4];
#pragma unroll
    for (int i = 0; i < 4; ++i)
#pragma unroll
        for (int j = 0; j < 4; ++j) C[i][j] = 0.f;
    float m[4] = {-1e30f, -1e30f, -1e30f, -1e30f};
    float l[4] = {0.f, 0.f, 0.f, 0.f};

    for (int kt = 0; kt <= qt; ++kt) {
        const int k0 = kt << 6;
        float4 kv[4], vv[4];
#pragma unroll
        for (int it = 0; it < 4; ++it) {
            const int d0 = sc + (it << 4);
            kv[it] = *reinterpret_cast<const float4*>(&kbase[(size_t)(k0 + sr) * DH + d0]);
            vv[it] = *reinterpret_cast<const float4*>(&vbase[(size_t)(k0 + sr) * DH + d0]);
        }
        __syncthreads();
#pragma unroll
        for (int it = 0; it < 4; ++it) {
            const int d0 = sc + (it << 4);
            Ks[d0 + 0][sr] = kv[it].x; Ks[d0 + 1][sr] = kv[it].y;
            Ks[d0 + 2][sr] = kv[it].z; Ks[d0 + 3][sr] = kv[it].w;
            *reinterpret_cast<float4*>(&Vs[sr][d0]) = vv[it];
        }
        __syncthreads();

        float s[4][4];
#pragma unroll
        for (int i = 0; i < 4; ++i)
#pragma unroll
            for (int j = 0; j < 4; ++j) s[i][j] = 0.f;
#pragma unroll 16
        for (int d = 0; d < 64; ++d) {
            const float4 qf = *reinterpret_cast<const float4*>(&Qs[d][tq << 2]);
            const float4 kf = *reinterpret_cast<const float4*>(&Ks[d][tk << 2]);
            const float qa[4] = {qf.x, qf.y, qf.z, qf.w};
            const float ka[4] = {kf.x, kf.y, kf.z, kf.w};
#pragma unroll
            for (int i = 0; i < 4; ++i)
#pragma unroll
                for (int j = 0; j < 4; ++j) s[i][j] += qa[i] * ka[j];
        }

        if (kt == qt) {
#pragma unroll
            for (int i = 0; i < 4; ++i) {
                const int qg = q0 + (tq << 2) + i;
#pragma unroll
                for (int j = 0; j < 4; ++j) {
                    const int kg = k0 + (tk << 2) + j;
                    s[i][j] = (kg <= qg) ? s[i][j] * 0.125f : -1e30f;
                }
            }
        } else {
#pragma unroll
            for (int i = 0; i < 4; ++i)
#pragma unroll
                for (int j = 0; j < 4; ++j) s[i][j] *= 0.125f;
        }

#pragma unroll
        for (int i = 0; i < 4; ++i) {
            float rm = fmaxf(fmaxf(s[i][0], s[i][1]), fmaxf(s[i][2], s[i][3]));
#pragma unroll
            for (int off = 1; off < 16; off <<= 1) rm = fmaxf(rm, __shfl_xor(rm, off));
            const float mn = fmaxf(m[i], rm);
            const float scale = __expf(m[i] - mn);
            float rs = 0.f;
#pragma unroll
            for (int j = 0; j < 4; ++j) {
                s[i][j] = __expf(s[i][j] - mn);
                rs += s[i][j];
            }
#pragma unroll
            for (int off = 1; off < 16; off <<= 1) rs += __shfl_xor(rs, off);
            l[i] = l[i] * scale + rs;
            m[i] = mn;
#pragma unroll
            for (int j = 0; j < 4; ++j) C[i][j] *= scale;
            *reinterpret_cast<float4*>(&Ps[(tq << 2) + i][tk << 2]) =
                make_float4(s[i][0], s[i][1], s[i][2], s[i][3]);
        }
        __syncthreads();

#pragma unroll 4
        for (int kc = 0; kc < 16; ++kc) {
            float4 pf[4], vf[4];
#pragma unroll
            for (int i = 0; i < 4; ++i)
                pf[i] = *reinterpret_cast<const float4*>(&Ps[(tq << 2) + i][kc << 2]);
#pragma unroll
            for (int j = 0; j < 4; ++j)
                vf[j] = *reinterpret_cast<const float4*>(&Vs[(kc << 2) + j][tk << 2]);
#pragma unroll
            for (int i = 0; i < 4; ++i) {
                const float pa[4] = {pf[i].x, pf[i].y, pf[i].z, pf[i].w};
#pragma unroll
                for (int j = 0; j < 4; ++j) {
                    C[i][j] += pa[0] * ((const float*)&vf[0])[j]
                             + pa[1] * ((const float*)&vf[1])[j]
                             + pa[2] * ((const float*)&vf[2])[j]
                             + pa[3] * ((const float*)&vf[3])[j];
                }
            }
        }
        __syncthreads();
    }

    const int b = bh >> 4, h = bh & (NH - 1);
#pragma unroll
    for (int i = 0; i < 4; ++i) {
        const int qg = q0 + (tq << 2) + i;
        const float inv = 1.f / l[i];
        float4 v;
        v.x = C[i][0] * inv; v.y = C[i][1] * inv;
        v.z = C[i][2] * inv; v.w = C[i][3] * inv;
        *reinterpret_cast<float4*>(&out[((size_t)(b * S + qg)) * DOUT + h * DH + (tk << 2)]) = v;
    }
}

// ===========================================================================
extern "C" void kernel_launch(void* const* d_in, const int* in_sizes, int n_in,
                              void* d_out, int out_size, void* d_ws, size_t ws_size,
                              hipStream_t stream) {
    const float* x  = (const float*)d_in[0];
    const float* Wq = (const float*)d_in[1];
    const float* Wk = (const float*)d_in[2];
    const float* Wv = (const float*)d_in[3];
    float* out = (float*)d_out;

    char* ws = (char*)d_ws;
    const size_t MB = 1024 * 1024;

    if (ws_size >= 84 * MB) {
        // layout: [0,16) Qf fp32 | [16,40) K 3-split | [40,56) V 2-split (pre-T)
        //         [56,80) x 3-split (reused: [56,72) VT 2-split) | [80,84) WT 2-split
        float*  qf   = (float*)(ws);
        ushort* ksp  = (ushort*)(ws + 16 * MB);
        ushort* vsp  = (ushort*)(ws + 40 * MB);
        ushort* xsp  = (ushort*)(ws + 56 * MB);
        ushort* vtsp = (ushort*)(ws + 56 * MB);   // overwrites x-splits (dead by then)
        ushort* wtsp = (ushort*)(ws + 80 * MB);

        split_x<<<4096, 256, 0, stream>>>(x, xsp);

        split_wT<<<dim3(16, 16), 256, 0, stream>>>(Wq, wtsp);
        proj_mfma<0><<<512, 256, 0, stream>>>(xsp, wtsp, qf, nullptr);
        split_wT<<<dim3(16, 16), 256, 0, stream>>>(Wk, wtsp);
        proj_mfma<1><<<512, 256, 0, stream>>>(xsp, wtsp, nullptr, ksp);
        split_wT<<<dim3(16, 16), 256, 0, stream>>>(Wv, wtsp);
        proj_mfma<2><<<512, 256, 0, stream>>>(xsp, wtsp, nullptr, vsp);

        transpose_v<<<1024, 256, 0, stream>>>(vsp, vtsp);
        attn_mfma2<<<1024, 256, 0, stream>>>(qf, ksp, vtsp, out);
    } else if (ws_size >= 56 * MB) {
        // round-3 path
        float*  qf  = (float*)(ws);
        ushort* ks0 = (ushort*)(ws + 16 * MB);
        ushort* ks1 = (ushort*)(ws + 24 * MB);
        ushort* ks2 = (ushort*)(ws + 32 * MB);
        ushort* vt0 = (ushort*)(ws + 40 * MB);
        ushort* vt1 = (ushort*)(ws + 48 * MB);

        dim3 pgrid(M_TOT / 64, DOUT / 64);
        proj_kernel<0><<<pgrid, 256, 0, stream>>>(x, Wq, qf, nullptr, nullptr, nullptr);
        proj_kernel<1><<<pgrid, 256, 0, stream>>>(x, Wk, nullptr, ks0, ks1, ks2);
        proj_kernel<2><<<pgrid, 256, 0, stream>>>(x, Wv, nullptr, vt0, vt1, nullptr);
        attn_mfma<<<32 * 32, 256, 0, stream>>>(qf, ks0, ks1, ks2, vt0, vt1, out);
    } else {
        // round-2 fp32 path
        float* qws = (float*)d_ws;
        float* kws = qws + (size_t)M_TOT * DOUT;
        float* vws = kws + (size_t)M_TOT * DOUT;

        dim3 pgrid(M_TOT / 64, DOUT / 64);
        proj_kernel<0><<<pgrid, 256, 0, stream>>>(x, Wq, qws, nullptr, nullptr, nullptr);
        proj_kernel<0><<<pgrid, 256, 0, stream>>>(x, Wk, kws, nullptr, nullptr, nullptr);
        proj_kernel<0><<<pgrid, 256, 0, stream>>>(x, Wv, vws, nullptr, nullptr, nullptr);
        attn_kernel<<<32 * 32, 256, 0, stream>>>(qws, kws, vws, out);
    }
}

// Round 5
// 268.332 us; speedup vs baseline: 15.2733x; 1.0462x over previous
//
#include <hip/hip_runtime.h>
#include <hip/hip_bf16.h>

// Problem constants: B=2, S=2048, D_IN=1024, D_OUT=1024, H=16, Dh=64
#define B 2
#define S 2048
#define DIN 1024
#define DOUT 1024
#define NH 16
#define DH 64
#define M_TOT (B * S)   // 4096

typedef __attribute__((ext_vector_type(8))) short bf16x8;
typedef __attribute__((ext_vector_type(8))) unsigned short u16x8;
typedef __attribute__((ext_vector_type(4))) float f32x4;

#define ASTRIDE 4194304   // elements per 4096x1024 split array
#define WSTRIDE 1048576   // elements per 1024x1024 split array

__device__ __forceinline__ ushort f2bf(float x) {
    union { float f; unsigned u; } c; c.f = x;
    unsigned r = (c.u + 0x7FFFu + ((c.u >> 16) & 1u)) >> 16;
    return (ushort)r;
}
__device__ __forceinline__ float bf2f(ushort h) {
    union { unsigned u; float f; } c; c.u = ((unsigned)h) << 16;
    return c.f;
}
__device__ __forceinline__ f32x4 mfma16(bf16x8 a, bf16x8 b, f32x4 c) {
    return __builtin_amdgcn_mfma_f32_16x16x32_bf16(a, b, c, 0, 0, 0);
}

// ===========================================================================
// MAIN PATH (ws >= 92 MB)
// ===========================================================================

// ---- prepass: x (fp32 [4096][1024]) -> 3-way bf16 splits ----
__global__ __launch_bounds__(256) void split_x(const float* __restrict__ x,
                                               ushort* __restrict__ xs) {
    const size_t gid = (size_t)blockIdx.x * 256 + threadIdx.x;
    const float4 v = *reinterpret_cast<const float4*>(x + gid * 4);
    const float in[4] = {v.x, v.y, v.z, v.w};
    ushort h0[4], h1[4], h2[4];
#pragma unroll
    for (int e = 0; e < 4; ++e) {
        h0[e] = f2bf(in[e]);
        const float r1 = in[e] - bf2f(h0[e]);
        h1[e] = f2bf(r1);
        h2[e] = f2bf(r1 - bf2f(h1[e]));
    }
    const size_t o = gid * 4;
    *reinterpret_cast<ushort4*>(xs + o)               = ushort4{h0[0], h0[1], h0[2], h0[3]};
    *reinterpret_cast<ushort4*>(xs + ASTRIDE + o)     = ushort4{h1[0], h1[1], h1[2], h1[3]};
    *reinterpret_cast<ushort4*>(xs + 2 * ASTRIDE + o) = ushort4{h2[0], h2[1], h2[2], h2[3]};
}

// ---- prepass: all three W -> W^T 2-way bf16 splits, wt[wi][sp][n][k] ----
__global__ __launch_bounds__(256) void split_wT3(const float* __restrict__ W0,
                                                 const float* __restrict__ W1,
                                                 const float* __restrict__ W2,
                                                 ushort* __restrict__ wt) {
    __shared__ float Ws[64][68];
    const int tid = threadIdx.x;
    const int k0 = blockIdx.x << 6;
    const int n0 = blockIdx.y << 6;
    const int wi = blockIdx.z;
    const float* W = (wi == 0) ? W0 : (wi == 1) ? W1 : W2;
    ushort* wto = wt + (size_t)wi * 2 * WSTRIDE;

    const int r = tid >> 2;
    const int cb = (tid & 3) << 2;
#pragma unroll
    for (int it = 0; it < 4; ++it) {
        const int c = cb + (it << 4);
        *reinterpret_cast<float4*>(&Ws[r][c]) =
            *reinterpret_cast<const float4*>(&W[(size_t)(k0 + r) * 1024 + n0 + c]);
    }
    __syncthreads();
    const int rn = tid >> 2;
    const int kc = (tid & 3) << 4;
    u16x8 o0[2], o1[2];
#pragma unroll
    for (int half = 0; half < 2; ++half)
#pragma unroll
        for (int i = 0; i < 8; ++i) {
            const float x = Ws[kc + (half << 3) + i][rn];
            const ushort a = f2bf(x);
            o0[half][i] = a;
            o1[half][i] = f2bf(x - bf2f(a));
        }
    const size_t base = (size_t)(n0 + rn) * 1024 + k0 + kc;
    *reinterpret_cast<u16x8*>(wto + base)               = o0[0];
    *reinterpret_cast<u16x8*>(wto + base + 8)           = o0[1];
    *reinterpret_cast<u16x8*>(wto + WSTRIDE + base)     = o1[0];
    *reinterpret_cast<u16x8*>(wto + WSTRIDE + base + 8) = o1[1];
}

// ---------------------------------------------------------------------------
// Fused QKV projection: one block computes the 64x64 (m,n) tile of Q, K, V.
// A (x 3-split) is read ONCE and multiplied against Wq/Wk/Wv tiles (2-split)
// with the 5-term product (a0b0+a1b0+a2b0+a0b1+a1b1) per output.
// LDS 72 KB: A 3x[64][64] + B 3Wx2spx[64][64], staged via global_load_lds,
// slot^(row&7) swizzle via pre-swizzled global source. 2 blocks/CU.
// Grid 1024 = 64 m-tiles x 16 n-tiles, n-major XCD chunks (A chunk ~3 MB L2).
// ---------------------------------------------------------------------------
__global__ __launch_bounds__(256, 2) void proj_fused(const ushort* __restrict__ xsp,
                                                     const ushort* __restrict__ wtsp,
                                                     float* __restrict__ qf,
                                                     ushort* __restrict__ ksp,
                                                     ushort* __restrict__ vsp) {
    __shared__ __align__(16) ushort SL[36864];   // 72 KB

    const int tid = threadIdx.x;
    const int lane = tid & 63;
    const int w = tid >> 6;
    const int swz = (blockIdx.x & 7) * 128 + (blockIdx.x >> 3);
    const int n0 = (swz & 15) << 6;
    const int m0 = (swz >> 4) << 6;
    const int col = lane & 15;
    const int glane = lane >> 4;
    const int lrow = lane >> 3;
    const int sl8 = ((lane & 7) ^ lrow) << 3;

    f32x4 acc[3][4];   // [W][nj]
#pragma unroll
    for (int wi = 0; wi < 3; ++wi)
#pragma unroll
        for (int nj = 0; nj < 4; ++nj) acc[wi][nj] = f32x4{0.f, 0.f, 0.f, 0.f};

    for (int k0 = 0; k0 < DIN; k0 += 64) {
        __syncthreads();   // previous step's LDS reads done
#pragma unroll
        for (int i = 0; i < 18; ++i) {
            const int u = (i << 2) | w;          // 0..71
            const ushort* g;
            if (u < 24) {
                const int sp = u >> 3, rb = u & 7;
                g = xsp + (size_t)sp * ASTRIDE + (size_t)(m0 + (rb << 3) + lrow) * 1024 + k0 + sl8;
            } else {
                const int v = u - 24;            // 0..47
                const int wi = v >> 4;
                const int sp = (v >> 3) & 1;
                const int rb = v & 7;
                g = wtsp + ((size_t)wi * 2 + sp) * WSTRIDE + (size_t)(n0 + (rb << 3) + lrow) * 1024 + k0 + sl8;
            }
            __builtin_amdgcn_global_load_lds(g, &SL[u * 512], 16, 0, 0);
        }
        __syncthreads();   // staging drained + visible

#pragma unroll
        for (int st = 0; st < 2; ++st) {
            const int arow = (w << 4) + col;
            const int ao = arow * 64 + (((glane + (st << 2)) ^ (col & 7)) << 3);
            const bf16x8 a0 = *reinterpret_cast<const bf16x8*>(&SL[ao]);
            const bf16x8 a1 = *reinterpret_cast<const bf16x8*>(&SL[4096 + ao]);
            const bf16x8 a2 = *reinterpret_cast<const bf16x8*>(&SL[8192 + ao]);
#pragma unroll
            for (int wi = 0; wi < 3; ++wi)
#pragma unroll
                for (int nj = 0; nj < 4; ++nj) {
                    const int brow = (nj << 4) + col;
                    const int bo = 12288 + wi * 8192 + brow * 64 + (((glane + (st << 2)) ^ (col & 7)) << 3);
                    const bf16x8 b0 = *reinterpret_cast<const bf16x8*>(&SL[bo]);
                    const bf16x8 b1 = *reinterpret_cast<const bf16x8*>(&SL[bo + 4096]);
                    acc[wi][nj] = mfma16(a0, b0, acc[wi][nj]);
                    acc[wi][nj] = mfma16(a1, b0, acc[wi][nj]);
                    acc[wi][nj] = mfma16(a0, b1, acc[wi][nj]);
                    acc[wi][nj] = mfma16(a1, b1, acc[wi][nj]);
                    acc[wi][nj] = mfma16(a2, b0, acc[wi][nj]);
                }
        }
    }

    // epilogue: [bh][s][d]; Q fp32, K 3-split, V 2-split
    const int b = m0 >> 11;
    const int h = n0 >> 6;
    const size_t bh_off = (size_t)(b * NH + h) * S * DH;
#pragma unroll
    for (int r = 0; r < 4; ++r) {
        const int srow = (m0 & (S - 1)) + (w << 4) + (glane << 2) + r;
#pragma unroll
        for (int nj = 0; nj < 4; ++nj) {
            const size_t o = bh_off + (size_t)srow * DH + (nj << 4) + col;
            qf[o] = acc[0][nj][r];
            const float xk = acc[1][nj][r];
            const ushort k0s = f2bf(xk);
            const float kr1 = xk - bf2f(k0s);
            const ushort k1s = f2bf(kr1);
            ksp[o] = k0s;
            ksp[ASTRIDE + o] = k1s;
            ksp[2 * ASTRIDE + o] = f2bf(kr1 - bf2f(k1s));
            const float xv = acc[2][nj][r];
            const ushort v0s = f2bf(xv);
            vsp[o] = v0s;
            vsp[ASTRIDE + o] = f2bf(xv - bf2f(v0s));
        }
    }
}

// ---- V transpose: 2-split [bh][s][64] -> 2-split [bh][64][s] ----
__global__ __launch_bounds__(256) void transpose_v(const ushort* __restrict__ v,
                                                   ushort* __restrict__ vt) {
    __shared__ ushort Ts[2][64][72];
    const int tid = threadIdx.x;
    const int bh = blockIdx.x & 31;
    const int s0 = (blockIdx.x >> 5) << 6;
    const int r = tid >> 2;
    const int c16 = (tid & 3) << 4;
#pragma unroll
    for (int sp = 0; sp < 2; ++sp)
#pragma unroll
        for (int e = 0; e < 2; ++e) {
            *reinterpret_cast<u16x8*>(&Ts[sp][r][c16 + (e << 3)]) =
                *reinterpret_cast<const u16x8*>(
                    &v[(size_t)sp * ASTRIDE + ((size_t)bh * S + s0 + r) * DH + c16 + (e << 3)]);
        }
    __syncthreads();
    const int dr = tid >> 2;
    const int sc = (tid & 3) << 4;
#pragma unroll
    for (int sp = 0; sp < 2; ++sp) {
        u16x8 o0, o1;
#pragma unroll
        for (int i = 0; i < 8; ++i) {
            o0[i] = Ts[sp][sc + i][dr];
            o1[i] = Ts[sp][sc + 8 + i][dr];
        }
        const size_t base = (size_t)sp * ASTRIDE + ((size_t)bh * DH + dr) * S + s0 + sc;
        *reinterpret_cast<u16x8*>(vt + base) = o0;
        *reinterpret_cast<u16x8*>(vt + base + 8) = o1;
    }
}

// ---------------------------------------------------------------------------
// MFMA flash attention v3: split-barrier software pipeline.
// Per tile: QK -> barrierA (drains V(t) loads, K region free) -> issue
// K-stage(t+1) -> softmax (skip-rescale) -> PV -> barrierB (drains K(t+1),
// V region free) -> issue V-stage(t+1). Stage latency hides under compute.
// Math identical to round 4 (Q 3-split w/ 1/8 folded, K 3-split, 6-term QK;
// P bf16; V 2-split pre-transposed). LDS 48 KB -> 3 blocks/CU.
// ---------------------------------------------------------------------------
__global__ __launch_bounds__(256, 3) void attn_mfma3(const float* __restrict__ Qf,
                                                     const ushort* __restrict__ ksp,
                                                     const ushort* __restrict__ vtsp,
                                                     float* __restrict__ out) {
    __shared__ __align__(16) ushort KL[3 * 4096];   // 24 KB
    __shared__ __align__(16) ushort VL[2 * 4096];   // 16 KB
    __shared__ __align__(16) ushort PL[4096];       //  8 KB

    const int tid = threadIdx.x;
    const int lane = tid & 63;
    const int w = tid >> 6;
    const int swz = (blockIdx.x & 7) * 128 + (blockIdx.x >> 3);
    const int bh = swz >> 5;
    const int qt = 31 - (swz & 31);        // big q-tiles first
    const int q0 = qt << 6;
    const int col = lane & 15;
    const int g = lane >> 4;
    const int lrow = lane >> 3;
    const int sl8 = ((lane & 7) ^ lrow) << 3;

    // ---- Q fragments: 1/8 scale folded in, 3 splits x 2 k-steps ----
    bf16x8 qfrag[3][2];
    {
        const int qrow = q0 + (w << 4) + col;
        const float* qp = Qf + ((size_t)bh * S + qrow) * DH + (g << 3);
#pragma unroll
        for (int st = 0; st < 2; ++st) {
            const float4 f0 = *reinterpret_cast<const float4*>(qp + 32 * st);
            const float4 f1 = *reinterpret_cast<const float4*>(qp + 32 * st + 4);
            const float xs[8] = {f0.x, f0.y, f0.z, f0.w, f1.x, f1.y, f1.z, f1.w};
#pragma unroll
            for (int e = 0; e < 8; ++e) {
                const float x = xs[e] * 0.125f;
                const ushort h0 = f2bf(x);
                const float r1 = x - bf2f(h0);
                const ushort h1 = f2bf(r1);
                qfrag[0][st][e] = (short)h0;
                qfrag[1][st][e] = (short)h1;
                qfrag[2][st][e] = (short)f2bf(r1 - bf2f(h1));
            }
        }
    }

    f32x4 O[4];
#pragma unroll
    for (int j = 0; j < 4; ++j) O[j] = f32x4{0.f, 0.f, 0.f, 0.f};
    float m_[4] = {-INFINITY, -INFINITY, -INFINITY, -INFINITY};
    float l_[4] = {0.f, 0.f, 0.f, 0.f};

    const size_t kbase = (size_t)bh * S * DH;
    const size_t vbase = (size_t)bh * DH * S;

#define ISSUE_K(K0)                                                                     \
    {                                                                                   \
        _Pragma("unroll")                                                               \
        for (int i = 0; i < 6; ++i) {                                                   \
            const int u = (i << 2) | w;                                                 \
            const int sp = u >> 3, rb = u & 7;                                          \
            const ushort* gp = ksp + (size_t)sp * ASTRIDE +                             \
                               (kbase + (size_t)((K0) + (rb << 3) + lrow) * DH) + sl8;  \
            __builtin_amdgcn_global_load_lds(gp, &KL[u * 512], 16, 0, 0);               \
        }                                                                               \
    }
#define ISSUE_V(K0)                                                                     \
    {                                                                                   \
        _Pragma("unroll")                                                               \
        for (int i = 0; i < 4; ++i) {                                                   \
            const int u = (i << 2) | w;                                                 \
            const int sp = u >> 3, rb = u & 7;                                          \
            const ushort* gp = vtsp + (size_t)sp * ASTRIDE +                            \
                               (vbase + (size_t)((rb << 3) + lrow) * S) + (K0) + sl8;   \
            __builtin_amdgcn_global_load_lds(gp, &VL[u * 512], 16, 0, 0);               \
        }                                                                               \
    }

    ISSUE_K(0);
    ISSUE_V(0);
    __syncthreads();

    for (int kt = 0; kt <= qt; ++kt) {
        const int k0 = kt << 6;

        // ---- S = Q K^T : 16q x 64k strip per wave (6 split terms) ----
        f32x4 Sf[4];
#pragma unroll
        for (int j = 0; j < 4; ++j) Sf[j] = f32x4{0.f, 0.f, 0.f, 0.f};
#pragma unroll
        for (int st = 0; st < 2; ++st) {
#pragma unroll
            for (int j = 0; j < 4; ++j) {
                const int krow = (j << 4) + col;
                const int eo = krow * 64 + (((g + (st << 2)) ^ (krow & 7)) << 3);
                const bf16x8 kb0 = *reinterpret_cast<const bf16x8*>(&KL[eo]);
                const bf16x8 kb1 = *reinterpret_cast<const bf16x8*>(&KL[4096 + eo]);
                const bf16x8 kb2 = *reinterpret_cast<const bf16x8*>(&KL[8192 + eo]);
                Sf[j] = mfma16(qfrag[0][st], kb0, Sf[j]);
                Sf[j] = mfma16(qfrag[0][st], kb1, Sf[j]);
                Sf[j] = mfma16(qfrag[1][st], kb0, Sf[j]);
                Sf[j] = mfma16(qfrag[1][st], kb1, Sf[j]);
                Sf[j] = mfma16(qfrag[0][st], kb2, Sf[j]);
                Sf[j] = mfma16(qfrag[2][st], kb0, Sf[j]);
            }
        }

        __syncthreads();            // A: all waves done with K; V(kt) drained
        if (kt < qt) ISSUE_K(k0 + 64);

        // ---- online softmax (rows = 4g+r within wave strip) ----
        const bool diag = (kt == qt);
#pragma unroll
        for (int r = 0; r < 4; ++r) {
            float s0 = Sf[0][r], s1 = Sf[1][r], s2 = Sf[2][r], s3 = Sf[3][r];
            if (diag) {
                const int qg = q0 + (w << 4) + (g << 2) + r;
                s0 = (k0 +  0 + col <= qg) ? s0 : -INFINITY;
                s1 = (k0 + 16 + col <= qg) ? s1 : -INFINITY;
                s2 = (k0 + 32 + col <= qg) ? s2 : -INFINITY;
                s3 = (k0 + 48 + col <= qg) ? s3 : -INFINITY;
            }
            float rm = fmaxf(fmaxf(s0, s1), fmaxf(s2, s3));
#pragma unroll
            for (int off = 1; off < 16; off <<= 1) rm = fmaxf(rm, __shfl_xor(rm, off));
            if (rm > m_[r]) {       // rescale only when the max actually grows
                const float scale = __expf(m_[r] - rm);
                m_[r] = rm;
                l_[r] *= scale;
                O[0][r] *= scale; O[1][r] *= scale; O[2][r] *= scale; O[3][r] *= scale;
            }
            const float mn = m_[r];
            const float p0 = __expf(s0 - mn);
            const float p1 = __expf(s1 - mn);
            const float p2 = __expf(s2 - mn);
            const float p3 = __expf(s3 - mn);
            float rs = (p0 + p1) + (p2 + p3);
#pragma unroll
            for (int off = 1; off < 16; off <<= 1) rs += __shfl_xor(rs, off);
            l_[r] += rs;

            const int prow = (w << 4) + (g << 2) + r;
            const int rsw = prow & 7;
            PL[prow * 64 + (((0 + (col >> 3)) ^ rsw) << 3) + (col & 7)] = f2bf(p0);
            PL[prow * 64 + (((2 + (col >> 3)) ^ rsw) << 3) + (col & 7)] = f2bf(p1);
            PL[prow * 64 + (((4 + (col >> 3)) ^ rsw) << 3) + (col & 7)] = f2bf(p2);
            PL[prow * 64 + (((6 + (col >> 3)) ^ rsw) << 3) + (col & 7)] = f2bf(p3);
        }

        // ---- O += P V (wave-private P; no barrier needed) ----
#pragma unroll
        for (int st = 0; st < 2; ++st) {
            const int prow = (w << 4) + col;
            const int po = prow * 64 + (((g + (st << 2)) ^ (prow & 7)) << 3);
            const bf16x8 pa = *reinterpret_cast<const bf16x8*>(&PL[po]);
#pragma unroll
            for (int j = 0; j < 4; ++j) {
                const int vrow = (j << 4) + col;
                const int vo = vrow * 64 + (((g + (st << 2)) ^ (vrow & 7)) << 3);
                const bf16x8 vb0 = *reinterpret_cast<const bf16x8*>(&VL[vo]);
                const bf16x8 vb1 = *reinterpret_cast<const bf16x8*>(&VL[4096 + vo]);
                O[j] = mfma16(pa, vb0, O[j]);
                O[j] = mfma16(pa, vb1, O[j]);
            }
        }

        __syncthreads();            // B: all waves done with V; K(kt+1) drained
        if (kt < qt) ISSUE_V(k0 + 64);
    }

    // ---- epilogue ----
    const int b = bh >> 4, h = bh & (NH - 1);
#pragma unroll
    for (int r = 0; r < 4; ++r) {
        const int qg = q0 + (w << 4) + (g << 2) + r;
        const float inv = 1.f / l_[r];
        float* op = out + ((size_t)(b * S + qg)) * DOUT + h * DH;
#pragma unroll
        for (int j = 0; j < 4; ++j) op[(j << 4) + col] = O[j][r] * inv;
    }
#undef ISSUE_K
#undef ISSUE_V
}

// ===========================================================================
// FALLBACK (fp32, ws >= 48 MB)
// ===========================================================================
__global__ __launch_bounds__(256) void proj_f32(const float* __restrict__ A,
                                                const float* __restrict__ W,
                                                float* __restrict__ outf) {
    __shared__ float As[16][68];
    __shared__ float Bs[16][68];
    const int tid = threadIdx.x;
    const int m0 = blockIdx.x * 64;
    const int n0 = blockIdx.y * 64;
    const int tm = tid >> 4, tn = tid & 15;
    const int la_r = tid >> 2, la_c = (tid & 3) << 2;
    const int lb_r = tid >> 4, lb_c = (tid & 15) << 2;

    float acc[4][4];
#pragma unroll
    for (int i = 0; i < 4; ++i)
#pragma unroll
        for (int j = 0; j < 4; ++j) acc[i][j] = 0.f;

    for (int k0 = 0; k0 < DIN; k0 += 16) {
        const float4 av = *reinterpret_cast<const float4*>(&A[(size_t)(m0 + la_r) * DIN + k0 + la_c]);
        const float4 bv = *reinterpret_cast<const float4*>(&W[(size_t)(k0 + lb_r) * DOUT + n0 + lb_c]);
        __syncthreads();
        As[la_c + 0][la_r] = av.x; As[la_c + 1][la_r] = av.y;
        As[la_c + 2][la_r] = av.z; As[la_c + 3][la_r] = av.w;
        *reinterpret_cast<float4*>(&Bs[lb_r][lb_c]) = bv;
        __syncthreads();
#pragma unroll
        for (int kk = 0; kk < 16; ++kk) {
            const float4 a = *reinterpret_cast<const float4*>(&As[kk][tm << 2]);
            const float4 b = *reinterpret_cast<const float4*>(&Bs[kk][tn << 2]);
            const float aa[4] = {a.x, a.y, a.z, a.w};
            const float bb[4] = {b.x, b.y, b.z, b.w};
#pragma unroll
            for (int i = 0; i < 4; ++i)
#pragma unroll
                for (int j = 0; j < 4; ++j) acc[i][j] += aa[i] * bb[j];
        }
    }
    const int b = m0 >> 11;
    const int s_base = (m0 & (S - 1)) + (tm << 2);
    const int h = n0 >> 6;
    const int dh = tn << 2;
    float* obase = outf + ((size_t)(b * NH + h) * S) * DH;
#pragma unroll
    for (int i = 0; i < 4; ++i) {
        float4 v;
        v.x = acc[i][0]; v.y = acc[i][1]; v.z = acc[i][2]; v.w = acc[i][3];
        *reinterpret_cast<float4*>(&obase[(size_t)(s_base + i) * DH + dh]) = v;
    }
}

__global__ __launch_bounds__(256) void attn_f32(const float* __restrict__ Q,
                                                const float* __restrict__ K,
                                                const float* __restrict__ V,
                                                float* __restrict__ out) {
    __shared__ float Qs[64][68];
    __shared__ float Ks[64][68];
    __shared__ float Vs[64][68];
    __shared__ float Ps[64][68];
    const int tid = threadIdx.x;
    const int bh = blockIdx.x & 31;
    const int qt = 31 - (blockIdx.x >> 5);
    const int q0 = qt << 6;
    const int tq = tid >> 4, tk = tid & 15;
    const int sr = tid >> 2, sc = (tid & 3) << 2;

    const float* qbase = Q + ((size_t)bh * S + q0) * DH;
    const float* kbase = K + (size_t)bh * S * DH;
    const float* vbase = V + (size_t)bh * S * DH;
#pragma unroll
    for (int it = 0; it < 4; ++it) {
        const int d0 = sc + (it << 4);
        const float4 v = *reinterpret_cast<const float4*>(&qbase[(size_t)sr * DH + d0]);
        Qs[d0 + 0][sr] = v.x; Qs[d0 + 1][sr] = v.y;
        Qs[d0 + 2][sr] = v.z; Qs[d0 + 3][sr] = v.w;
    }
    float C[4][4];
#pragma unroll
    for (int i = 0; i < 4; ++i)
#pragma unroll
        for (int j = 0; j < 4; ++j) C[i][j] = 0.f;
    float m[4] = {-1e30f, -1e30f, -1e30f, -1e30f};
    float l[4] = {0.f, 0.f, 0.f, 0.f};

    for (int kt = 0; kt <= qt; ++kt) {
        const int k0 = kt << 6;
        float4 kv[4], vv[4];
#pragma unroll
        for (int it = 0; it < 4; ++it) {
            const int d0 = sc + (it << 4);
            kv[it] = *reinterpret_cast<const float4*>(&kbase[(size_t)(k0 + sr) * DH + d0]);
            vv[it] = *reinterpret_cast<const float4*>(&vbase[(size_t)(k0 + sr) * DH + d0]);
        }
        __syncthreads();
#pragma unroll
        for (int it = 0; it < 4; ++it) {
            const int d0 = sc + (it << 4);
            Ks[d0 + 0][sr] = kv[it].x; Ks[d0 + 1][sr] = kv[it].y;
            Ks[d0 + 2][sr] = kv[it].z; Ks[d0 + 3][sr] = kv[it].w;
            *reinterpret_cast<float4*>(&Vs[sr][d0]) = vv[it];
        }
        __syncthreads();

        float s[4][4];
#pragma unroll
        for (int i = 0; i < 4; ++i)
#pragma unroll
            for (int j = 0; j < 4; ++j) s[i][j] = 0.f;
#pragma unroll 16
        for (int d = 0; d < 64; ++d) {
            const float4 qf4 = *reinterpret_cast<const float4*>(&Qs[d][tq << 2]);
            const float4 kf4 = *reinterpret_cast<const float4*>(&Ks[d][tk << 2]);
            const float qa[4] = {qf4.x, qf4.y, qf4.z, qf4.w};
            const float ka[4] = {kf4.x, kf4.y, kf4.z, kf4.w};
#pragma unroll
            for (int i = 0; i < 4; ++i)
#pragma unroll
                for (int j = 0; j < 4; ++j) s[i][j] += qa[i] * ka[j];
        }
        if (kt == qt) {
#pragma unroll
            for (int i = 0; i < 4; ++i) {
                const int qg = q0 + (tq << 2) + i;
#pragma unroll
                for (int j = 0; j < 4; ++j) {
                    const int kg = k0 + (tk << 2) + j;
                    s[i][j] = (kg <= qg) ? s[i][j] * 0.125f : -1e30f;
                }
            }
        } else {
#pragma unroll
            for (int i = 0; i < 4; ++i)
#pragma unroll
                for (int j = 0; j < 4; ++j) s[i][j] *= 0.125f;
        }
#pragma unroll
        for (int i = 0; i < 4; ++i) {
            float rm = fmaxf(fmaxf(s[i][0], s[i][1]), fmaxf(s[i][2], s[i][3]));
#pragma unroll
            for (int off = 1; off < 16; off <<= 1) rm = fmaxf(rm, __shfl_xor(rm, off));
            const float mn = fmaxf(m[i], rm);
            const float scale = __expf(m[i] - mn);
            float rs = 0.f;
#pragma unroll
            for (int j = 0; j < 4; ++j) {
                s[i][j] = __expf(s[i][j] - mn);
                rs += s[i][j];
            }
#pragma unroll
            for (int off = 1; off < 16; off <<= 1) rs += __shfl_xor(rs, off);
            l[i] = l[i] * scale + rs;
            m[i] = mn;
#pragma unroll
            for (int j = 0; j < 4; ++j) C[i][j] *= scale;
            *reinterpret_cast<float4*>(&Ps[(tq << 2) + i][tk << 2]) =
                make_float4(s[i][0], s[i][1], s[i][2], s[i][3]);
        }
        __syncthreads();
#pragma unroll 4
        for (int kc = 0; kc < 16; ++kc) {
            float4 pf[4], vf[4];
#pragma unroll
            for (int i = 0; i < 4; ++i)
                pf[i] = *reinterpret_cast<const float4*>(&Ps[(tq << 2) + i][kc << 2]);
#pragma unroll
            for (int j = 0; j < 4; ++j)
                vf[j] = *reinterpret_cast<const float4*>(&Vs[(kc << 2) + j][tk << 2]);
#pragma unroll
            for (int i = 0; i < 4; ++i) {
                const float pa[4] = {pf[i].x, pf[i].y, pf[i].z, pf[i].w};
#pragma unroll
                for (int j = 0; j < 4; ++j) {
                    C[i][j] += pa[0] * ((const float*)&vf[0])[j]
                             + pa[1] * ((const float*)&vf[1])[j]
                             + pa[2] * ((const float*)&vf[2])[j]
                             + pa[3] * ((const float*)&vf[3])[j];
                }
            }
        }
        __syncthreads();
    }
    const int b = bh >> 4, h = bh & (NH - 1);
#pragma unroll
    for (int i = 0; i < 4; ++i) {
        const int qg = q0 + (tq << 2) + i;
        const float inv = 1.f / l[i];
        float4 v;
        v.x = C[i][0] * inv; v.y = C[i][1] * inv;
        v.z = C[i][2] * inv; v.w = C[i][3] * inv;
        *reinterpret_cast<float4*>(&out[((size_t)(b * S + qg)) * DOUT + h * DH + (tk << 2)]) = v;
    }
}

// ===========================================================================
extern "C" void kernel_launch(void* const* d_in, const int* in_sizes, int n_in,
                              void* d_out, int out_size, void* d_ws, size_t ws_size,
                              hipStream_t stream) {
    const float* x  = (const float*)d_in[0];
    const float* Wq = (const float*)d_in[1];
    const float* Wk = (const float*)d_in[2];
    const float* Wv = (const float*)d_in[3];
    float* out = (float*)d_out;

    char* ws = (char*)d_ws;
    const size_t MB = 1024 * 1024;

    if (ws_size >= 92 * MB) {
        // layout: wT[0,12) | xsp[12,36) (later reused as VT[12,28)) |
        //         Q[36,52) | K 3-split[52,76) | Vtmp[76,92)
        ushort* wtsp = (ushort*)(ws);
        ushort* xsp  = (ushort*)(ws + 12 * MB);
        float*  qf   = (float*)(ws + 36 * MB);
        ushort* ksp  = (ushort*)(ws + 52 * MB);
        ushort* vsp  = (ushort*)(ws + 76 * MB);
        ushort* vtsp = (ushort*)(ws + 12 * MB);   // overwrites xsp (dead after proj)

        split_x<<<4096, 256, 0, stream>>>(x, xsp);
        split_wT3<<<dim3(16, 16, 3), 256, 0, stream>>>(Wq, Wk, Wv, wtsp);
        proj_fused<<<1024, 256, 0, stream>>>(xsp, wtsp, qf, ksp, vsp);
        transpose_v<<<1024, 256, 0, stream>>>(vsp, vtsp);
        attn_mfma3<<<1024, 256, 0, stream>>>(qf, ksp, vtsp, out);
    } else {
        // fp32 fallback (48 MB)
        float* qws = (float*)d_ws;
        float* kws = qws + (size_t)M_TOT * DOUT;
        float* vws = kws + (size_t)M_TOT * DOUT;
        dim3 pgrid(M_TOT / 64, DOUT / 64);
        proj_f32<<<pgrid, 256, 0, stream>>>(x, Wq, qws);
        proj_f32<<<pgrid, 256, 0, stream>>>(x, Wk, kws);
        proj_f32<<<pgrid, 256, 0, stream>>>(x, Wv, vws);
        attn_f32<<<32 * 32, 256, 0, stream>>>(qws, kws, vws, out);
    }
}

// Round 7
// 235.512 us; speedup vs baseline: 17.4016x; 1.1394x over previous
//
#include <hip/hip_runtime.h>
#include <hip/hip_bf16.h>

// Problem constants: B=2, S=2048, D_IN=1024, D_OUT=1024, H=16, Dh=64
#define B 2
#define S 2048
#define DIN 1024
#define DOUT 1024
#define NH 16
#define DH 64
#define M_TOT (B * S)   // 4096

typedef __attribute__((ext_vector_type(8))) short bf16x8;
typedef __attribute__((ext_vector_type(8))) unsigned short u16x8;
typedef __attribute__((ext_vector_type(4))) float f32x4;
typedef __attribute__((ext_vector_type(16))) float f32x16;

#define ASTRIDE 4194304   // elements per 4096x1024 split array
#define WSTRIDE 1048576   // elements per 1024x1024 split array

__device__ __forceinline__ ushort f2bf(float x) {
    union { float f; unsigned u; } c; c.f = x;
    unsigned r = (c.u + 0x7FFFu + ((c.u >> 16) & 1u)) >> 16;
    return (ushort)r;
}
__device__ __forceinline__ float bf2f(ushort h) {
    union { unsigned u; float f; } c; c.u = ((unsigned)h) << 16;
    return c.f;
}
__device__ __forceinline__ f32x4 mfma16(bf16x8 a, bf16x8 b, f32x4 c) {
    return __builtin_amdgcn_mfma_f32_16x16x32_bf16(a, b, c, 0, 0, 0);
}
__device__ __forceinline__ f32x16 mfma32(bf16x8 a, bf16x8 b, f32x16 c) {
    return __builtin_amdgcn_mfma_f32_32x32x16_bf16(a, b, c, 0, 0, 0);
}
__device__ __forceinline__ unsigned cvt_pk(float lo, float hi) {
    unsigned r;
    asm("v_cvt_pk_bf16_f32 %0, %1, %2" : "=v"(r) : "v"(lo), "v"(hi));
    return r;
}
__device__ __forceinline__ float exp2fast(float x) {
    float r;
    asm("v_exp_f32 %0, %1" : "=v"(r) : "v"(x));
    return r;
}

// ===========================================================================
// MAIN PATH (ws >= 92 MB)
// ===========================================================================

// ---- prepass: x (fp32 [4096][1024]) -> 3-way bf16 splits ----
__global__ __launch_bounds__(256) void split_x(const float* __restrict__ x,
                                               ushort* __restrict__ xs) {
    const size_t gid = (size_t)blockIdx.x * 256 + threadIdx.x;
    const float4 v = *reinterpret_cast<const float4*>(x + gid * 4);
    const float in[4] = {v.x, v.y, v.z, v.w};
    ushort h0[4], h1[4], h2[4];
#pragma unroll
    for (int e = 0; e < 4; ++e) {
        h0[e] = f2bf(in[e]);
        const float r1 = in[e] - bf2f(h0[e]);
        h1[e] = f2bf(r1);
        h2[e] = f2bf(r1 - bf2f(h1[e]));
    }
    const size_t o = gid * 4;
    *reinterpret_cast<ushort4*>(xs + o)               = ushort4{h0[0], h0[1], h0[2], h0[3]};
    *reinterpret_cast<ushort4*>(xs + ASTRIDE + o)     = ushort4{h1[0], h1[1], h1[2], h1[3]};
    *reinterpret_cast<ushort4*>(xs + 2 * ASTRIDE + o) = ushort4{h2[0], h2[1], h2[2], h2[3]};
}

// ---- prepass: all three W -> W^T 2-way bf16 splits, wt[wi][sp][n][k] ----
__global__ __launch_bounds__(256) void split_wT3(const float* __restrict__ W0,
                                                 const float* __restrict__ W1,
                                                 const float* __restrict__ W2,
                                                 ushort* __restrict__ wt) {
    __shared__ float Ws[64][68];
    const int tid = threadIdx.x;
    const int k0 = blockIdx.x << 6;
    const int n0 = blockIdx.y << 6;
    const int wi = blockIdx.z;
    const float* W = (wi == 0) ? W0 : (wi == 1) ? W1 : W2;
    ushort* wto = wt + (size_t)wi * 2 * WSTRIDE;

    const int r = tid >> 2;
    const int cb = (tid & 3) << 2;
#pragma unroll
    for (int it = 0; it < 4; ++it) {
        const int c = cb + (it << 4);
        *reinterpret_cast<float4*>(&Ws[r][c]) =
            *reinterpret_cast<const float4*>(&W[(size_t)(k0 + r) * 1024 + n0 + c]);
    }
    __syncthreads();
    const int rn = tid >> 2;
    const int kc = (tid & 3) << 4;
    u16x8 o0[2], o1[2];
#pragma unroll
    for (int half = 0; half < 2; ++half)
#pragma unroll
        for (int i = 0; i < 8; ++i) {
            const float x = Ws[kc + (half << 3) + i][rn];
            const ushort a = f2bf(x);
            o0[half][i] = a;
            o1[half][i] = f2bf(x - bf2f(a));
        }
    const size_t base = (size_t)(n0 + rn) * 1024 + k0 + kc;
    *reinterpret_cast<u16x8*>(wto + base)               = o0[0];
    *reinterpret_cast<u16x8*>(wto + base + 8)           = o0[1];
    *reinterpret_cast<u16x8*>(wto + WSTRIDE + base)     = o1[0];
    *reinterpret_cast<u16x8*>(wto + WSTRIDE + base + 8) = o1[1];
}

// ---------------------------------------------------------------------------
// Fused QKV projection (unchanged, verified round 5): 64x64 tile of Q,K,V per
// block, 5-term split product, A read once. LDS 72 KB, global_load_lds staging.
// ---------------------------------------------------------------------------
__global__ __launch_bounds__(256, 2) void proj_fused(const ushort* __restrict__ xsp,
                                                     const ushort* __restrict__ wtsp,
                                                     float* __restrict__ qf,
                                                     ushort* __restrict__ ksp,
                                                     ushort* __restrict__ vsp) {
    __shared__ __align__(16) ushort SL[36864];   // 72 KB

    const int tid = threadIdx.x;
    const int lane = tid & 63;
    const int w = tid >> 6;
    const int swz = (blockIdx.x & 7) * 128 + (blockIdx.x >> 3);
    const int n0 = (swz & 15) << 6;
    const int m0 = (swz >> 4) << 6;
    const int col = lane & 15;
    const int glane = lane >> 4;
    const int lrow = lane >> 3;
    const int sl8 = ((lane & 7) ^ lrow) << 3;

    f32x4 acc[3][4];   // [W][nj]
#pragma unroll
    for (int wi = 0; wi < 3; ++wi)
#pragma unroll
        for (int nj = 0; nj < 4; ++nj) acc[wi][nj] = f32x4{0.f, 0.f, 0.f, 0.f};

    for (int k0 = 0; k0 < DIN; k0 += 64) {
        __syncthreads();
#pragma unroll
        for (int i = 0; i < 18; ++i) {
            const int u = (i << 2) | w;          // 0..71
            const ushort* g;
            if (u < 24) {
                const int sp = u >> 3, rb = u & 7;
                g = xsp + (size_t)sp * ASTRIDE + (size_t)(m0 + (rb << 3) + lrow) * 1024 + k0 + sl8;
            } else {
                const int v = u - 24;
                const int wi = v >> 4;
                const int sp = (v >> 3) & 1;
                const int rb = v & 7;
                g = wtsp + ((size_t)wi * 2 + sp) * WSTRIDE + (size_t)(n0 + (rb << 3) + lrow) * 1024 + k0 + sl8;
            }
            __builtin_amdgcn_global_load_lds(g, &SL[u * 512], 16, 0, 0);
        }
        __syncthreads();

#pragma unroll
        for (int st = 0; st < 2; ++st) {
            const int arow = (w << 4) + col;
            const int ao = arow * 64 + (((glane + (st << 2)) ^ (col & 7)) << 3);
            const bf16x8 a0 = *reinterpret_cast<const bf16x8*>(&SL[ao]);
            const bf16x8 a1 = *reinterpret_cast<const bf16x8*>(&SL[4096 + ao]);
            const bf16x8 a2 = *reinterpret_cast<const bf16x8*>(&SL[8192 + ao]);
#pragma unroll
            for (int wi = 0; wi < 3; ++wi)
#pragma unroll
                for (int nj = 0; nj < 4; ++nj) {
                    const int brow = (nj << 4) + col;
                    const int bo = 12288 + wi * 8192 + brow * 64 + (((glane + (st << 2)) ^ (col & 7)) << 3);
                    const bf16x8 b0 = *reinterpret_cast<const bf16x8*>(&SL[bo]);
                    const bf16x8 b1 = *reinterpret_cast<const bf16x8*>(&SL[bo + 4096]);
                    acc[wi][nj] = mfma16(a0, b0, acc[wi][nj]);
                    acc[wi][nj] = mfma16(a1, b0, acc[wi][nj]);
                    acc[wi][nj] = mfma16(a0, b1, acc[wi][nj]);
                    acc[wi][nj] = mfma16(a1, b1, acc[wi][nj]);
                    acc[wi][nj] = mfma16(a2, b0, acc[wi][nj]);
                }
        }
    }

    const int b = m0 >> 11;
    const int h = n0 >> 6;
    const size_t bh_off = (size_t)(b * NH + h) * S * DH;
#pragma unroll
    for (int r = 0; r < 4; ++r) {
        const int srow = (m0 & (S - 1)) + (w << 4) + (glane << 2) + r;
#pragma unroll
        for (int nj = 0; nj < 4; ++nj) {
            const size_t o = bh_off + (size_t)srow * DH + (nj << 4) + col;
            qf[o] = acc[0][nj][r];
            const float xk = acc[1][nj][r];
            const ushort k0s = f2bf(xk);
            const float kr1 = xk - bf2f(k0s);
            const ushort k1s = f2bf(kr1);
            ksp[o] = k0s;
            ksp[ASTRIDE + o] = k1s;
            ksp[2 * ASTRIDE + o] = f2bf(kr1 - bf2f(k1s));
            const float xv = acc[2][nj][r];
            const ushort v0s = f2bf(xv);
            vsp[o] = v0s;
            vsp[ASTRIDE + o] = f2bf(xv - bf2f(v0s));
        }
    }
}

// ---- V transpose: 2-split [bh][s][64] -> 2-split [bh][64][s'], where the
// k-columns are granule-permuted per 16 (order [0,2,1,3] of 4-element granules)
// so the attention PV B-fragment packs from each lane's OWN S-values. ----
__global__ __launch_bounds__(256) void transpose_v(const ushort* __restrict__ v,
                                                   ushort* __restrict__ vt) {
    __shared__ ushort Ts[2][64][72];
    const int tid = threadIdx.x;
    const int bh = blockIdx.x & 31;
    const int s0 = (blockIdx.x >> 5) << 6;
    const int r = tid >> 2;
    const int c16 = (tid & 3) << 4;
#pragma unroll
    for (int sp = 0; sp < 2; ++sp)
#pragma unroll
        for (int e = 0; e < 2; ++e) {
            *reinterpret_cast<u16x8*>(&Ts[sp][r][c16 + (e << 3)]) =
                *reinterpret_cast<const u16x8*>(
                    &v[(size_t)sp * ASTRIDE + ((size_t)bh * S + s0 + r) * DH + c16 + (e << 3)]);
        }
    __syncthreads();
    const int dr = tid >> 2;
    const int sc = (tid & 3) << 4;   // 16-aligned k block
#pragma unroll
    for (int sp = 0; sp < 2; ++sp) {
        u16x8 o0, o1;
#pragma unroll
        for (int i = 0; i < 8; ++i) {
            const int j0 = (i < 4) ? i : i + 4;        // out col i      <- k sc+j0
            const int j1 = (i < 4) ? i + 4 : i + 8;    // out col 8 + i  <- k sc+j1
            o0[i] = Ts[sp][sc + j0][dr];
            o1[i] = Ts[sp][sc + j1][dr];
        }
        const size_t base = (size_t)sp * ASTRIDE + ((size_t)bh * DH + dr) * S + s0 + sc;
        *reinterpret_cast<u16x8*>(vt + base) = o0;
        *reinterpret_cast<u16x8*>(vt + base + 8) = o1;
    }
}

// ---------------------------------------------------------------------------
// MFMA flash attention v5: 32x32 swapped-QK, permutation-free P packing.
// Block = 128 q-rows x (bh); 4 waves, wave owns 32 q. S^T = mfma32(K, Q):
// lane owns q-col = lane&31, holds S^T rows crow(r,hi)=(r&3)+8*(r>>2)+4*hi.
// Because V^T's k-columns are granule-permuted (transpose_v), the PV B-frag
// for k-chunk kc is simply p[8*(kc&1)..+8] of half ks=kc>>1 packed in order
// via v_cvt_pk_bf16_f32 -- NO cross-lane exchange. Softmax lane-local with
// defer-max (THR=8 in log2 units; ln2/8 folded into Q split). Double-buffered
// global_load_lds staging (80 KB LDS, 2 blocks/CU), one barrier per tile.
// Split math unchanged: Q/K 3-split 6-term QK, V 2-split 2-term PV.
// ---------------------------------------------------------------------------
__global__ __launch_bounds__(256, 2) void attn_mfma5(const float* __restrict__ Qf,
                                                     const ushort* __restrict__ ksp,
                                                     const ushort* __restrict__ vtsp,
                                                     float* __restrict__ out) {
    // [buf][ K: 3*4096 | V: 2*4096 ] ushorts = 40 KB per buffer, 80 KB total
    __shared__ __align__(16) ushort SB[2][20480];

    const int tid = threadIdx.x;
    const int lane = tid & 63;
    const int w = tid >> 6;
    const int swz = (blockIdx.x & 7) * 64 + (blockIdx.x >> 3);   // 512 blocks, bijective
    const int bh = swz >> 4;
    const int qt = 15 - (swz & 15);        // big q-tiles first
    const int q0 = qt << 7;                // 128-row q tile
    const int qw0 = q0 + (w << 5);         // wave's 32 q rows
    const int hi = lane >> 5;
    const int ql = lane & 31;
    const int qg = qw0 + ql;               // lane's global q row
    const int lrow = lane >> 3;
    const int sl8 = ((lane & 7) ^ lrow) << 3;

    // ---- Q fragments: (1/8 * log2e) folded, 3 splits x 4 d-chunks ----
    bf16x8 qb[3][4];
    {
        const float* qp = Qf + ((size_t)bh * S + qg) * DH + (hi << 3);
#pragma unroll
        for (int dc = 0; dc < 4; ++dc) {
            const float4 f0 = *reinterpret_cast<const float4*>(qp + (dc << 4));
            const float4 f1 = *reinterpret_cast<const float4*>(qp + (dc << 4) + 4);
            const float xs[8] = {f0.x, f0.y, f0.z, f0.w, f1.x, f1.y, f1.z, f1.w};
#pragma unroll
            for (int e = 0; e < 8; ++e) {
                const float x = xs[e] * 0.18033688011112042f;   // 1/8 * log2(e)
                const ushort h0 = f2bf(x);
                const float r1 = x - bf2f(h0);
                const ushort h1 = f2bf(r1);
                qb[0][dc][e] = (short)h0;
                qb[1][dc][e] = (short)h1;
                qb[2][dc][e] = (short)f2bf(r1 - bf2f(h1));
            }
        }
    }

    f32x16 O[2];
#pragma unroll
    for (int ds = 0; ds < 2; ++ds)
#pragma unroll
        for (int r = 0; r < 16; ++r) O[ds][r] = 0.f;
    float m_ = -INFINITY, l_ = 0.f;

    const size_t kbase = (size_t)bh * S * DH;
    const size_t vbase = (size_t)bh * DH * S;

#define ISSUE_KV(K0, BUF)                                                               \
    {                                                                                   \
        _Pragma("unroll")                                                               \
        for (int i = 0; i < 10; ++i) {                                                  \
            const int u = (i << 2) | w;                                                 \
            const ushort* gp;                                                           \
            if (u < 24) {                                                               \
                const int sp = u >> 3, rb = u & 7;                                      \
                gp = ksp + (size_t)sp * ASTRIDE + kbase +                               \
                     (size_t)((K0) + (rb << 3) + lrow) * DH + sl8;                      \
            } else {                                                                    \
                const int v_ = u - 24;                                                  \
                const int sp = v_ >> 3, rb = v_ & 7;                                    \
                gp = vtsp + (size_t)sp * ASTRIDE + vbase +                              \
                     (size_t)((rb << 3) + lrow) * S + (K0) + sl8;                       \
            }                                                                           \
            __builtin_amdgcn_global_load_lds(gp, &SB[BUF][u * 512], 16, 0, 0);          \
        }                                                                               \
    }

    ISSUE_KV(0, 0);
    __syncthreads();

    const int ktmax = (q0 >> 6) + 1;
    for (int kt = 0; kt <= ktmax; ++kt) {
        const int k0 = kt << 6;
        const int cur = kt & 1;
        if (kt < ktmax) ISSUE_KV(k0 + 64, cur ^ 1);   // prefetch under compute

        const bool active = (k0 <= qw0 + 31);          // wave-uniform
        if (active) {
            const ushort* KL = &SB[cur][0];
            const ushort* VL = &SB[cur][12288];

            // ---- S^T = K Q^T (64k x 32q per wave, 6 split terms) ----
            f32x16 Sf[2];
#pragma unroll
            for (int ks = 0; ks < 2; ++ks)
#pragma unroll
                for (int r = 0; r < 16; ++r) Sf[ks][r] = 0.f;
#pragma unroll
            for (int ks = 0; ks < 2; ++ks) {
#pragma unroll
                for (int dc = 0; dc < 4; ++dc) {
                    const int row = (ks << 5) + ql;
                    const int eo = row * 64 + ((((dc << 1) | hi) ^ (row & 7)) << 3);
                    const bf16x8 ka = *reinterpret_cast<const bf16x8*>(&KL[eo]);
                    const bf16x8 kb = *reinterpret_cast<const bf16x8*>(&KL[4096 + eo]);
                    const bf16x8 kc2 = *reinterpret_cast<const bf16x8*>(&KL[8192 + eo]);
                    Sf[ks] = mfma32(ka, qb[0][dc], Sf[ks]);
                    Sf[ks] = mfma32(kb, qb[0][dc], Sf[ks]);
                    Sf[ks] = mfma32(ka, qb[1][dc], Sf[ks]);
                    Sf[ks] = mfma32(kb, qb[1][dc], Sf[ks]);
                    Sf[ks] = mfma32(kc2, qb[0][dc], Sf[ks]);
                    Sf[ks] = mfma32(ka, qb[2][dc], Sf[ks]);
                }
            }

            // ---- causal mask (only near-diagonal tiles) ----
            if (k0 + 63 > qw0) {
#pragma unroll
                for (int ks = 0; ks < 2; ++ks)
#pragma unroll
                    for (int r = 0; r < 16; ++r) {
                        const int kg = k0 + (ks << 5) + (r & 3) + ((r >> 2) << 3) + (hi << 2);
                        if (kg > qg) Sf[ks][r] = -1e30f;
                    }
            }

            // ---- lane-local softmax with defer-max ----
            float rm = Sf[0][0];
#pragma unroll
            for (int ks = 0; ks < 2; ++ks)
#pragma unroll
                for (int r = 0; r < 16; ++r) rm = fmaxf(rm, Sf[ks][r]);
            rm = fmaxf(rm, __shfl_xor(rm, 32));
            if (__any(rm > m_ + 8.f)) {
                const float nm = fmaxf(m_, rm);
                const float sc = exp2fast(m_ - nm);
                m_ = nm;
                l_ *= sc;
#pragma unroll
                for (int ds = 0; ds < 2; ++ds)
#pragma unroll
                    for (int r = 0; r < 16; ++r) O[ds][r] *= sc;
            }

            // ---- P = 2^(S - m), sum, in-order in-register B-frag packing ----
            // (V^T k-granule permutation makes pb[kc][e] = own p[8*(kc&1)+e])
            float rs = 0.f;
            bf16x8 pb[4];
#pragma unroll
            for (int ks = 0; ks < 2; ++ks) {
                float p[16];
#pragma unroll
                for (int r = 0; r < 16; ++r) {
                    p[r] = exp2fast(Sf[ks][r] - m_);
                    rs += p[r];
                }
#pragma unroll
                for (int c = 0; c < 2; ++c) {
                    union { unsigned u[4]; bf16x8 v; } pw;
                    pw.u[0] = cvt_pk(p[(c << 3) + 0], p[(c << 3) + 1]);
                    pw.u[1] = cvt_pk(p[(c << 3) + 2], p[(c << 3) + 3]);
                    pw.u[2] = cvt_pk(p[(c << 3) + 4], p[(c << 3) + 5]);
                    pw.u[3] = cvt_pk(p[(c << 3) + 6], p[(c << 3) + 7]);
                    pb[(ks << 1) + c] = pw.v;
                }
            }
            rs += __shfl_xor(rs, 32);
            l_ += rs;

            // ---- O^T += V^T P^T ----
#pragma unroll
            for (int sp = 0; sp < 2; ++sp)
#pragma unroll
                for (int ds = 0; ds < 2; ++ds)
#pragma unroll
                    for (int kc = 0; kc < 4; ++kc) {
                        const int row = (ds << 5) + ql;
                        const int eo = sp * 4096 + row * 64 + ((((kc << 1) | hi) ^ (row & 7)) << 3);
                        const bf16x8 va = *reinterpret_cast<const bf16x8*>(&VL[eo]);
                        O[ds] = mfma32(va, pb[kc], O[ds]);
                    }
        }
        __syncthreads();   // compute(cur) done AND prefetch(cur^1) drained
    }

    // ---- epilogue: O^T[d, q] -> out[b, q, h*64 + d] ----
    const float inv = 1.f / l_;
    const int b = bh >> 4, h = bh & (NH - 1);
    float* op = out + ((size_t)(b * S + qg)) * DOUT + h * DH;
#pragma unroll
    for (int ds = 0; ds < 2; ++ds)
#pragma unroll
        for (int rg = 0; rg < 4; ++rg) {
            float4 v;
            v.x = O[ds][(rg << 2) + 0] * inv;
            v.y = O[ds][(rg << 2) + 1] * inv;
            v.z = O[ds][(rg << 2) + 2] * inv;
            v.w = O[ds][(rg << 2) + 3] * inv;
            *reinterpret_cast<float4*>(&op[(ds << 5) + (rg << 3) + (hi << 2)]) = v;
        }
#undef ISSUE_KV
}

// ===========================================================================
// FALLBACK (fp32, ws >= 48 MB)
// ===========================================================================
__global__ __launch_bounds__(256) void proj_f32(const float* __restrict__ A,
                                                const float* __restrict__ W,
                                                float* __restrict__ outf) {
    __shared__ float As[16][68];
    __shared__ float Bs[16][68];
    const int tid = threadIdx.x;
    const int m0 = blockIdx.x * 64;
    const int n0 = blockIdx.y * 64;
    const int tm = tid >> 4, tn = tid & 15;
    const int la_r = tid >> 2, la_c = (tid & 3) << 2;
    const int lb_r = tid >> 4, lb_c = (tid & 15) << 2;

    float acc[4][4];
#pragma unroll
    for (int i = 0; i < 4; ++i)
#pragma unroll
        for (int j = 0; j < 4; ++j) acc[i][j] = 0.f;

    for (int k0 = 0; k0 < DIN; k0 += 16) {
        const float4 av = *reinterpret_cast<const float4*>(&A[(size_t)(m0 + la_r) * DIN + k0 + la_c]);
        const float4 bv = *reinterpret_cast<const float4*>(&W[(size_t)(k0 + lb_r) * DOUT + n0 + lb_c]);
        __syncthreads();
        As[la_c + 0][la_r] = av.x; As[la_c + 1][la_r] = av.y;
        As[la_c + 2][la_r] = av.z; As[la_c + 3][la_r] = av.w;
        *reinterpret_cast<float4*>(&Bs[lb_r][lb_c]) = bv;
        __syncthreads();
#pragma unroll
        for (int kk = 0; kk < 16; ++kk) {
            const float4 a = *reinterpret_cast<const float4*>(&As[kk][tm << 2]);
            const float4 b = *reinterpret_cast<const float4*>(&Bs[kk][tn << 2]);
            const float aa[4] = {a.x, a.y, a.z, a.w};
            const float bb[4] = {b.x, b.y, b.z, b.w};
#pragma unroll
            for (int i = 0; i < 4; ++i)
#pragma unroll
                for (int j = 0; j < 4; ++j) acc[i][j] += aa[i] * bb[j];
        }
    }
    const int b = m0 >> 11;
    const int s_base = (m0 & (S - 1)) + (tm << 2);
    const int h = n0 >> 6;
    const int dh = tn << 2;
    float* obase = outf + ((size_t)(b * NH + h) * S) * DH;
#pragma unroll
    for (int i = 0; i < 4; ++i) {
        float4 v;
        v.x = acc[i][0]; v.y = acc[i][1]; v.z = acc[i][2]; v.w = acc[i][3];
        *reinterpret_cast<float4*>(&obase[(size_t)(s_base + i) * DH + dh]) = v;
    }
}

__global__ __launch_bounds__(256) void attn_f32(const float* __restrict__ Q,
                                                const float* __restrict__ K,
                                                const float* __restrict__ V,
                                                float* __restrict__ out) {
    __shared__ float Qs[64][68];
    __shared__ float Ks[64][68];
    __shared__ float Vs[64][68];
    __shared__ float Ps[64][68];
    const int tid = threadIdx.x;
    const int bh = blockIdx.x & 31;
    const int qt = 31 - (blockIdx.x >> 5);
    const int q0 = qt << 6;
    const int tq = tid >> 4, tk = tid & 15;
    const int sr = tid >> 2, sc = (tid & 3) << 2;

    const float* qbase = Q + ((size_t)bh * S + q0) * DH;
    const float* kbase = K + (size_t)bh * S * DH;
    const float* vbase = V + (size_t)bh * S * DH;
#pragma unroll
    for (int it = 0; it < 4; ++it) {
        const int d0 = sc + (it << 4);
        const float4 v = *reinterpret_cast<const float4*>(&qbase[(size_t)sr * DH + d0]);
        Qs[d0 + 0][sr] = v.x; Qs[d0 + 1][sr] = v.y;
        Qs[d0 + 2][sr] = v.z; Qs[d0 + 3][sr] = v.w;
    }
    float C[4][4];
#pragma unroll
    for (int i = 0; i < 4; ++i)
#pragma unroll
        for (int j = 0; j < 4; ++j) C[i][j] = 0.f;
    float m[4] = {-1e30f, -1e30f, -1e30f, -1e30f};
    float l[4] = {0.f, 0.f, 0.f, 0.f};

    for (int kt = 0; kt <= qt; ++kt) {
        const int k0 = kt << 6;
        float4 kv[4], vv[4];
#pragma unroll
        for (int it = 0; it < 4; ++it) {
            const int d0 = sc + (it << 4);
            kv[it] = *reinterpret_cast<const float4*>(&kbase[(size_t)(k0 + sr) * DH + d0]);
            vv[it] = *reinterpret_cast<const float4*>(&vbase[(size_t)(k0 + sr) * DH + d0]);
        }
        __syncthreads();
#pragma unroll
        for (int it = 0; it < 4; ++it) {
            const int d0 = sc + (it << 4);
            Ks[d0 + 0][sr] = kv[it].x; Ks[d0 + 1][sr] = kv[it].y;
            Ks[d0 + 2][sr] = kv[it].z; Ks[d0 + 3][sr] = kv[it].w;
            *reinterpret_cast<float4*>(&Vs[sr][d0]) = vv[it];
        }
        __syncthreads();

        float s[4][4];
#pragma unroll
        for (int i = 0; i < 4; ++i)
#pragma unroll
            for (int j = 0; j < 4; ++j) s[i][j] = 0.f;
#pragma unroll 16
        for (int d = 0; d < 64; ++d) {
            const float4 qf4 = *reinterpret_cast<const float4*>(&Qs[d][tq << 2]);
            const float4 kf4 = *reinterpret_cast<const float4*>(&Ks[d][tk << 2]);
            const float qa[4] = {qf4.x, qf4.y, qf4.z, qf4.w};
            const float ka[4] = {kf4.x, kf4.y, kf4.z, kf4.w};
#pragma unroll
            for (int i = 0; i < 4; ++i)
#pragma unroll
                for (int j = 0; j < 4; ++j) s[i][j] += qa[i] * ka[j];
        }
        if (kt == qt) {
#pragma unroll
            for (int i = 0; i < 4; ++i) {
                const int qg = q0 + (tq << 2) + i;
#pragma unroll
                for (int j = 0; j < 4; ++j) {
                    const int kg = k0 + (tk << 2) + j;
                    s[i][j] = (kg <= qg) ? s[i][j] * 0.125f : -1e30f;
                }
            }
        } else {
#pragma unroll
            for (int i = 0; i < 4; ++i)
#pragma unroll
                for (int j = 0; j < 4; ++j) s[i][j] *= 0.125f;
        }
#pragma unroll
        for (int i = 0; i < 4; ++i) {
            float rm = fmaxf(fmaxf(s[i][0], s[i][1]), fmaxf(s[i][2], s[i][3]));
#pragma unroll
            for (int off = 1; off < 16; off <<= 1) rm = fmaxf(rm, __shfl_xor(rm, off));
            const float mn = fmaxf(m[i], rm);
            const float scale = __expf(m[i] - mn);
            float rs = 0.f;
#pragma unroll
            for (int j = 0; j < 4; ++j) {
                s[i][j] = __expf(s[i][j] - mn);
                rs += s[i][j];
            }
#pragma unroll
            for (int off = 1; off < 16; off <<= 1) rs += __shfl_xor(rs, off);
            l[i] = l[i] * scale + rs;
            m[i] = mn;
#pragma unroll
            for (int j = 0; j < 4; ++j) C[i][j] *= scale;
            *reinterpret_cast<float4*>(&Ps[(tq << 2) + i][tk << 2]) =
                make_float4(s[i][0], s[i][1], s[i][2], s[i][3]);
        }
        __syncthreads();
#pragma unroll 4
        for (int kc = 0; kc < 16; ++kc) {
            float4 pf[4], vf[4];
#pragma unroll
            for (int i = 0; i < 4; ++i)
                pf[i] = *reinterpret_cast<const float4*>(&Ps[(tq << 2) + i][kc << 2]);
#pragma unroll
            for (int j = 0; j < 4; ++j)
                vf[j] = *reinterpret_cast<const float4*>(&Vs[(kc << 2) + j][tk << 2]);
#pragma unroll
            for (int i = 0; i < 4; ++i) {
                const float pa[4] = {pf[i].x, pf[i].y, pf[i].z, pf[i].w};
#pragma unroll
                for (int j = 0; j < 4; ++j) {
                    C[i][j] += pa[0] * ((const float*)&vf[0])[j]
                             + pa[1] * ((const float*)&vf[1])[j]
                             + pa[2] * ((const float*)&vf[2])[j]
                             + pa[3] * ((const float*)&vf[3])[j];
                }
            }
        }
        __syncthreads();
    }
    const int b = bh >> 4, h = bh & (NH - 1);
#pragma unroll
    for (int i = 0; i < 4; ++i) {
        const int qg = q0 + (tq << 2) + i;
        const float inv = 1.f / l[i];
        float4 v;
        v.x = C[i][0] * inv; v.y = C[i][1] * inv;
        v.z = C[i][2] * inv; v.w = C[i][3] * inv;
        *reinterpret_cast<float4*>(&out[((size_t)(b * S + qg)) * DOUT + h * DH + (tk << 2)]) = v;
    }
}

// ===========================================================================
extern "C" void kernel_launch(void* const* d_in, const int* in_sizes, int n_in,
                              void* d_out, int out_size, void* d_ws, size_t ws_size,
                              hipStream_t stream) {
    const float* x  = (const float*)d_in[0];
    const float* Wq = (const float*)d_in[1];
    const float* Wk = (const float*)d_in[2];
    const float* Wv = (const float*)d_in[3];
    float* out = (float*)d_out;

    char* ws = (char*)d_ws;
    const size_t MB = 1024 * 1024;

    if (ws_size >= 92 * MB) {
        // layout: wT[0,12) | xsp[12,36) (later reused as VT[12,28)) |
        //         Q[36,52) | K 3-split[52,76) | Vtmp[76,92)
        ushort* wtsp = (ushort*)(ws);
        ushort* xsp  = (ushort*)(ws + 12 * MB);
        float*  qf   = (float*)(ws + 36 * MB);
        ushort* ksp  = (ushort*)(ws + 52 * MB);
        ushort* vsp  = (ushort*)(ws + 76 * MB);
        ushort* vtsp = (ushort*)(ws + 12 * MB);   // overwrites xsp (dead after proj)

        split_x<<<4096, 256, 0, stream>>>(x, xsp);
        split_wT3<<<dim3(16, 16, 3), 256, 0, stream>>>(Wq, Wk, Wv, wtsp);
        proj_fused<<<1024, 256, 0, stream>>>(xsp, wtsp, qf, ksp, vsp);
        transpose_v<<<1024, 256, 0, stream>>>(vsp, vtsp);
        attn_mfma5<<<512, 256, 0, stream>>>(qf, ksp, vtsp, out);
    } else {
        // fp32 fallback (48 MB)
        float* qws = (float*)d_ws;
        float* kws = qws + (size_t)M_TOT * DOUT;
        float* vws = kws + (size_t)M_TOT * DOUT;
        dim3 pgrid(M_TOT / 64, DOUT / 64);
        proj_f32<<<pgrid, 256, 0, stream>>>(x, Wq, qws);
        proj_f32<<<pgrid, 256, 0, stream>>>(x, Wk, kws);
        proj_f32<<<pgrid, 256, 0, stream>>>(x, Wv, vws);
        attn_f32<<<32 * 32, 256, 0, stream>>>(qws, kws, vws, out);
    }
}

// Round 8
// 181.807 us; speedup vs baseline: 22.5420x; 1.2954x over previous
//
#include <hip/hip_runtime.h>
#include <hip/hip_bf16.h>

// Problem constants: B=2, S=2048, D_IN=1024, D_OUT=1024, H=16, Dh=64
#define B 2
#define S 2048
#define DIN 1024
#define DOUT 1024
#define NH 16
#define DH 64
#define M_TOT (B * S)   // 4096

typedef __attribute__((ext_vector_type(8))) short bf16x8;
typedef __attribute__((ext_vector_type(8))) unsigned short u16x8;
typedef __attribute__((ext_vector_type(4))) float f32x4;
typedef __attribute__((ext_vector_type(16))) float f32x16;

#define ASTRIDE 4194304   // elements per 4096x1024 split array
#define WSTRIDE 1048576   // elements per 1024x1024 split array

__device__ __forceinline__ ushort f2bf(float x) {
    union { float f; unsigned u; } c; c.f = x;
    unsigned r = (c.u + 0x7FFFu + ((c.u >> 16) & 1u)) >> 16;
    return (ushort)r;
}
__device__ __forceinline__ float bf2f(ushort h) {
    union { unsigned u; float f; } c; c.u = ((unsigned)h) << 16;
    return c.f;
}
__device__ __forceinline__ f32x4 mfma16(bf16x8 a, bf16x8 b, f32x4 c) {
    return __builtin_amdgcn_mfma_f32_16x16x32_bf16(a, b, c, 0, 0, 0);
}
__device__ __forceinline__ f32x16 mfma32(bf16x8 a, bf16x8 b, f32x16 c) {
    return __builtin_amdgcn_mfma_f32_32x32x16_bf16(a, b, c, 0, 0, 0);
}
__device__ __forceinline__ unsigned cvt_pk(float lo, float hi) {
    unsigned r;
    asm("v_cvt_pk_bf16_f32 %0, %1, %2" : "=v"(r) : "v"(lo), "v"(hi));
    return r;
}
__device__ __forceinline__ float exp2fast(float x) {
    float r;
    asm("v_exp_f32 %0, %1" : "=v"(r) : "v"(x));
    return r;
}

// ===========================================================================
// MAIN PATH (ws >= 76 MB)
// ===========================================================================

// ---- prepass: x (fp32 [4096][1024]) -> 2-way bf16 splits ----
__global__ __launch_bounds__(256) void split_x(const float* __restrict__ x,
                                               ushort* __restrict__ xs) {
    const size_t gid = (size_t)blockIdx.x * 256 + threadIdx.x;
    const float4 v = *reinterpret_cast<const float4*>(x + gid * 4);
    const float in[4] = {v.x, v.y, v.z, v.w};
    ushort h0[4], h1[4];
#pragma unroll
    for (int e = 0; e < 4; ++e) {
        h0[e] = f2bf(in[e]);
        h1[e] = f2bf(in[e] - bf2f(h0[e]));
    }
    const size_t o = gid * 4;
    *reinterpret_cast<ushort4*>(xs + o)           = ushort4{h0[0], h0[1], h0[2], h0[3]};
    *reinterpret_cast<ushort4*>(xs + ASTRIDE + o) = ushort4{h1[0], h1[1], h1[2], h1[3]};
}

// ---- prepass: all three W -> W^T 2-way bf16 splits, wt[wi][sp][n][k] ----
__global__ __launch_bounds__(256) void split_wT3(const float* __restrict__ W0,
                                                 const float* __restrict__ W1,
                                                 const float* __restrict__ W2,
                                                 ushort* __restrict__ wt) {
    __shared__ float Ws[64][68];
    const int tid = threadIdx.x;
    const int k0 = blockIdx.x << 6;
    const int n0 = blockIdx.y << 6;
    const int wi = blockIdx.z;
    const float* W = (wi == 0) ? W0 : (wi == 1) ? W1 : W2;
    ushort* wto = wt + (size_t)wi * 2 * WSTRIDE;

    const int r = tid >> 2;
    const int cb = (tid & 3) << 2;
#pragma unroll
    for (int it = 0; it < 4; ++it) {
        const int c = cb + (it << 4);
        *reinterpret_cast<float4*>(&Ws[r][c]) =
            *reinterpret_cast<const float4*>(&W[(size_t)(k0 + r) * 1024 + n0 + c]);
    }
    __syncthreads();
    const int rn = tid >> 2;
    const int kc = (tid & 3) << 4;
    u16x8 o0[2], o1[2];
#pragma unroll
    for (int half = 0; half < 2; ++half)
#pragma unroll
        for (int i = 0; i < 8; ++i) {
            const float x = Ws[kc + (half << 3) + i][rn];
            const ushort a = f2bf(x);
            o0[half][i] = a;
            o1[half][i] = f2bf(x - bf2f(a));
        }
    const size_t base = (size_t)(n0 + rn) * 1024 + k0 + kc;
    *reinterpret_cast<u16x8*>(wto + base)               = o0[0];
    *reinterpret_cast<u16x8*>(wto + base + 8)           = o0[1];
    *reinterpret_cast<u16x8*>(wto + WSTRIDE + base)     = o1[0];
    *reinterpret_cast<u16x8*>(wto + WSTRIDE + base + 8) = o1[1];
}

// ---------------------------------------------------------------------------
// Fused QKV projection v2: 128(M)x64(N) tile; Q/K 4-term ((x0+x1)(w0+w1)),
// V 2-term ((x0+x1)w0). A (x 2-split) read once per tile and used for all
// three outputs. LDS 72 KB: A 2x[128][64] + B 5x[64][64] (Wq0,Wq1,Wk0,Wk1,
// Wv0), global_load_lds staging with slot^(row&7) swizzle via pre-swizzled
// global source. 512 blocks (32 m x 16 n), XCD-chunked. 2 blocks/CU.
// Outputs: Q fp32, K 2-split, V 2-split ([bh][s][d]).
// ---------------------------------------------------------------------------
__global__ __launch_bounds__(256, 2) void proj_fused2(const ushort* __restrict__ xsp,
                                                      const ushort* __restrict__ wtsp,
                                                      float* __restrict__ qf,
                                                      ushort* __restrict__ ksp,
                                                      ushort* __restrict__ vsp) {
    __shared__ __align__(16) ushort SL[36864];   // 72 KB

    const int tid = threadIdx.x;
    const int lane = tid & 63;
    const int w = tid >> 6;
    const int swz = (blockIdx.x & 7) * 64 + (blockIdx.x >> 3);   // 512 blocks, bijective
    const int n0 = (swz & 15) << 6;
    const int m0 = (swz >> 4) << 7;   // 32 m-tiles of 128
    const int col = lane & 15;
    const int glane = lane >> 4;
    const int lrow = lane >> 3;
    const int sl8 = ((lane & 7) ^ lrow) << 3;

    f32x4 accq[2][4], acck[2][4], accv[2][4];   // [mi][nj]
#pragma unroll
    for (int mi = 0; mi < 2; ++mi)
#pragma unroll
        for (int nj = 0; nj < 4; ++nj) {
            accq[mi][nj] = f32x4{0.f, 0.f, 0.f, 0.f};
            acck[mi][nj] = f32x4{0.f, 0.f, 0.f, 0.f};
            accv[mi][nj] = f32x4{0.f, 0.f, 0.f, 0.f};
        }

    for (int k0 = 0; k0 < DIN; k0 += 64) {
        __syncthreads();   // previous step's LDS reads done
        // 72 staging units of 1 KB: A 2sp x 16 row-blocks, B 5 tiles x 8
#pragma unroll
        for (int i = 0; i < 18; ++i) {
            const int u = (i << 2) | w;          // 0..71
            const ushort* g;
            if (u < 32) {
                const int sp = u >> 4, rb = u & 15;
                g = xsp + (size_t)sp * ASTRIDE + (size_t)(m0 + (rb << 3) + lrow) * 1024 + k0 + sl8;
            } else {
                const int v = u - 32;            // 0..39
                const int bi = v >> 3;           // 0..4 = Wq0,Wq1,Wk0,Wk1,Wv0
                const int rb = v & 7;
                g = wtsp + (size_t)bi * WSTRIDE + (size_t)(n0 + (rb << 3) + lrow) * 1024 + k0 + sl8;
            }
            __builtin_amdgcn_global_load_lds(g, &SL[u * 512], 16, 0, 0);
        }
        __syncthreads();   // staging drained + visible

#pragma unroll
        for (int st = 0; st < 2; ++st) {
            const int sw = (((st << 2) | glane) ^ (col & 7)) << 3;
            bf16x8 a[2][2];   // [sp][mi]
#pragma unroll
            for (int sp = 0; sp < 2; ++sp)
#pragma unroll
                for (int mi = 0; mi < 2; ++mi) {
                    const int arow = (w << 5) + (mi << 4) + col;
                    a[sp][mi] = *reinterpret_cast<const bf16x8*>(&SL[sp * 8192 + arow * 64 + sw]);
                }
#pragma unroll
            for (int nj = 0; nj < 4; ++nj) {
                const int brow = (nj << 4) + col;
                const int bb = 16384 + brow * 64 + sw;
                const bf16x8 bq0 = *reinterpret_cast<const bf16x8*>(&SL[bb]);
                const bf16x8 bq1 = *reinterpret_cast<const bf16x8*>(&SL[bb + 4096]);
                const bf16x8 bk0 = *reinterpret_cast<const bf16x8*>(&SL[bb + 8192]);
                const bf16x8 bk1 = *reinterpret_cast<const bf16x8*>(&SL[bb + 12288]);
                const bf16x8 bv0 = *reinterpret_cast<const bf16x8*>(&SL[bb + 16384]);
#pragma unroll
                for (int mi = 0; mi < 2; ++mi) {
                    accq[mi][nj] = mfma16(a[0][mi], bq0, accq[mi][nj]);
                    accq[mi][nj] = mfma16(a[1][mi], bq0, accq[mi][nj]);
                    accq[mi][nj] = mfma16(a[0][mi], bq1, accq[mi][nj]);
                    accq[mi][nj] = mfma16(a[1][mi], bq1, accq[mi][nj]);
                    acck[mi][nj] = mfma16(a[0][mi], bk0, acck[mi][nj]);
                    acck[mi][nj] = mfma16(a[1][mi], bk0, acck[mi][nj]);
                    acck[mi][nj] = mfma16(a[0][mi], bk1, acck[mi][nj]);
                    acck[mi][nj] = mfma16(a[1][mi], bk1, acck[mi][nj]);
                    accv[mi][nj] = mfma16(a[0][mi], bv0, accv[mi][nj]);
                    accv[mi][nj] = mfma16(a[1][mi], bv0, accv[mi][nj]);
                }
            }
        }
    }

    // epilogue: [bh][s][d]; Q fp32, K 2-split, V 2-split
    const int b = m0 >> 11;
    const int h = n0 >> 6;
    const size_t bh_off = (size_t)(b * NH + h) * S * DH;
#pragma unroll
    for (int mi = 0; mi < 2; ++mi)
#pragma unroll
        for (int r = 0; r < 4; ++r) {
            const int srow = (m0 & (S - 1)) + (w << 5) + (mi << 4) + (glane << 2) + r;
#pragma unroll
            for (int nj = 0; nj < 4; ++nj) {
                const size_t o = bh_off + (size_t)srow * DH + (nj << 4) + col;
                qf[o] = accq[mi][nj][r];
                const float xk = acck[mi][nj][r];
                const ushort k0s = f2bf(xk);
                ksp[o] = k0s;
                ksp[ASTRIDE + o] = f2bf(xk - bf2f(k0s));
                const float xv = accv[mi][nj][r];
                const ushort v0s = f2bf(xv);
                vsp[o] = v0s;
                vsp[ASTRIDE + o] = f2bf(xv - bf2f(v0s));
            }
        }
}

// ---- V transpose: 2-split [bh][s][64] -> 2-split [bh][64][s'], where the
// k-columns are granule-permuted per 16 (order [0,2,1,3] of 4-element granules)
// so the attention PV B-fragment packs from each lane's OWN S-values. ----
__global__ __launch_bounds__(256) void transpose_v(const ushort* __restrict__ v,
                                                   ushort* __restrict__ vt) {
    __shared__ ushort Ts[2][64][72];
    const int tid = threadIdx.x;
    const int bh = blockIdx.x & 31;
    const int s0 = (blockIdx.x >> 5) << 6;
    const int r = tid >> 2;
    const int c16 = (tid & 3) << 4;
#pragma unroll
    for (int sp = 0; sp < 2; ++sp)
#pragma unroll
        for (int e = 0; e < 2; ++e) {
            *reinterpret_cast<u16x8*>(&Ts[sp][r][c16 + (e << 3)]) =
                *reinterpret_cast<const u16x8*>(
                    &v[(size_t)sp * ASTRIDE + ((size_t)bh * S + s0 + r) * DH + c16 + (e << 3)]);
        }
    __syncthreads();
    const int dr = tid >> 2;
    const int sc = (tid & 3) << 4;   // 16-aligned k block
#pragma unroll
    for (int sp = 0; sp < 2; ++sp) {
        u16x8 o0, o1;
#pragma unroll
        for (int i = 0; i < 8; ++i) {
            const int j0 = (i < 4) ? i : i + 4;        // out col i      <- k sc+j0
            const int j1 = (i < 4) ? i + 4 : i + 8;    // out col 8 + i  <- k sc+j1
            o0[i] = Ts[sp][sc + j0][dr];
            o1[i] = Ts[sp][sc + j1][dr];
        }
        const size_t base = (size_t)sp * ASTRIDE + ((size_t)bh * DH + dr) * S + s0 + sc;
        *reinterpret_cast<u16x8*>(vt + base) = o0;
        *reinterpret_cast<u16x8*>(vt + base + 8) = o1;
    }
}

// ---------------------------------------------------------------------------
// MFMA flash attention v6: 32x32 swapped-QK, permutation-free P packing
// (structure verified round 7). K now 2-split, QK 5-term:
// (k0,q0),(k0,q1),(k0,q2),(k1,q0),(k1,q1). V 2-split 2-term PV. Softmax
// lane-local, defer-max (log2 domain). Double-buffered global_load_lds
// staging: 64 KB LDS (K 2x8KB + V 2x8KB per buffer), one barrier per tile.
// ---------------------------------------------------------------------------
__global__ __launch_bounds__(256, 2) void attn_mfma6(const float* __restrict__ Qf,
                                                     const ushort* __restrict__ ksp,
                                                     const ushort* __restrict__ vtsp,
                                                     float* __restrict__ out) {
    // [buf][ K: 2*4096 | V: 2*4096 ] ushorts = 32 KB per buffer, 64 KB total
    __shared__ __align__(16) ushort SB[2][16384];

    const int tid = threadIdx.x;
    const int lane = tid & 63;
    const int w = tid >> 6;
    const int swz = (blockIdx.x & 7) * 64 + (blockIdx.x >> 3);   // 512 blocks, bijective
    const int bh = swz >> 4;
    const int qt = 15 - (swz & 15);        // big q-tiles first
    const int q0 = qt << 7;                // 128-row q tile
    const int qw0 = q0 + (w << 5);         // wave's 32 q rows
    const int hi = lane >> 5;
    const int ql = lane & 31;
    const int qg = qw0 + ql;               // lane's global q row
    const int lrow = lane >> 3;
    const int sl8 = ((lane & 7) ^ lrow) << 3;

    // ---- Q fragments: (1/8 * log2e) folded, 3 splits x 4 d-chunks ----
    bf16x8 qb[3][4];
    {
        const float* qp = Qf + ((size_t)bh * S + qg) * DH + (hi << 3);
#pragma unroll
        for (int dc = 0; dc < 4; ++dc) {
            const float4 f0 = *reinterpret_cast<const float4*>(qp + (dc << 4));
            const float4 f1 = *reinterpret_cast<const float4*>(qp + (dc << 4) + 4);
            const float xs[8] = {f0.x, f0.y, f0.z, f0.w, f1.x, f1.y, f1.z, f1.w};
#pragma unroll
            for (int e = 0; e < 8; ++e) {
                const float x = xs[e] * 0.18033688011112042f;   // 1/8 * log2(e)
                const ushort h0 = f2bf(x);
                const float r1 = x - bf2f(h0);
                const ushort h1 = f2bf(r1);
                qb[0][dc][e] = (short)h0;
                qb[1][dc][e] = (short)h1;
                qb[2][dc][e] = (short)f2bf(r1 - bf2f(h1));
            }
        }
    }

    f32x16 O[2];
#pragma unroll
    for (int ds = 0; ds < 2; ++ds)
#pragma unroll
        for (int r = 0; r < 16; ++r) O[ds][r] = 0.f;
    float m_ = -INFINITY, l_ = 0.f;

    const size_t kbase = (size_t)bh * S * DH;
    const size_t vbase = (size_t)bh * DH * S;

#define ISSUE_KV(K0, BUF)                                                               \
    {                                                                                   \
        _Pragma("unroll")                                                               \
        for (int i = 0; i < 8; ++i) {                                                   \
            const int u = (i << 2) | w;                                                 \
            const ushort* gp;                                                           \
            if (u < 16) {                                                               \
                const int sp = u >> 3, rb = u & 7;                                      \
                gp = ksp + (size_t)sp * ASTRIDE + kbase +                               \
                     (size_t)((K0) + (rb << 3) + lrow) * DH + sl8;                      \
            } else {                                                                    \
                const int v_ = u - 16;                                                  \
                const int sp = v_ >> 3, rb = v_ & 7;                                    \
                gp = vtsp + (size_t)sp * ASTRIDE + vbase +                              \
                     (size_t)((rb << 3) + lrow) * S + (K0) + sl8;                       \
            }                                                                           \
            __builtin_amdgcn_global_load_lds(gp, &SB[BUF][u * 512], 16, 0, 0);          \
        }                                                                               \
    }

    ISSUE_KV(0, 0);
    __syncthreads();

    const int ktmax = (q0 >> 6) + 1;
    for (int kt = 0; kt <= ktmax; ++kt) {
        const int k0 = kt << 6;
        const int cur = kt & 1;
        if (kt < ktmax) ISSUE_KV(k0 + 64, cur ^ 1);   // prefetch under compute

        const bool active = (k0 <= qw0 + 31);          // wave-uniform
        if (active) {
            const ushort* KL = &SB[cur][0];
            const ushort* VL = &SB[cur][8192];

            // ---- S^T = K Q^T (64k x 32q per wave, 5 split terms) ----
            f32x16 Sf[2];
#pragma unroll
            for (int ks = 0; ks < 2; ++ks)
#pragma unroll
                for (int r = 0; r < 16; ++r) Sf[ks][r] = 0.f;
#pragma unroll
            for (int ks = 0; ks < 2; ++ks) {
#pragma unroll
                for (int dc = 0; dc < 4; ++dc) {
                    const int row = (ks << 5) + ql;
                    const int eo = row * 64 + ((((dc << 1) | hi) ^ (row & 7)) << 3);
                    const bf16x8 ka = *reinterpret_cast<const bf16x8*>(&KL[eo]);
                    const bf16x8 kb = *reinterpret_cast<const bf16x8*>(&KL[4096 + eo]);
                    Sf[ks] = mfma32(ka, qb[0][dc], Sf[ks]);
                    Sf[ks] = mfma32(ka, qb[1][dc], Sf[ks]);
                    Sf[ks] = mfma32(ka, qb[2][dc], Sf[ks]);
                    Sf[ks] = mfma32(kb, qb[0][dc], Sf[ks]);
                    Sf[ks] = mfma32(kb, qb[1][dc], Sf[ks]);
                }
            }

            // ---- causal mask (only near-diagonal tiles) ----
            if (k0 + 63 > qw0) {
#pragma unroll
                for (int ks = 0; ks < 2; ++ks)
#pragma unroll
                    for (int r = 0; r < 16; ++r) {
                        const int kg = k0 + (ks << 5) + (r & 3) + ((r >> 2) << 3) + (hi << 2);
                        if (kg > qg) Sf[ks][r] = -1e30f;
                    }
            }

            // ---- lane-local softmax with defer-max ----
            float rm = Sf[0][0];
#pragma unroll
            for (int ks = 0; ks < 2; ++ks)
#pragma unroll
                for (int r = 0; r < 16; ++r) rm = fmaxf(rm, Sf[ks][r]);
            rm = fmaxf(rm, __shfl_xor(rm, 32));
            if (__any(rm > m_ + 8.f)) {
                const float nm = fmaxf(m_, rm);
                const float sc = exp2fast(m_ - nm);
                m_ = nm;
                l_ *= sc;
#pragma unroll
                for (int ds = 0; ds < 2; ++ds)
#pragma unroll
                    for (int r = 0; r < 16; ++r) O[ds][r] *= sc;
            }

            // ---- P = 2^(S - m), sum, in-order in-register B-frag packing ----
            float rs = 0.f;
            bf16x8 pb[4];
#pragma unroll
            for (int ks = 0; ks < 2; ++ks) {
                float p[16];
#pragma unroll
                for (int r = 0; r < 16; ++r) {
                    p[r] = exp2fast(Sf[ks][r] - m_);
                    rs += p[r];
                }
#pragma unroll
                for (int c = 0; c < 2; ++c) {
                    union { unsigned u[4]; bf16x8 v; } pw;
                    pw.u[0] = cvt_pk(p[(c << 3) + 0], p[(c << 3) + 1]);
                    pw.u[1] = cvt_pk(p[(c << 3) + 2], p[(c << 3) + 3]);
                    pw.u[2] = cvt_pk(p[(c << 3) + 4], p[(c << 3) + 5]);
                    pw.u[3] = cvt_pk(p[(c << 3) + 6], p[(c << 3) + 7]);
                    pb[(ks << 1) + c] = pw.v;
                }
            }
            rs += __shfl_xor(rs, 32);
            l_ += rs;

            // ---- O^T += V^T P^T ----
#pragma unroll
            for (int sp = 0; sp < 2; ++sp)
#pragma unroll
                for (int ds = 0; ds < 2; ++ds)
#pragma unroll
                    for (int kc = 0; kc < 4; ++kc) {
                        const int row = (ds << 5) + ql;
                        const int eo = sp * 4096 + row * 64 + ((((kc << 1) | hi) ^ (row & 7)) << 3);
                        const bf16x8 va = *reinterpret_cast<const bf16x8*>(&VL[eo]);
                        O[ds] = mfma32(va, pb[kc], O[ds]);
                    }
        }
        __syncthreads();   // compute(cur) done AND prefetch(cur^1) drained
    }

    // ---- epilogue: O^T[d, q] -> out[b, q, h*64 + d] ----
    const float inv = 1.f / l_;
    const int b = bh >> 4, h = bh & (NH - 1);
    float* op = out + ((size_t)(b * S + qg)) * DOUT + h * DH;
#pragma unroll
    for (int ds = 0; ds < 2; ++ds)
#pragma unroll
        for (int rg = 0; rg < 4; ++rg) {
            float4 v;
            v.x = O[ds][(rg << 2) + 0] * inv;
            v.y = O[ds][(rg << 2) + 1] * inv;
            v.z = O[ds][(rg << 2) + 2] * inv;
            v.w = O[ds][(rg << 2) + 3] * inv;
            *reinterpret_cast<float4*>(&op[(ds << 5) + (rg << 3) + (hi << 2)]) = v;
        }
#undef ISSUE_KV
}

// ===========================================================================
// FALLBACK (fp32, ws >= 48 MB)
// ===========================================================================
__global__ __launch_bounds__(256) void proj_f32(const float* __restrict__ A,
                                                const float* __restrict__ W,
                                                float* __restrict__ outf) {
    __shared__ float As[16][68];
    __shared__ float Bs[16][68];
    const int tid = threadIdx.x;
    const int m0 = blockIdx.x * 64;
    const int n0 = blockIdx.y * 64;
    const int tm = tid >> 4, tn = tid & 15;
    const int la_r = tid >> 2, la_c = (tid & 3) << 2;
    const int lb_r = tid >> 4, lb_c = (tid & 15) << 2;

    float acc[4][4];
#pragma unroll
    for (int i = 0; i < 4; ++i)
#pragma unroll
        for (int j = 0; j < 4; ++j) acc[i][j] = 0.f;

    for (int k0 = 0; k0 < DIN; k0 += 16) {
        const float4 av = *reinterpret_cast<const float4*>(&A[(size_t)(m0 + la_r) * DIN + k0 + la_c]);
        const float4 bv = *reinterpret_cast<const float4*>(&W[(size_t)(k0 + lb_r) * DOUT + n0 + lb_c]);
        __syncthreads();
        As[la_c + 0][la_r] = av.x; As[la_c + 1][la_r] = av.y;
        As[la_c + 2][la_r] = av.z; As[la_c + 3][la_r] = av.w;
        *reinterpret_cast<float4*>(&Bs[lb_r][lb_c]) = bv;
        __syncthreads();
#pragma unroll
        for (int kk = 0; kk < 16; ++kk) {
            const float4 a = *reinterpret_cast<const float4*>(&As[kk][tm << 2]);
            const float4 b = *reinterpret_cast<const float4*>(&Bs[kk][tn << 2]);
            const float aa[4] = {a.x, a.y, a.z, a.w};
            const float bb[4] = {b.x, b.y, b.z, b.w};
#pragma unroll
            for (int i = 0; i < 4; ++i)
#pragma unroll
                for (int j = 0; j < 4; ++j) acc[i][j] += aa[i] * bb[j];
        }
    }
    const int b = m0 >> 11;
    const int s_base = (m0 & (S - 1)) + (tm << 2);
    const int h = n0 >> 6;
    const int dh = tn << 2;
    float* obase = outf + ((size_t)(b * NH + h) * S) * DH;
#pragma unroll
    for (int i = 0; i < 4; ++i) {
        float4 v;
        v.x = acc[i][0]; v.y = acc[i][1]; v.z = acc[i][2]; v.w = acc[i][3];
        *reinterpret_cast<float4*>(&obase[(size_t)(s_base + i) * DH + dh]) = v;
    }
}

__global__ __launch_bounds__(256) void attn_f32(const float* __restrict__ Q,
                                                const float* __restrict__ K,
                                                const float* __restrict__ V,
                                                float* __restrict__ out) {
    __shared__ float Qs[64][68];
    __shared__ float Ks[64][68];
    __shared__ float Vs[64][68];
    __shared__ float Ps[64][68];
    const int tid = threadIdx.x;
    const int bh = blockIdx.x & 31;
    const int qt = 31 - (blockIdx.x >> 5);
    const int q0 = qt << 6;
    const int tq = tid >> 4, tk = tid & 15;
    const int sr = tid >> 2, sc = (tid & 3) << 2;

    const float* qbase = Q + ((size_t)bh * S + q0) * DH;
    const float* kbase = K + (size_t)bh * S * DH;
    const float* vbase = V + (size_t)bh * S * DH;
#pragma unroll
    for (int it = 0; it < 4; ++it) {
        const int d0 = sc + (it << 4);
        const float4 v = *reinterpret_cast<const float4*>(&qbase[(size_t)sr * DH + d0]);
        Qs[d0 + 0][sr] = v.x; Qs[d0 + 1][sr] = v.y;
        Qs[d0 + 2][sr] = v.z; Qs[d0 + 3][sr] = v.w;
    }
    float C[4][4];
#pragma unroll
    for (int i = 0; i < 4; ++i)
#pragma unroll
        for (int j = 0; j < 4; ++j) C[i][j] = 0.f;
    float m[4] = {-1e30f, -1e30f, -1e30f, -1e30f};
    float l[4] = {0.f, 0.f, 0.f, 0.f};

    for (int kt = 0; kt <= qt; ++kt) {
        const int k0 = kt << 6;
        float4 kv[4], vv[4];
#pragma unroll
        for (int it = 0; it < 4; ++it) {
            const int d0 = sc + (it << 4);
            kv[it] = *reinterpret_cast<const float4*>(&kbase[(size_t)(k0 + sr) * DH + d0]);
            vv[it] = *reinterpret_cast<const float4*>(&vbase[(size_t)(k0 + sr) * DH + d0]);
        }
        __syncthreads();
#pragma unroll
        for (int it = 0; it < 4; ++it) {
            const int d0 = sc + (it << 4);
            Ks[d0 + 0][sr] = kv[it].x; Ks[d0 + 1][sr] = kv[it].y;
            Ks[d0 + 2][sr] = kv[it].z; Ks[d0 + 3][sr] = kv[it].w;
            *reinterpret_cast<float4*>(&Vs[sr][d0]) = vv[it];
        }
        __syncthreads();

        float s[4][4];
#pragma unroll
        for (int i = 0; i < 4; ++i)
#pragma unroll
            for (int j = 0; j < 4; ++j) s[i][j] = 0.f;
#pragma unroll 16
        for (int d = 0; d < 64; ++d) {
            const float4 qf4 = *reinterpret_cast<const float4*>(&Qs[d][tq << 2]);
            const float4 kf4 = *reinterpret_cast<const float4*>(&Ks[d][tk << 2]);
            const float qa[4] = {qf4.x, qf4.y, qf4.z, qf4.w};
            const float ka[4] = {kf4.x, kf4.y, kf4.z, kf4.w};
#pragma unroll
            for (int i = 0; i < 4; ++i)
#pragma unroll
                for (int j = 0; j < 4; ++j) s[i][j] += qa[i] * ka[j];
        }
        if (kt == qt) {
#pragma unroll
            for (int i = 0; i < 4; ++i) {
                const int qg = q0 + (tq << 2) + i;
#pragma unroll
                for (int j = 0; j < 4; ++j) {
                    const int kg = k0 + (tk << 2) + j;
                    s[i][j] = (kg <= qg) ? s[i][j] * 0.125f : -1e30f;
                }
            }
        } else {
#pragma unroll
            for (int i = 0; i < 4; ++i)
#pragma unroll
                for (int j = 0; j < 4; ++j) s[i][j] *= 0.125f;
        }
#pragma unroll
        for (int i = 0; i < 4; ++i) {
            float rm = fmaxf(fmaxf(s[i][0], s[i][1]), fmaxf(s[i][2], s[i][3]));
#pragma unroll
            for (int off = 1; off < 16; off <<= 1) rm = fmaxf(rm, __shfl_xor(rm, off));
            const float mn = fmaxf(m[i], rm);
            const float scale = __expf(m[i] - mn);
            float rs = 0.f;
#pragma unroll
            for (int j = 0; j < 4; ++j) {
                s[i][j] = __expf(s[i][j] - mn);
                rs += s[i][j];
            }
#pragma unroll
            for (int off = 1; off < 16; off <<= 1) rs += __shfl_xor(rs, off);
            l[i] = l[i] * scale + rs;
            m[i] = mn;
#pragma unroll
            for (int j = 0; j < 4; ++j) C[i][j] *= scale;
            *reinterpret_cast<float4*>(&Ps[(tq << 2) + i][tk << 2]) =
                make_float4(s[i][0], s[i][1], s[i][2], s[i][3]);
        }
        __syncthreads();
#pragma unroll 4
        for (int kc = 0; kc < 16; ++kc) {
            float4 pf[4], vf[4];
#pragma unroll
            for (int i = 0; i < 4; ++i)
                pf[i] = *reinterpret_cast<const float4*>(&Ps[(tq << 2) + i][kc << 2]);
#pragma unroll
            for (int j = 0; j < 4; ++j)
                vf[j] = *reinterpret_cast<const float4*>(&Vs[(kc << 2) + j][tk << 2]);
#pragma unroll
            for (int i = 0; i < 4; ++i) {
                const float pa[4] = {pf[i].x, pf[i].y, pf[i].z, pf[i].w};
#pragma unroll
                for (int j = 0; j < 4; ++j) {
                    C[i][j] += pa[0] * ((const float*)&vf[0])[j]
                             + pa[1] * ((const float*)&vf[1])[j]
                             + pa[2] * ((const float*)&vf[2])[j]
                             + pa[3] * ((const float*)&vf[3])[j];
                }
            }
        }
        __syncthreads();
    }
    const int b = bh >> 4, h = bh & (NH - 1);
#pragma unroll
    for (int i = 0; i < 4; ++i) {
        const int qg = q0 + (tq << 2) + i;
        const float inv = 1.f / l[i];
        float4 v;
        v.x = C[i][0] * inv; v.y = C[i][1] * inv;
        v.z = C[i][2] * inv; v.w = C[i][3] * inv;
        *reinterpret_cast<float4*>(&out[((size_t)(b * S + qg)) * DOUT + h * DH + (tk << 2)]) = v;
    }
}

// ===========================================================================
extern "C" void kernel_launch(void* const* d_in, const int* in_sizes, int n_in,
                              void* d_out, int out_size, void* d_ws, size_t ws_size,
                              hipStream_t stream) {
    const float* x  = (const float*)d_in[0];
    const float* Wq = (const float*)d_in[1];
    const float* Wk = (const float*)d_in[2];
    const float* Wv = (const float*)d_in[3];
    float* out = (float*)d_out;

    char* ws = (char*)d_ws;
    const size_t MB = 1024 * 1024;

    if (ws_size >= 76 * MB) {
        // layout: wT[0,12) | xsp 2-split[12,28) (later reused as VT[12,28)) |
        //         Q[28,44) | K 2-split[44,60) | Vtmp 2-split[60,76)
        ushort* wtsp = (ushort*)(ws);
        ushort* xsp  = (ushort*)(ws + 12 * MB);
        float*  qf   = (float*)(ws + 28 * MB);
        ushort* ksp  = (ushort*)(ws + 44 * MB);
        ushort* vsp  = (ushort*)(ws + 60 * MB);
        ushort* vtsp = (ushort*)(ws + 12 * MB);   // overwrites xsp (dead after proj)

        split_x<<<4096, 256, 0, stream>>>(x, xsp);
        split_wT3<<<dim3(16, 16, 3), 256, 0, stream>>>(Wq, Wk, Wv, wtsp);
        proj_fused2<<<512, 256, 0, stream>>>(xsp, wtsp, qf, ksp, vsp);
        transpose_v<<<1024, 256, 0, stream>>>(vsp, vtsp);
        attn_mfma6<<<512, 256, 0, stream>>>(qf, ksp, vtsp, out);
    } else {
        // fp32 fallback (48 MB)
        float* qws = (float*)d_ws;
        float* kws = qws + (size_t)M_TOT * DOUT;
        float* vws = kws + (size_t)M_TOT * DOUT;
        dim3 pgrid(M_TOT / 64, DOUT / 64);
        proj_f32<<<pgrid, 256, 0, stream>>>(x, Wq, qws);
        proj_f32<<<pgrid, 256, 0, stream>>>(x, Wk, kws);
        proj_f32<<<pgrid, 256, 0, stream>>>(x, Wv, vws);
        attn_f32<<<32 * 32, 256, 0, stream>>>(qws, kws, vws, out);
    }
}

// Round 9
// 144.468 us; speedup vs baseline: 28.3682x; 1.2585x over previous
//
#include <hip/hip_runtime.h>
#include <hip/hip_bf16.h>

// Problem constants: B=2, S=2048, D_IN=1024, D_OUT=1024, H=16, Dh=64
#define B 2
#define S 2048
#define DIN 1024
#define DOUT 1024
#define NH 16
#define DH 64
#define M_TOT (B * S)   // 4096

typedef __attribute__((ext_vector_type(8))) short bf16x8;
typedef __attribute__((ext_vector_type(8))) unsigned short u16x8;
typedef __attribute__((ext_vector_type(4))) float f32x4;
typedef __attribute__((ext_vector_type(16))) float f32x16;

#define ASTRIDE 4194304   // elements per 4096x1024 split array
#define WSTRIDE 1048576   // elements per 1024x1024 split array

__device__ __forceinline__ ushort f2bf(float x) {
    union { float f; unsigned u; } c; c.f = x;
    unsigned r = (c.u + 0x7FFFu + ((c.u >> 16) & 1u)) >> 16;
    return (ushort)r;
}
__device__ __forceinline__ float bf2f(ushort h) {
    union { unsigned u; float f; } c; c.u = ((unsigned)h) << 16;
    return c.f;
}
__device__ __forceinline__ f32x4 mfma16(bf16x8 a, bf16x8 b, f32x4 c) {
    return __builtin_amdgcn_mfma_f32_16x16x32_bf16(a, b, c, 0, 0, 0);
}
__device__ __forceinline__ f32x16 mfma32(bf16x8 a, bf16x8 b, f32x16 c) {
    return __builtin_amdgcn_mfma_f32_32x32x16_bf16(a, b, c, 0, 0, 0);
}
__device__ __forceinline__ unsigned cvt_pk(float lo, float hi) {
    unsigned r;
    asm("v_cvt_pk_bf16_f32 %0, %1, %2" : "=v"(r) : "v"(lo), "v"(hi));
    return r;
}
__device__ __forceinline__ float exp2fast(float x) {
    float r;
    asm("v_exp_f32 %0, %1" : "=v"(r) : "v"(x));
    return r;
}

// ===========================================================================
// MAIN PATH (ws >= 68 MB)
// ===========================================================================

// ---- prepass: x (fp32 [4096][1024]) -> 2-way bf16 splits ----
__global__ __launch_bounds__(256) void split_x(const float* __restrict__ x,
                                               ushort* __restrict__ xs) {
    const size_t gid = (size_t)blockIdx.x * 256 + threadIdx.x;
    const float4 v = *reinterpret_cast<const float4*>(x + gid * 4);
    const float in[4] = {v.x, v.y, v.z, v.w};
    ushort h0[4], h1[4];
#pragma unroll
    for (int e = 0; e < 4; ++e) {
        h0[e] = f2bf(in[e]);
        h1[e] = f2bf(in[e] - bf2f(h0[e]));
    }
    const size_t o = gid * 4;
    *reinterpret_cast<ushort4*>(xs + o)           = ushort4{h0[0], h0[1], h0[2], h0[3]};
    *reinterpret_cast<ushort4*>(xs + ASTRIDE + o) = ushort4{h1[0], h1[1], h1[2], h1[3]};
}

// ---- prepass: all three W -> W^T 2-way bf16 splits, wt[wi][sp][n][k] ----
__global__ __launch_bounds__(256) void split_wT3(const float* __restrict__ W0,
                                                 const float* __restrict__ W1,
                                                 const float* __restrict__ W2,
                                                 ushort* __restrict__ wt) {
    __shared__ float Ws[64][68];
    const int tid = threadIdx.x;
    const int k0 = blockIdx.x << 6;
    const int n0 = blockIdx.y << 6;
    const int wi = blockIdx.z;
    const float* W = (wi == 0) ? W0 : (wi == 1) ? W1 : W2;
    ushort* wto = wt + (size_t)wi * 2 * WSTRIDE;

    const int r = tid >> 2;
    const int cb = (tid & 3) << 2;
#pragma unroll
    for (int it = 0; it < 4; ++it) {
        const int c = cb + (it << 4);
        *reinterpret_cast<float4*>(&Ws[r][c]) =
            *reinterpret_cast<const float4*>(&W[(size_t)(k0 + r) * 1024 + n0 + c]);
    }
    __syncthreads();
    const int rn = tid >> 2;
    const int kc = (tid & 3) << 4;
    u16x8 o0[2], o1[2];
#pragma unroll
    for (int half = 0; half < 2; ++half)
#pragma unroll
        for (int i = 0; i < 8; ++i) {
            const float x = Ws[kc + (half << 3) + i][rn];
            const ushort a = f2bf(x);
            o0[half][i] = a;
            o1[half][i] = f2bf(x - bf2f(a));
        }
    const size_t base = (size_t)(n0 + rn) * 1024 + k0 + kc;
    *reinterpret_cast<u16x8*>(wto + base)               = o0[0];
    *reinterpret_cast<u16x8*>(wto + base + 8)           = o0[1];
    *reinterpret_cast<u16x8*>(wto + WSTRIDE + base)     = o1[0];
    *reinterpret_cast<u16x8*>(wto + WSTRIDE + base + 8) = o1[1];
}

// ---------------------------------------------------------------------------
// Fused QKV projection v3: 128(M)x64(N) tile; Q/K 4-term ((x0+x1)(w0+w1)),
// V 2-term ((x0+x1)w0). Q fp32 out, K 2-split out ([bh][s][d]).
// V is TRANSPOSED IN-BLOCK via LDS and written bf16 1-split directly to
// vt[bh][d][s'] with the 4-elem granule permutation [0,2,1,3] per 16-s block
// (matches attention's permutation-free P packing; replicates transpose_v).
// LDS 72 KB staging, reused as fp32 [64][132] for the V transpose.
// ---------------------------------------------------------------------------
__global__ __launch_bounds__(256, 2) void proj_fused3(const ushort* __restrict__ xsp,
                                                      const ushort* __restrict__ wtsp,
                                                      float* __restrict__ qf,
                                                      ushort* __restrict__ ksp,
                                                      ushort* __restrict__ vtsp) {
    __shared__ __align__(16) ushort SL[36864];   // 72 KB

    const int tid = threadIdx.x;
    const int lane = tid & 63;
    const int w = tid >> 6;
    const int swz = (blockIdx.x & 7) * 64 + (blockIdx.x >> 3);   // 512 blocks, bijective
    const int n0 = (swz & 15) << 6;
    const int m0 = (swz >> 4) << 7;   // 32 m-tiles of 128
    const int col = lane & 15;
    const int glane = lane >> 4;
    const int lrow = lane >> 3;
    const int sl8 = ((lane & 7) ^ lrow) << 3;

    f32x4 accq[2][4], acck[2][4], accv[2][4];   // [mi][nj]
#pragma unroll
    for (int mi = 0; mi < 2; ++mi)
#pragma unroll
        for (int nj = 0; nj < 4; ++nj) {
            accq[mi][nj] = f32x4{0.f, 0.f, 0.f, 0.f};
            acck[mi][nj] = f32x4{0.f, 0.f, 0.f, 0.f};
            accv[mi][nj] = f32x4{0.f, 0.f, 0.f, 0.f};
        }

    for (int k0 = 0; k0 < DIN; k0 += 64) {
        __syncthreads();   // previous step's LDS reads done
#pragma unroll
        for (int i = 0; i < 18; ++i) {
            const int u = (i << 2) | w;          // 0..71
            const ushort* g;
            if (u < 32) {
                const int sp = u >> 4, rb = u & 15;
                g = xsp + (size_t)sp * ASTRIDE + (size_t)(m0 + (rb << 3) + lrow) * 1024 + k0 + sl8;
            } else {
                const int v = u - 32;            // 0..39
                const int bi = v >> 3;           // 0..4 = Wq0,Wq1,Wk0,Wk1,Wv0
                const int rb = v & 7;
                g = wtsp + (size_t)bi * WSTRIDE + (size_t)(n0 + (rb << 3) + lrow) * 1024 + k0 + sl8;
            }
            __builtin_amdgcn_global_load_lds(g, &SL[u * 512], 16, 0, 0);
        }
        __syncthreads();   // staging drained + visible

#pragma unroll
        for (int st = 0; st < 2; ++st) {
            const int sw = (((st << 2) | glane) ^ (col & 7)) << 3;
            bf16x8 a[2][2];   // [sp][mi]
#pragma unroll
            for (int sp = 0; sp < 2; ++sp)
#pragma unroll
                for (int mi = 0; mi < 2; ++mi) {
                    const int arow = (w << 5) + (mi << 4) + col;
                    a[sp][mi] = *reinterpret_cast<const bf16x8*>(&SL[sp * 8192 + arow * 64 + sw]);
                }
#pragma unroll
            for (int nj = 0; nj < 4; ++nj) {
                const int brow = (nj << 4) + col;
                const int bb = 16384 + brow * 64 + sw;
                const bf16x8 bq0 = *reinterpret_cast<const bf16x8*>(&SL[bb]);
                const bf16x8 bq1 = *reinterpret_cast<const bf16x8*>(&SL[bb + 4096]);
                const bf16x8 bk0 = *reinterpret_cast<const bf16x8*>(&SL[bb + 8192]);
                const bf16x8 bk1 = *reinterpret_cast<const bf16x8*>(&SL[bb + 12288]);
                const bf16x8 bv0 = *reinterpret_cast<const bf16x8*>(&SL[bb + 16384]);
#pragma unroll
                for (int mi = 0; mi < 2; ++mi) {
                    accq[mi][nj] = mfma16(a[0][mi], bq0, accq[mi][nj]);
                    accq[mi][nj] = mfma16(a[1][mi], bq0, accq[mi][nj]);
                    accq[mi][nj] = mfma16(a[0][mi], bq1, accq[mi][nj]);
                    accq[mi][nj] = mfma16(a[1][mi], bq1, accq[mi][nj]);
                    acck[mi][nj] = mfma16(a[0][mi], bk0, acck[mi][nj]);
                    acck[mi][nj] = mfma16(a[1][mi], bk0, acck[mi][nj]);
                    acck[mi][nj] = mfma16(a[0][mi], bk1, acck[mi][nj]);
                    acck[mi][nj] = mfma16(a[1][mi], bk1, acck[mi][nj]);
                    accv[mi][nj] = mfma16(a[0][mi], bv0, accv[mi][nj]);
                    accv[mi][nj] = mfma16(a[1][mi], bv0, accv[mi][nj]);
                }
            }
        }
    }

    // ---- epilogue: Q fp32, K 2-split to [bh][s][d] ----
    const int b = m0 >> 11;
    const int h = n0 >> 6;
    const size_t bh_off = (size_t)(b * NH + h) * S * DH;
#pragma unroll
    for (int mi = 0; mi < 2; ++mi)
#pragma unroll
        for (int r = 0; r < 4; ++r) {
            const int srow = (m0 & (S - 1)) + (w << 5) + (mi << 4) + (glane << 2) + r;
#pragma unroll
            for (int nj = 0; nj < 4; ++nj) {
                const size_t o = bh_off + (size_t)srow * DH + (nj << 4) + col;
                qf[o] = accq[mi][nj][r];
                const float xk = acck[mi][nj][r];
                const ushort k0s = f2bf(xk);
                ksp[o] = k0s;
                ksp[ASTRIDE + o] = f2bf(xk - bf2f(k0s));
            }
        }

    // ---- V: transpose in LDS, write bf16 granule-permuted [bh][d][s'] ----
    float* SLf = reinterpret_cast<float*>(SL);
    __syncthreads();   // all staging reads done; SL reusable
#pragma unroll
    for (int mi = 0; mi < 2; ++mi)
#pragma unroll
        for (int r = 0; r < 4; ++r) {
            const int sl_ = (w << 5) + (mi << 4) + (glane << 2) + r;
#pragma unroll
            for (int nj = 0; nj < 4; ++nj)
                SLf[((nj << 4) + col) * 132 + sl_] = accv[mi][nj][r];
        }
    __syncthreads();
    {
        const int d = tid >> 2;
        const size_t vb = ((size_t)(b * NH + h) * DH + d) * S + (m0 & (S - 1));
#pragma unroll
        for (int blk = 0; blk < 2; ++blk) {
            const int sb = ((tid & 3) << 5) + (blk << 4);
            u16x8 oA, oB;
#pragma unroll
            for (int i = 0; i < 8; ++i) {
                const int jA = (i < 4) ? i : i + 4;       // out col i     <- in sb+jA
                const int jB = (i < 4) ? i + 4 : i + 8;   // out col 8+i   <- in sb+jB
                oA[i] = f2bf(SLf[d * 132 + sb + jA]);
                oB[i] = f2bf(SLf[d * 132 + sb + jB]);
            }
            *reinterpret_cast<u16x8*>(vtsp + vb + sb)     = oA;
            *reinterpret_cast<u16x8*>(vtsp + vb + sb + 8) = oB;
        }
    }
}

// ---------------------------------------------------------------------------
// MFMA flash attention v7: 32x32 swapped-QK, permutation-free P packing
// (verified r7/r8). K 2-split (5-term QK), V bf16 1-split (8 PV MFMA).
// LOAD-BALANCED grid: each XCD chunk of 64 blocks pairs (qt, 15-qt) on the
// same CU slot (u and u+32), so every CU does ~34 tile-works.
// Double-buffered global_load_lds staging: 48 KB LDS total, 1 barrier/tile.
// Tree-structured softmax reductions.
// ---------------------------------------------------------------------------
__global__ __launch_bounds__(256, 2) void attn_mfma7(const float* __restrict__ Qf,
                                                     const ushort* __restrict__ ksp,
                                                     const ushort* __restrict__ vtsp,
                                                     float* __restrict__ out) {
    // [buf][ K0: 4096 | K1: 4096 | V: 4096 ] ushorts = 24 KB/buf, 48 KB total
    __shared__ __align__(16) ushort SB[2][12288];

    const int tid = threadIdx.x;
    const int lane = tid & 63;
    const int w = tid >> 6;

    // balanced bijective mapping: XCD x owns bh in [4x,4x+4); within an XCD's
    // 64 blocks, block u and u+32 (same CU slot) get qt and 15-qt.
    const int xcd = blockIdx.x & 7;
    const int u_ = blockIdx.x >> 3;   // 0..63
    int bh, qt;
    if (u_ < 32) { bh = (xcd << 2) | (u_ >> 4);                 qt = 15 - (u_ & 15); }
    else         { const int v2 = u_ - 32; bh = (xcd << 2) | 2 | (v2 >> 4); qt = v2 & 15; }

    const int q0 = qt << 7;                // 128-row q tile
    const int qw0 = q0 + (w << 5);         // wave's 32 q rows
    const int hi = lane >> 5;
    const int ql = lane & 31;
    const int qg = qw0 + ql;               // lane's global q row
    const int lrow = lane >> 3;
    const int sl8 = ((lane & 7) ^ lrow) << 3;

    // ---- Q fragments: (1/8 * log2e) folded, 3 splits x 4 d-chunks ----
    bf16x8 qb[3][4];
    {
        const float* qp = Qf + ((size_t)bh * S + qg) * DH + (hi << 3);
#pragma unroll
        for (int dc = 0; dc < 4; ++dc) {
            const float4 f0 = *reinterpret_cast<const float4*>(qp + (dc << 4));
            const float4 f1 = *reinterpret_cast<const float4*>(qp + (dc << 4) + 4);
            const float xs[8] = {f0.x, f0.y, f0.z, f0.w, f1.x, f1.y, f1.z, f1.w};
#pragma unroll
            for (int e = 0; e < 8; ++e) {
                const float x = xs[e] * 0.18033688011112042f;   // 1/8 * log2(e)
                const ushort h0 = f2bf(x);
                const float r1 = x - bf2f(h0);
                const ushort h1 = f2bf(r1);
                qb[0][dc][e] = (short)h0;
                qb[1][dc][e] = (short)h1;
                qb[2][dc][e] = (short)f2bf(r1 - bf2f(h1));
            }
        }
    }

    f32x16 O[2];
#pragma unroll
    for (int ds = 0; ds < 2; ++ds)
#pragma unroll
        for (int r = 0; r < 16; ++r) O[ds][r] = 0.f;
    float m_ = -INFINITY, l_ = 0.f;

    const size_t kbase = (size_t)bh * S * DH;
    const size_t vbase = (size_t)bh * DH * S;

#define ISSUE_KV(K0, BUF)                                                               \
    {                                                                                   \
        _Pragma("unroll")                                                               \
        for (int i = 0; i < 6; ++i) {                                                   \
            const int u = (i << 2) | w;                                                 \
            const ushort* gp;                                                           \
            if (u < 16) {                                                               \
                const int sp = u >> 3, rb = u & 7;                                      \
                gp = ksp + (size_t)sp * ASTRIDE + kbase +                               \
                     (size_t)((K0) + (rb << 3) + lrow) * DH + sl8;                      \
            } else {                                                                    \
                const int rb = u & 7;                                                   \
                gp = vtsp + vbase + (size_t)((rb << 3) + lrow) * S + (K0) + sl8;        \
            }                                                                           \
            __builtin_amdgcn_global_load_lds(gp, &SB[BUF][u * 512], 16, 0, 0);          \
        }                                                                               \
    }

    ISSUE_KV(0, 0);
    __syncthreads();

    const int ktmax = (q0 >> 6) + 1;
    for (int kt = 0; kt <= ktmax; ++kt) {
        const int k0 = kt << 6;
        const int cur = kt & 1;
        if (kt < ktmax) ISSUE_KV(k0 + 64, cur ^ 1);   // prefetch under compute

        const bool active = (k0 <= qw0 + 31);          // wave-uniform
        if (active) {
            const ushort* KL = &SB[cur][0];
            const ushort* VL = &SB[cur][8192];

            // ---- S^T = K Q^T (64k x 32q per wave, 5 split terms) ----
            f32x16 Sf[2];
#pragma unroll
            for (int ks = 0; ks < 2; ++ks)
#pragma unroll
                for (int r = 0; r < 16; ++r) Sf[ks][r] = 0.f;
#pragma unroll
            for (int ks = 0; ks < 2; ++ks) {
#pragma unroll
                for (int dc = 0; dc < 4; ++dc) {
                    const int row = (ks << 5) + ql;
                    const int eo = row * 64 + ((((dc << 1) | hi) ^ (row & 7)) << 3);
                    const bf16x8 ka = *reinterpret_cast<const bf16x8*>(&KL[eo]);
                    const bf16x8 kb = *reinterpret_cast<const bf16x8*>(&KL[4096 + eo]);
                    Sf[ks] = mfma32(ka, qb[0][dc], Sf[ks]);
                    Sf[ks] = mfma32(ka, qb[1][dc], Sf[ks]);
                    Sf[ks] = mfma32(ka, qb[2][dc], Sf[ks]);
                    Sf[ks] = mfma32(kb, qb[0][dc], Sf[ks]);
                    Sf[ks] = mfma32(kb, qb[1][dc], Sf[ks]);
                }
            }

            // ---- causal mask (only near-diagonal tiles) ----
            if (k0 + 63 > qw0) {
#pragma unroll
                for (int ks = 0; ks < 2; ++ks)
#pragma unroll
                    for (int r = 0; r < 16; ++r) {
                        const int kg = k0 + (ks << 5) + (r & 3) + ((r >> 2) << 3) + (hi << 2);
                        if (kg > qg) Sf[ks][r] = -1e30f;
                    }
            }

            // ---- lane-local softmax, tree max, defer-max ----
            float mx[8];
#pragma unroll
            for (int i = 0; i < 8; ++i)
                mx[i] = fmaxf(fmaxf(Sf[0][i], Sf[0][i + 8]),
                              fmaxf(Sf[1][i], Sf[1][i + 8]));
            float rm = fmaxf(fmaxf(fmaxf(mx[0], mx[1]), fmaxf(mx[2], mx[3])),
                             fmaxf(fmaxf(mx[4], mx[5]), fmaxf(mx[6], mx[7])));
            rm = fmaxf(rm, __shfl_xor(rm, 32));
            if (__any(rm > m_ + 8.f)) {
                const float nm = fmaxf(m_, rm);
                const float sc = exp2fast(m_ - nm);
                m_ = nm;
                l_ *= sc;
#pragma unroll
                for (int ds = 0; ds < 2; ++ds)
#pragma unroll
                    for (int r = 0; r < 16; ++r) O[ds][r] *= sc;
            }

            // ---- P = 2^(S - m), tree sum, in-order B-frag packing ----
            float rsa[4] = {0.f, 0.f, 0.f, 0.f};
            bf16x8 pb[4];
#pragma unroll
            for (int ks = 0; ks < 2; ++ks) {
                float p[16];
#pragma unroll
                for (int r = 0; r < 16; ++r) {
                    p[r] = exp2fast(Sf[ks][r] - m_);
                    rsa[r & 3] += p[r];
                }
#pragma unroll
                for (int c = 0; c < 2; ++c) {
                    union { unsigned u[4]; bf16x8 v; } pw;
                    pw.u[0] = cvt_pk(p[(c << 3) + 0], p[(c << 3) + 1]);
                    pw.u[1] = cvt_pk(p[(c << 3) + 2], p[(c << 3) + 3]);
                    pw.u[2] = cvt_pk(p[(c << 3) + 4], p[(c << 3) + 5]);
                    pw.u[3] = cvt_pk(p[(c << 3) + 6], p[(c << 3) + 7]);
                    pb[(ks << 1) + c] = pw.v;
                }
            }
            float rs = (rsa[0] + rsa[1]) + (rsa[2] + rsa[3]);
            rs += __shfl_xor(rs, 32);
            l_ += rs;

            // ---- O^T += V^T P^T (single V split) ----
#pragma unroll
            for (int ds = 0; ds < 2; ++ds)
#pragma unroll
                for (int kc = 0; kc < 4; ++kc) {
                    const int row = (ds << 5) + ql;
                    const int eo = row * 64 + ((((kc << 1) | hi) ^ (row & 7)) << 3);
                    const bf16x8 va = *reinterpret_cast<const bf16x8*>(&VL[eo]);
                    O[ds] = mfma32(va, pb[kc], O[ds]);
                }
        }
        __syncthreads();   // compute(cur) done AND prefetch(cur^1) drained
    }

    // ---- epilogue: O^T[d, q] -> out[b, q, h*64 + d] ----
    const float inv = 1.f / l_;
    const int b = bh >> 4, h = bh & (NH - 1);
    float* op = out + ((size_t)(b * S + qg)) * DOUT + h * DH;
#pragma unroll
    for (int ds = 0; ds < 2; ++ds)
#pragma unroll
        for (int rg = 0; rg < 4; ++rg) {
            float4 v;
            v.x = O[ds][(rg << 2) + 0] * inv;
            v.y = O[ds][(rg << 2) + 1] * inv;
            v.z = O[ds][(rg << 2) + 2] * inv;
            v.w = O[ds][(rg << 2) + 3] * inv;
            *reinterpret_cast<float4*>(&op[(ds << 5) + (rg << 3) + (hi << 2)]) = v;
        }
#undef ISSUE_KV
}

// ===========================================================================
// FALLBACK (fp32, ws >= 48 MB)
// ===========================================================================
__global__ __launch_bounds__(256) void proj_f32(const float* __restrict__ A,
                                                const float* __restrict__ W,
                                                float* __restrict__ outf) {
    __shared__ float As[16][68];
    __shared__ float Bs[16][68];
    const int tid = threadIdx.x;
    const int m0 = blockIdx.x * 64;
    const int n0 = blockIdx.y * 64;
    const int tm = tid >> 4, tn = tid & 15;
    const int la_r = tid >> 2, la_c = (tid & 3) << 2;
    const int lb_r = tid >> 4, lb_c = (tid & 15) << 2;

    float acc[4][4];
#pragma unroll
    for (int i = 0; i < 4; ++i)
#pragma unroll
        for (int j = 0; j < 4; ++j) acc[i][j] = 0.f;

    for (int k0 = 0; k0 < DIN; k0 += 16) {
        const float4 av = *reinterpret_cast<const float4*>(&A[(size_t)(m0 + la_r) * DIN + k0 + la_c]);
        const float4 bv = *reinterpret_cast<const float4*>(&W[(size_t)(k0 + lb_r) * DOUT + n0 + lb_c]);
        __syncthreads();
        As[la_c + 0][la_r] = av.x; As[la_c + 1][la_r] = av.y;
        As[la_c + 2][la_r] = av.z; As[la_c + 3][la_r] = av.w;
        *reinterpret_cast<float4*>(&Bs[lb_r][lb_c]) = bv;
        __syncthreads();
#pragma unroll
        for (int kk = 0; kk < 16; ++kk) {
            const float4 a = *reinterpret_cast<const float4*>(&As[kk][tm << 2]);
            const float4 b = *reinterpret_cast<const float4*>(&Bs[kk][tn << 2]);
            const float aa[4] = {a.x, a.y, a.z, a.w};
            const float bb[4] = {b.x, b.y, b.z, b.w};
#pragma unroll
            for (int i = 0; i < 4; ++i)
#pragma unroll
                for (int j = 0; j < 4; ++j) acc[i][j] += aa[i] * bb[j];
        }
    }
    const int b = m0 >> 11;
    const int s_base = (m0 & (S - 1)) + (tm << 2);
    const int h = n0 >> 6;
    const int dh = tn << 2;
    float* obase = outf + ((size_t)(b * NH + h) * S) * DH;
#pragma unroll
    for (int i = 0; i < 4; ++i) {
        float4 v;
        v.x = acc[i][0]; v.y = acc[i][1]; v.z = acc[i][2]; v.w = acc[i][3];
        *reinterpret_cast<float4*>(&obase[(size_t)(s_base + i) * DH + dh]) = v;
    }
}

__global__ __launch_bounds__(256) void attn_f32(const float* __restrict__ Q,
                                                const float* __restrict__ K,
                                                const float* __restrict__ V,
                                                float* __restrict__ out) {
    __shared__ float Qs[64][68];
    __shared__ float Ks[64][68];
    __shared__ float Vs[64][68];
    __shared__ float Ps[64][68];
    const int tid = threadIdx.x;
    const int bh = blockIdx.x & 31;
    const int qt = 31 - (blockIdx.x >> 5);
    const int q0 = qt << 6;
    const int tq = tid >> 4, tk = tid & 15;
    const int sr = tid >> 2, sc = (tid & 3) << 2;

    const float* qbase = Q + ((size_t)bh * S + q0) * DH;
    const float* kbase = K + (size_t)bh * S * DH;
    const float* vbase = V + (size_t)bh * S * DH;
#pragma unroll
    for (int it = 0; it < 4; ++it) {
        const int d0 = sc + (it << 4);
        const float4 v = *reinterpret_cast<const float4*>(&qbase[(size_t)sr * DH + d0]);
        Qs[d0 + 0][sr] = v.x; Qs[d0 + 1][sr] = v.y;
        Qs[d0 + 2][sr] = v.z; Qs[d0 + 3][sr] = v.w;
    }
    float C[4][4];
#pragma unroll
    for (int i = 0; i < 4; ++i)
#pragma unroll
        for (int j = 0; j < 4; ++j) C[i][j] = 0.f;
    float m[4] = {-1e30f, -1e30f, -1e30f, -1e30f};
    float l[4] = {0.f, 0.f, 0.f, 0.f};

    for (int kt = 0; kt <= qt; ++kt) {
        const int k0 = kt << 6;
        float4 kv[4], vv[4];
#pragma unroll
        for (int it = 0; it < 4; ++it) {
            const int d0 = sc + (it << 4);
            kv[it] = *reinterpret_cast<const float4*>(&kbase[(size_t)(k0 + sr) * DH + d0]);
            vv[it] = *reinterpret_cast<const float4*>(&vbase[(size_t)(k0 + sr) * DH + d0]);
        }
        __syncthreads();
#pragma unroll
        for (int it = 0; it < 4; ++it) {
            const int d0 = sc + (it << 4);
            Ks[d0 + 0][sr] = kv[it].x; Ks[d0 + 1][sr] = kv[it].y;
            Ks[d0 + 2][sr] = kv[it].z; Ks[d0 + 3][sr] = kv[it].w;
            *reinterpret_cast<float4*>(&Vs[sr][d0]) = vv[it];
        }
        __syncthreads();

        float s[4][4];
#pragma unroll
        for (int i = 0; i < 4; ++i)
#pragma unroll
            for (int j = 0; j < 4; ++j) s[i][j] = 0.f;
#pragma unroll 16
        for (int d = 0; d < 64; ++d) {
            const float4 qf4 = *reinterpret_cast<const float4*>(&Qs[d][tq << 2]);
            const float4 kf4 = *reinterpret_cast<const float4*>(&Ks[d][tk << 2]);
            const float qa[4] = {qf4.x, qf4.y, qf4.z, qf4.w};
            const float ka[4] = {kf4.x, kf4.y, kf4.z, kf4.w};
#pragma unroll
            for (int i = 0; i < 4; ++i)
#pragma unroll
                for (int j = 0; j < 4; ++j) s[i][j] += qa[i] * ka[j];
        }
        if (kt == qt) {
#pragma unroll
            for (int i = 0; i < 4; ++i) {
                const int qg = q0 + (tq << 2) + i;
#pragma unroll
                for (int j = 0; j < 4; ++j) {
                    const int kg = k0 + (tk << 2) + j;
                    s[i][j] = (kg <= qg) ? s[i][j] * 0.125f : -1e30f;
                }
            }
        } else {
#pragma unroll
            for (int i = 0; i < 4; ++i)
#pragma unroll
                for (int j = 0; j < 4; ++j) s[i][j] *= 0.125f;
        }
#pragma unroll
        for (int i = 0; i < 4; ++i) {
            float rm = fmaxf(fmaxf(s[i][0], s[i][1]), fmaxf(s[i][2], s[i][3]));
#pragma unroll
            for (int off = 1; off < 16; off <<= 1) rm = fmaxf(rm, __shfl_xor(rm, off));
            const float mn = fmaxf(m[i], rm);
            const float scale = __expf(m[i] - mn);
            float rs = 0.f;
#pragma unroll
            for (int j = 0; j < 4; ++j) {
                s[i][j] = __expf(s[i][j] - mn);
                rs += s[i][j];
            }
#pragma unroll
            for (int off = 1; off < 16; off <<= 1) rs += __shfl_xor(rs, off);
            l[i] = l[i] * scale + rs;
            m[i] = mn;
#pragma unroll
            for (int j = 0; j < 4; ++j) C[i][j] *= scale;
            *reinterpret_cast<float4*>(&Ps[(tq << 2) + i][tk << 2]) =
                make_float4(s[i][0], s[i][1], s[i][2], s[i][3]);
        }
        __syncthreads();
#pragma unroll 4
        for (int kc = 0; kc < 16; ++kc) {
            float4 pf[4], vf[4];
#pragma unroll
            for (int i = 0; i < 4; ++i)
                pf[i] = *reinterpret_cast<const float4*>(&Ps[(tq << 2) + i][kc << 2]);
#pragma unroll
            for (int j = 0; j < 4; ++j)
                vf[j] = *reinterpret_cast<const float4*>(&Vs[(kc << 2) + j][tk << 2]);
#pragma unroll
            for (int i = 0; i < 4; ++i) {
                const float pa[4] = {pf[i].x, pf[i].y, pf[i].z, pf[i].w};
#pragma unroll
                for (int j = 0; j < 4; ++j) {
                    C[i][j] += pa[0] * ((const float*)&vf[0])[j]
                             + pa[1] * ((const float*)&vf[1])[j]
                             + pa[2] * ((const float*)&vf[2])[j]
                             + pa[3] * ((const float*)&vf[3])[j];
                }
            }
        }
        __syncthreads();
    }
    const int b = bh >> 4, h = bh & (NH - 1);
#pragma unroll
    for (int i = 0; i < 4; ++i) {
        const int qg = q0 + (tq << 2) + i;
        const float inv = 1.f / l[i];
        float4 v;
        v.x = C[i][0] * inv; v.y = C[i][1] * inv;
        v.z = C[i][2] * inv; v.w = C[i][3] * inv;
        *reinterpret_cast<float4*>(&out[((size_t)(b * S + qg)) * DOUT + h * DH + (tk << 2)]) = v;
    }
}

// ===========================================================================
extern "C" void kernel_launch(void* const* d_in, const int* in_sizes, int n_in,
                              void* d_out, int out_size, void* d_ws, size_t ws_size,
                              hipStream_t stream) {
    const float* x  = (const float*)d_in[0];
    const float* Wq = (const float*)d_in[1];
    const float* Wk = (const float*)d_in[2];
    const float* Wv = (const float*)d_in[3];
    float* out = (float*)d_out;

    char* ws = (char*)d_ws;
    const size_t MB = 1024 * 1024;

    if (ws_size >= 68 * MB) {
        // layout: wT[0,12) | xsp 2-split[12,28) | Q[28,44) | K 2-split[44,60) |
        //         V^T bf16 1-split[60,68)
        ushort* wtsp = (ushort*)(ws);
        ushort* xsp  = (ushort*)(ws + 12 * MB);
        float*  qf   = (float*)(ws + 28 * MB);
        ushort* ksp  = (ushort*)(ws + 44 * MB);
        ushort* vtsp = (ushort*)(ws + 60 * MB);

        split_x<<<4096, 256, 0, stream>>>(x, xsp);
        split_wT3<<<dim3(16, 16, 3), 256, 0, stream>>>(Wq, Wk, Wv, wtsp);
        proj_fused3<<<512, 256, 0, stream>>>(xsp, wtsp, qf, ksp, vtsp);
        attn_mfma7<<<512, 256, 0, stream>>>(qf, ksp, vtsp, out);
    } else {
        // fp32 fallback (48 MB)
        float* qws = (float*)d_ws;
        float* kws = qws + (size_t)M_TOT * DOUT;
        float* vws = kws + (size_t)M_TOT * DOUT;
        dim3 pgrid(M_TOT / 64, DOUT / 64);
        proj_f32<<<pgrid, 256, 0, stream>>>(x, Wq, qws);
        proj_f32<<<pgrid, 256, 0, stream>>>(x, Wk, kws);
        proj_f32<<<pgrid, 256, 0, stream>>>(x, Wv, vws);
        attn_f32<<<32 * 32, 256, 0, stream>>>(qws, kws, vws, out);
    }
}

// Round 10
// 143.436 us; speedup vs baseline: 28.5723x; 1.0072x over previous
//
#include <hip/hip_runtime.h>
#include <hip/hip_bf16.h>

// Problem constants: B=2, S=2048, D_IN=1024, D_OUT=1024, H=16, Dh=64
#define B 2
#define S 2048
#define DIN 1024
#define DOUT 1024
#define NH 16
#define DH 64
#define M_TOT (B * S)   // 4096

typedef __attribute__((ext_vector_type(8))) short bf16x8;
typedef __attribute__((ext_vector_type(8))) unsigned short u16x8;
typedef __attribute__((ext_vector_type(4))) float f32x4;
typedef __attribute__((ext_vector_type(16))) float f32x16;

#define ASTRIDE 4194304   // elements per 4096x1024 split array
#define WSTRIDE 1048576   // elements per 1024x1024 split array

__device__ __forceinline__ ushort f2bf(float x) {
    union { float f; unsigned u; } c; c.f = x;
    unsigned r = (c.u + 0x7FFFu + ((c.u >> 16) & 1u)) >> 16;
    return (ushort)r;
}
__device__ __forceinline__ float bf2f(ushort h) {
    union { unsigned u; float f; } c; c.u = ((unsigned)h) << 16;
    return c.f;
}
__device__ __forceinline__ f32x4 mfma16(bf16x8 a, bf16x8 b, f32x4 c) {
    return __builtin_amdgcn_mfma_f32_16x16x32_bf16(a, b, c, 0, 0, 0);
}
__device__ __forceinline__ f32x16 mfma32(bf16x8 a, bf16x8 b, f32x16 c) {
    return __builtin_amdgcn_mfma_f32_32x32x16_bf16(a, b, c, 0, 0, 0);
}
__device__ __forceinline__ unsigned cvt_pk(float lo, float hi) {
    unsigned r;
    asm("v_cvt_pk_bf16_f32 %0, %1, %2" : "=v"(r) : "v"(lo), "v"(hi));
    return r;
}
__device__ __forceinline__ float exp2fast(float x) {
    float r;
    asm("v_exp_f32 %0, %1" : "=v"(r) : "v"(x));
    return r;
}

// ===========================================================================
// MAIN PATH (ws >= 68 MB)
// ===========================================================================

// ---- prepass: x (fp32 [4096][1024]) -> 2-way bf16 splits ----
__global__ __launch_bounds__(256) void split_x(const float* __restrict__ x,
                                               ushort* __restrict__ xs) {
    const size_t gid = (size_t)blockIdx.x * 256 + threadIdx.x;
    const float4 v = *reinterpret_cast<const float4*>(x + gid * 4);
    const float in[4] = {v.x, v.y, v.z, v.w};
    ushort h0[4], h1[4];
#pragma unroll
    for (int e = 0; e < 4; ++e) {
        h0[e] = f2bf(in[e]);
        h1[e] = f2bf(in[e] - bf2f(h0[e]));
    }
    const size_t o = gid * 4;
    *reinterpret_cast<ushort4*>(xs + o)           = ushort4{h0[0], h0[1], h0[2], h0[3]};
    *reinterpret_cast<ushort4*>(xs + ASTRIDE + o) = ushort4{h1[0], h1[1], h1[2], h1[3]};
}

// ---- prepass: all three W -> W^T 2-way bf16 splits, wt[wi][sp][n][k] ----
__global__ __launch_bounds__(256) void split_wT3(const float* __restrict__ W0,
                                                 const float* __restrict__ W1,
                                                 const float* __restrict__ W2,
                                                 ushort* __restrict__ wt) {
    __shared__ float Ws[64][68];
    const int tid = threadIdx.x;
    const int k0 = blockIdx.x << 6;
    const int n0 = blockIdx.y << 6;
    const int wi = blockIdx.z;
    const float* W = (wi == 0) ? W0 : (wi == 1) ? W1 : W2;
    ushort* wto = wt + (size_t)wi * 2 * WSTRIDE;

    const int r = tid >> 2;
    const int cb = (tid & 3) << 2;
#pragma unroll
    for (int it = 0; it < 4; ++it) {
        const int c = cb + (it << 4);
        *reinterpret_cast<float4*>(&Ws[r][c]) =
            *reinterpret_cast<const float4*>(&W[(size_t)(k0 + r) * 1024 + n0 + c]);
    }
    __syncthreads();
    const int rn = tid >> 2;
    const int kc = (tid & 3) << 4;
    u16x8 o0[2], o1[2];
#pragma unroll
    for (int half = 0; half < 2; ++half)
#pragma unroll
        for (int i = 0; i < 8; ++i) {
            const float x = Ws[kc + (half << 3) + i][rn];
            const ushort a = f2bf(x);
            o0[half][i] = a;
            o1[half][i] = f2bf(x - bf2f(a));
        }
    const size_t base = (size_t)(n0 + rn) * 1024 + k0 + kc;
    *reinterpret_cast<u16x8*>(wto + base)               = o0[0];
    *reinterpret_cast<u16x8*>(wto + base + 8)           = o0[1];
    *reinterpret_cast<u16x8*>(wto + WSTRIDE + base)     = o1[0];
    *reinterpret_cast<u16x8*>(wto + WSTRIDE + base + 8) = o1[1];
}

// ---------------------------------------------------------------------------
// Fused QKV projection v4: 128(M)x64(N) tile, BK=64, DOUBLE-BUFFERED
// split-barrier staging (two 72 KB buffers, 144 KB LDS, 1 block/CU):
// prefetch(t+1) issued into buf^1 before computing buf -> one barrier/step,
// staging latency hidden under compute (attn-v7's verified pattern).
// Q/K 3-term (a0b0+a1b0+a0b1), V 2-term. V^T computed directly via
// SWAPPED-OPERAND mfma16(bv, a) (output transposed: rows=d, cols=s) and
// stored bf16 1-split to vt[bh][d][s'] with the 4-elem granule permutation
// [0,2,1,3] folded into the store index. Grid 512 (32m x 16n), XCD-chunked.
// ---------------------------------------------------------------------------
__global__ __launch_bounds__(256) void proj_fused4(const ushort* __restrict__ xsp,
                                                   const ushort* __restrict__ wtsp,
                                                   float* __restrict__ qf,
                                                   ushort* __restrict__ ksp,
                                                   ushort* __restrict__ vtsp) {
    __shared__ __align__(16) ushort SB[2][36864];   // 2 x 72 KB = 144 KB

    const int tid = threadIdx.x;
    const int lane = tid & 63;
    const int w = tid >> 6;
    const int swz = (blockIdx.x & 7) * 64 + (blockIdx.x >> 3);   // 512 blocks, bijective
    const int n0 = (swz & 15) << 6;
    const int m0 = (swz >> 4) << 7;   // 32 m-tiles of 128
    const int col = lane & 15;
    const int glane = lane >> 4;
    const int lrow = lane >> 3;
    const int sl8 = ((lane & 7) ^ lrow) << 3;

    f32x4 accq[2][4], acck[2][4], accv[2][4];   // [mi][nj]; accv is TRANSPOSED
#pragma unroll
    for (int mi = 0; mi < 2; ++mi)
#pragma unroll
        for (int nj = 0; nj < 4; ++nj) {
            accq[mi][nj] = f32x4{0.f, 0.f, 0.f, 0.f};
            acck[mi][nj] = f32x4{0.f, 0.f, 0.f, 0.f};
            accv[mi][nj] = f32x4{0.f, 0.f, 0.f, 0.f};
        }

    // 72 staging units of 1 KB (8 rows x 128 B): A 2sp x 16 blocks, B 5 x 8
#define PISSUE(K0, BUF)                                                                 \
    {                                                                                   \
        _Pragma("unroll")                                                               \
        for (int i = 0; i < 18; ++i) {                                                  \
            const int u = (i << 2) | w;                                                 \
            const ushort* g;                                                            \
            if (u < 32) {                                                               \
                const int sp = u >> 4, rb = u & 15;                                     \
                g = xsp + (size_t)sp * ASTRIDE +                                        \
                    (size_t)(m0 + (rb << 3) + lrow) * 1024 + (K0) + sl8;                \
            } else {                                                                    \
                const int v = u - 32;                                                   \
                const int bi = v >> 3;   /* 0..4 = Wq0,Wq1,Wk0,Wk1,Wv0 */               \
                const int rb = v & 7;                                                   \
                g = wtsp + (size_t)bi * WSTRIDE +                                       \
                    (size_t)(n0 + (rb << 3) + lrow) * 1024 + (K0) + sl8;                \
            }                                                                           \
            __builtin_amdgcn_global_load_lds(g, &SB[BUF][u * 512], 16, 0, 0);           \
        }                                                                               \
    }

    PISSUE(0, 0);
    __syncthreads();

    for (int kt = 0; kt < 16; ++kt) {
        const int cur = kt & 1;
        if (kt < 15) PISSUE((kt + 1) << 6, cur ^ 1);   // prefetch under compute

        const ushort* SL = SB[cur];
#pragma unroll
        for (int st = 0; st < 2; ++st) {
            const int sw = (((st << 2) | glane) ^ (col & 7)) << 3;
            bf16x8 a[2][2];   // [sp][mi]
#pragma unroll
            for (int sp = 0; sp < 2; ++sp)
#pragma unroll
                for (int mi = 0; mi < 2; ++mi) {
                    const int arow = (w << 5) + (mi << 4) + col;
                    a[sp][mi] = *reinterpret_cast<const bf16x8*>(&SL[sp * 8192 + arow * 64 + sw]);
                }
#pragma unroll
            for (int nj = 0; nj < 4; ++nj) {
                const int brow = (nj << 4) + col;
                const int bb = 16384 + brow * 64 + sw;
                const bf16x8 bq0 = *reinterpret_cast<const bf16x8*>(&SL[bb]);
                const bf16x8 bq1 = *reinterpret_cast<const bf16x8*>(&SL[bb + 4096]);
                const bf16x8 bk0 = *reinterpret_cast<const bf16x8*>(&SL[bb + 8192]);
                const bf16x8 bk1 = *reinterpret_cast<const bf16x8*>(&SL[bb + 12288]);
                const bf16x8 bv0 = *reinterpret_cast<const bf16x8*>(&SL[bb + 16384]);
#pragma unroll
                for (int mi = 0; mi < 2; ++mi) {
                    // Q, K: 3-term (a0b0 + a1b0 + a0b1)
                    accq[mi][nj] = mfma16(a[0][mi], bq0, accq[mi][nj]);
                    accq[mi][nj] = mfma16(a[1][mi], bq0, accq[mi][nj]);
                    accq[mi][nj] = mfma16(a[0][mi], bq1, accq[mi][nj]);
                    acck[mi][nj] = mfma16(a[0][mi], bk0, acck[mi][nj]);
                    acck[mi][nj] = mfma16(a[1][mi], bk0, acck[mi][nj]);
                    acck[mi][nj] = mfma16(a[0][mi], bk1, acck[mi][nj]);
                    // V^T: swapped operands -> out rows = d (bv rows),
                    // out cols = s (a rows)
                    accv[mi][nj] = mfma16(bv0, a[0][mi], accv[mi][nj]);
                    accv[mi][nj] = mfma16(bv0, a[1][mi], accv[mi][nj]);
                }
            }
        }
        __syncthreads();   // compute(cur) done AND prefetch(cur^1) drained
    }
#undef PISSUE

    // ---- epilogue: Q fp32, K 2-split to [bh][s][d] ----
    const int b = m0 >> 11;
    const int h = n0 >> 6;
    const size_t bh_off = (size_t)(b * NH + h) * S * DH;
#pragma unroll
    for (int mi = 0; mi < 2; ++mi)
#pragma unroll
        for (int r = 0; r < 4; ++r) {
            const int srow = (m0 & (S - 1)) + (w << 5) + (mi << 4) + (glane << 2) + r;
#pragma unroll
            for (int nj = 0; nj < 4; ++nj) {
                const size_t o = bh_off + (size_t)srow * DH + (nj << 4) + col;
                qf[o] = accq[mi][nj][r];
                const float xk = acck[mi][nj][r];
                const ushort k0s = f2bf(xk);
                ksp[o] = k0s;
                ksp[ASTRIDE + o] = f2bf(xk - bf2f(k0s));
            }
        }

    // ---- V^T: direct register store to [bh][d][s'], granule-permuted ----
    // out col within 16-block: bit-reverse of the middle 2 bits ({0,2,1,3})
    const int cm = col >> 2;
    const int colp = (col & 3) | ((((cm & 1) << 1) | (cm >> 1)) << 2);
    const size_t vbh = (size_t)(b * NH + h) * DH * S;
#pragma unroll
    for (int mi = 0; mi < 2; ++mi) {
        const int s = (m0 & (S - 1)) + (w << 5) + (mi << 4) + colp;
#pragma unroll
        for (int nj = 0; nj < 4; ++nj)
#pragma unroll
            for (int r = 0; r < 4; ++r) {
                const int d = (nj << 4) + (glane << 2) + r;
                vtsp[vbh + (size_t)d * S + s] = f2bf(accv[mi][nj][r]);
            }
    }
}

// ---------------------------------------------------------------------------
// MFMA flash attention v7 (UNCHANGED from round 9, verified): 32x32
// swapped-QK, permutation-free P packing, K 2-split (5-term QK), V bf16
// 1-split (8 PV MFMA), balanced (qt, 15-qt) CU pairing, double-buffered
// global_load_lds staging (48 KB LDS), tree softmax reductions.
// ---------------------------------------------------------------------------
__global__ __launch_bounds__(256, 2) void attn_mfma7(const float* __restrict__ Qf,
                                                     const ushort* __restrict__ ksp,
                                                     const ushort* __restrict__ vtsp,
                                                     float* __restrict__ out) {
    __shared__ __align__(16) ushort SB[2][12288];

    const int tid = threadIdx.x;
    const int lane = tid & 63;
    const int w = tid >> 6;

    const int xcd = blockIdx.x & 7;
    const int u_ = blockIdx.x >> 3;   // 0..63
    int bh, qt;
    if (u_ < 32) { bh = (xcd << 2) | (u_ >> 4);                 qt = 15 - (u_ & 15); }
    else         { const int v2 = u_ - 32; bh = (xcd << 2) | 2 | (v2 >> 4); qt = v2 & 15; }

    const int q0 = qt << 7;
    const int qw0 = q0 + (w << 5);
    const int hi = lane >> 5;
    const int ql = lane & 31;
    const int qg = qw0 + ql;
    const int lrow = lane >> 3;
    const int sl8 = ((lane & 7) ^ lrow) << 3;

    bf16x8 qb[3][4];
    {
        const float* qp = Qf + ((size_t)bh * S + qg) * DH + (hi << 3);
#pragma unroll
        for (int dc = 0; dc < 4; ++dc) {
            const float4 f0 = *reinterpret_cast<const float4*>(qp + (dc << 4));
            const float4 f1 = *reinterpret_cast<const float4*>(qp + (dc << 4) + 4);
            const float xs[8] = {f0.x, f0.y, f0.z, f0.w, f1.x, f1.y, f1.z, f1.w};
#pragma unroll
            for (int e = 0; e < 8; ++e) {
                const float x = xs[e] * 0.18033688011112042f;   // 1/8 * log2(e)
                const ushort h0 = f2bf(x);
                const float r1 = x - bf2f(h0);
                const ushort h1 = f2bf(r1);
                qb[0][dc][e] = (short)h0;
                qb[1][dc][e] = (short)h1;
                qb[2][dc][e] = (short)f2bf(r1 - bf2f(h1));
            }
        }
    }

    f32x16 O[2];
#pragma unroll
    for (int ds = 0; ds < 2; ++ds)
#pragma unroll
        for (int r = 0; r < 16; ++r) O[ds][r] = 0.f;
    float m_ = -INFINITY, l_ = 0.f;

    const size_t kbase = (size_t)bh * S * DH;
    const size_t vbase = (size_t)bh * DH * S;

#define ISSUE_KV(K0, BUF)                                                               \
    {                                                                                   \
        _Pragma("unroll")                                                               \
        for (int i = 0; i < 6; ++i) {                                                   \
            const int u = (i << 2) | w;                                                 \
            const ushort* gp;                                                           \
            if (u < 16) {                                                               \
                const int sp = u >> 3, rb = u & 7;                                      \
                gp = ksp + (size_t)sp * ASTRIDE + kbase +                               \
                     (size_t)((K0) + (rb << 3) + lrow) * DH + sl8;                      \
            } else {                                                                    \
                const int rb = u & 7;                                                   \
                gp = vtsp + vbase + (size_t)((rb << 3) + lrow) * S + (K0) + sl8;        \
            }                                                                           \
            __builtin_amdgcn_global_load_lds(gp, &SB[BUF][u * 512], 16, 0, 0);          \
        }                                                                               \
    }

    ISSUE_KV(0, 0);
    __syncthreads();

    const int ktmax = (q0 >> 6) + 1;
    for (int kt = 0; kt <= ktmax; ++kt) {
        const int k0 = kt << 6;
        const int cur = kt & 1;
        if (kt < ktmax) ISSUE_KV(k0 + 64, cur ^ 1);

        const bool active = (k0 <= qw0 + 31);
        if (active) {
            const ushort* KL = &SB[cur][0];
            const ushort* VL = &SB[cur][8192];

            f32x16 Sf[2];
#pragma unroll
            for (int ks = 0; ks < 2; ++ks)
#pragma unroll
                for (int r = 0; r < 16; ++r) Sf[ks][r] = 0.f;
#pragma unroll
            for (int ks = 0; ks < 2; ++ks) {
#pragma unroll
                for (int dc = 0; dc < 4; ++dc) {
                    const int row = (ks << 5) + ql;
                    const int eo = row * 64 + ((((dc << 1) | hi) ^ (row & 7)) << 3);
                    const bf16x8 ka = *reinterpret_cast<const bf16x8*>(&KL[eo]);
                    const bf16x8 kb = *reinterpret_cast<const bf16x8*>(&KL[4096 + eo]);
                    Sf[ks] = mfma32(ka, qb[0][dc], Sf[ks]);
                    Sf[ks] = mfma32(ka, qb[1][dc], Sf[ks]);
                    Sf[ks] = mfma32(ka, qb[2][dc], Sf[ks]);
                    Sf[ks] = mfma32(kb, qb[0][dc], Sf[ks]);
                    Sf[ks] = mfma32(kb, qb[1][dc], Sf[ks]);
                }
            }

            if (k0 + 63 > qw0) {
#pragma unroll
                for (int ks = 0; ks < 2; ++ks)
#pragma unroll
                    for (int r = 0; r < 16; ++r) {
                        const int kg = k0 + (ks << 5) + (r & 3) + ((r >> 2) << 3) + (hi << 2);
                        if (kg > qg) Sf[ks][r] = -1e30f;
                    }
            }

            float mx[8];
#pragma unroll
            for (int i = 0; i < 8; ++i)
                mx[i] = fmaxf(fmaxf(Sf[0][i], Sf[0][i + 8]),
                              fmaxf(Sf[1][i], Sf[1][i + 8]));
            float rm = fmaxf(fmaxf(fmaxf(mx[0], mx[1]), fmaxf(mx[2], mx[3])),
                             fmaxf(fmaxf(mx[4], mx[5]), fmaxf(mx[6], mx[7])));
            rm = fmaxf(rm, __shfl_xor(rm, 32));
            if (__any(rm > m_ + 8.f)) {
                const float nm = fmaxf(m_, rm);
                const float sc = exp2fast(m_ - nm);
                m_ = nm;
                l_ *= sc;
#pragma unroll
                for (int ds = 0; ds < 2; ++ds)
#pragma unroll
                    for (int r = 0; r < 16; ++r) O[ds][r] *= sc;
            }

            float rsa[4] = {0.f, 0.f, 0.f, 0.f};
            bf16x8 pb[4];
#pragma unroll
            for (int ks = 0; ks < 2; ++ks) {
                float p[16];
#pragma unroll
                for (int r = 0; r < 16; ++r) {
                    p[r] = exp2fast(Sf[ks][r] - m_);
                    rsa[r & 3] += p[r];
                }
#pragma unroll
                for (int c = 0; c < 2; ++c) {
                    union { unsigned u[4]; bf16x8 v; } pw;
                    pw.u[0] = cvt_pk(p[(c << 3) + 0], p[(c << 3) + 1]);
                    pw.u[1] = cvt_pk(p[(c << 3) + 2], p[(c << 3) + 3]);
                    pw.u[2] = cvt_pk(p[(c << 3) + 4], p[(c << 3) + 5]);
                    pw.u[3] = cvt_pk(p[(c << 3) + 6], p[(c << 3) + 7]);
                    pb[(ks << 1) + c] = pw.v;
                }
            }
            float rs = (rsa[0] + rsa[1]) + (rsa[2] + rsa[3]);
            rs += __shfl_xor(rs, 32);
            l_ += rs;

#pragma unroll
            for (int ds = 0; ds < 2; ++ds)
#pragma unroll
                for (int kc = 0; kc < 4; ++kc) {
                    const int row = (ds << 5) + ql;
                    const int eo = row * 64 + ((((kc << 1) | hi) ^ (row & 7)) << 3);
                    const bf16x8 va = *reinterpret_cast<const bf16x8*>(&VL[eo]);
                    O[ds] = mfma32(va, pb[kc], O[ds]);
                }
        }
        __syncthreads();
    }

    const float inv = 1.f / l_;
    const int b = bh >> 4, h = bh & (NH - 1);
    float* op = out + ((size_t)(b * S + qg)) * DOUT + h * DH;
#pragma unroll
    for (int ds = 0; ds < 2; ++ds)
#pragma unroll
        for (int rg = 0; rg < 4; ++rg) {
            float4 v;
            v.x = O[ds][(rg << 2) + 0] * inv;
            v.y = O[ds][(rg << 2) + 1] * inv;
            v.z = O[ds][(rg << 2) + 2] * inv;
            v.w = O[ds][(rg << 2) + 3] * inv;
            *reinterpret_cast<float4*>(&op[(ds << 5) + (rg << 3) + (hi << 2)]) = v;
        }
#undef ISSUE_KV
}

// ===========================================================================
// FALLBACK (fp32, ws >= 48 MB)
// ===========================================================================
__global__ __launch_bounds__(256) void proj_f32(const float* __restrict__ A,
                                                const float* __restrict__ W,
                                                float* __restrict__ outf) {
    __shared__ float As[16][68];
    __shared__ float Bs[16][68];
    const int tid = threadIdx.x;
    const int m0 = blockIdx.x * 64;
    const int n0 = blockIdx.y * 64;
    const int tm = tid >> 4, tn = tid & 15;
    const int la_r = tid >> 2, la_c = (tid & 3) << 2;
    const int lb_r = tid >> 4, lb_c = (tid & 15) << 2;

    float acc[4][4];
#pragma unroll
    for (int i = 0; i < 4; ++i)
#pragma unroll
        for (int j = 0; j < 4; ++j) acc[i][j] = 0.f;

    for (int k0 = 0; k0 < DIN; k0 += 16) {
        const float4 av = *reinterpret_cast<const float4*>(&A[(size_t)(m0 + la_r) * DIN + k0 + la_c]);
        const float4 bv = *reinterpret_cast<const float4*>(&W[(size_t)(k0 + lb_r) * DOUT + n0 + lb_c]);
        __syncthreads();
        As[la_c + 0][la_r] = av.x; As[la_c + 1][la_r] = av.y;
        As[la_c + 2][la_r] = av.z; As[la_c + 3][la_r] = av.w;
        *reinterpret_cast<float4*>(&Bs[lb_r][lb_c]) = bv;
        __syncthreads();
#pragma unroll
        for (int kk = 0; kk < 16; ++kk) {
            const float4 a = *reinterpret_cast<const float4*>(&As[kk][tm << 2]);
            const float4 b = *reinterpret_cast<const float4*>(&Bs[kk][tn << 2]);
            const float aa[4] = {a.x, a.y, a.z, a.w};
            const float bb[4] = {b.x, b.y, b.z, b.w};
#pragma unroll
            for (int i = 0; i < 4; ++i)
#pragma unroll
                for (int j = 0; j < 4; ++j) acc[i][j] += aa[i] * bb[j];
        }
    }
    const int b = m0 >> 11;
    const int s_base = (m0 & (S - 1)) + (tm << 2);
    const int h = n0 >> 6;
    const int dh = tn << 2;
    float* obase = outf + ((size_t)(b * NH + h) * S) * DH;
#pragma unroll
    for (int i = 0; i < 4; ++i) {
        float4 v;
        v.x = acc[i][0]; v.y = acc[i][1]; v.z = acc[i][2]; v.w = acc[i][3];
        *reinterpret_cast<float4*>(&obase[(size_t)(s_base + i) * DH + dh]) = v;
    }
}

__global__ __launch_bounds__(256) void attn_f32(const float* __restrict__ Q,
                                                const float* __restrict__ K,
                                                const float* __restrict__ V,
                                                float* __restrict__ out) {
    __shared__ float Qs[64][68];
    __shared__ float Ks[64][68];
    __shared__ float Vs[64][68];
    __shared__ float Ps[64][68];
    const int tid = threadIdx.x;
    const int bh = blockIdx.x & 31;
    const int qt = 31 - (blockIdx.x >> 5);
    const int q0 = qt << 6;
    const int tq = tid >> 4, tk = tid & 15;
    const int sr = tid >> 2, sc = (tid & 3) << 2;

    const float* qbase = Q + ((size_t)bh * S + q0) * DH;
    const float* kbase = K + (size_t)bh * S * DH;
    const float* vbase = V + (size_t)bh * S * DH;
#pragma unroll
    for (int it = 0; it < 4; ++it) {
        const int d0 = sc + (it << 4);
        const float4 v = *reinterpret_cast<const float4*>(&qbase[(size_t)sr * DH + d0]);
        Qs[d0 + 0][sr] = v.x; Qs[d0 + 1][sr] = v.y;
        Qs[d0 + 2][sr] = v.z; Qs[d0 + 3][sr] = v.w;
    }
    float C[4][4];
#pragma unroll
    for (int i = 0; i < 4; ++i)
#pragma unroll
        for (int j = 0; j < 4; ++j) C[i][j] = 0.f;
    float m[4] = {-1e30f, -1e30f, -1e30f, -1e30f};
    float l[4] = {0.f, 0.f, 0.f, 0.f};

    for (int kt = 0; kt <= qt; ++kt) {
        const int k0 = kt << 6;
        float4 kv[4], vv[4];
#pragma unroll
        for (int it = 0; it < 4; ++it) {
            const int d0 = sc + (it << 4);
            kv[it] = *reinterpret_cast<const float4*>(&kbase[(size_t)(k0 + sr) * DH + d0]);
            vv[it] = *reinterpret_cast<const float4*>(&vbase[(size_t)(k0 + sr) * DH + d0]);
        }
        __syncthreads();
#pragma unroll
        for (int it = 0; it < 4; ++it) {
            const int d0 = sc + (it << 4);
            Ks[d0 + 0][sr] = kv[it].x; Ks[d0 + 1][sr] = kv[it].y;
            Ks[d0 + 2][sr] = kv[it].z; Ks[d0 + 3][sr] = kv[it].w;
            *reinterpret_cast<float4*>(&Vs[sr][d0]) = vv[it];
        }
        __syncthreads();

        float s[4][4];
#pragma unroll
        for (int i = 0; i < 4; ++i)
#pragma unroll
            for (int j = 0; j < 4; ++j) s[i][j] = 0.f;
#pragma unroll 16
        for (int d = 0; d < 64; ++d) {
            const float4 qf4 = *reinterpret_cast<const float4*>(&Qs[d][tq << 2]);
            const float4 kf4 = *reinterpret_cast<const float4*>(&Ks[d][tk << 2]);
            const float qa[4] = {qf4.x, qf4.y, qf4.z, qf4.w};
            const float ka[4] = {kf4.x, kf4.y, kf4.z, kf4.w};
#pragma unroll
            for (int i = 0; i < 4; ++i)
#pragma unroll
                for (int j = 0; j < 4; ++j) s[i][j] += qa[i] * ka[j];
        }
        if (kt == qt) {
#pragma unroll
            for (int i = 0; i < 4; ++i) {
                const int qg = q0 + (tq << 2) + i;
#pragma unroll
                for (int j = 0; j < 4; ++j) {
                    const int kg = k0 + (tk << 2) + j;
                    s[i][j] = (kg <= qg) ? s[i][j] * 0.125f : -1e30f;
                }
            }
        } else {
#pragma unroll
            for (int i = 0; i < 4; ++i)
#pragma unroll
                for (int j = 0; j < 4; ++j) s[i][j] *= 0.125f;
        }
#pragma unroll
        for (int i = 0; i < 4; ++i) {
            float rm = fmaxf(fmaxf(s[i][0], s[i][1]), fmaxf(s[i][2], s[i][3]));
#pragma unroll
            for (int off = 1; off < 16; off <<= 1) rm = fmaxf(rm, __shfl_xor(rm, off));
            const float mn = fmaxf(m[i], rm);
            const float scale = __expf(m[i] - mn);
            float rs = 0.f;
#pragma unroll
            for (int j = 0; j < 4; ++j) {
                s[i][j] = __expf(s[i][j] - mn);
                rs += s[i][j];
            }
#pragma unroll
            for (int off = 1; off < 16; off <<= 1) rs += __shfl_xor(rs, off);
            l[i] = l[i] * scale + rs;
            m[i] = mn;
#pragma unroll
            for (int j = 0; j < 4; ++j) C[i][j] *= scale;
            *reinterpret_cast<float4*>(&Ps[(tq << 2) + i][tk << 2]) =
                make_float4(s[i][0], s[i][1], s[i][2], s[i][3]);
        }
        __syncthreads();
#pragma unroll 4
        for (int kc = 0; kc < 16; ++kc) {
            float4 pf[4], vf[4];
#pragma unroll
            for (int i = 0; i < 4; ++i)
                pf[i] = *reinterpret_cast<const float4*>(&Ps[(tq << 2) + i][kc << 2]);
#pragma unroll
            for (int j = 0; j < 4; ++j)
                vf[j] = *reinterpret_cast<const float4*>(&Vs[(kc << 2) + j][tk << 2]);
#pragma unroll
            for (int i = 0; i < 4; ++i) {
                const float pa[4] = {pf[i].x, pf[i].y, pf[i].z, pf[i].w};
#pragma unroll
                for (int j = 0; j < 4; ++j) {
                    C[i][j] += pa[0] * ((const float*)&vf[0])[j]
                             + pa[1] * ((const float*)&vf[1])[j]
                             + pa[2] * ((const float*)&vf[2])[j]
                             + pa[3] * ((const float*)&vf[3])[j];
                }
            }
        }
        __syncthreads();
    }
    const int b = bh >> 4, h = bh & (NH - 1);
#pragma unroll
    for (int i = 0; i < 4; ++i) {
        const int qg = q0 + (tq << 2) + i;
        const float inv = 1.f / l[i];
        float4 v;
        v.x = C[i][0] * inv; v.y = C[i][1] * inv;
        v.z = C[i][2] * inv; v.w = C[i][3] * inv;
        *reinterpret_cast<float4*>(&out[((size_t)(b * S + qg)) * DOUT + h * DH + (tk << 2)]) = v;
    }
}

// ===========================================================================
extern "C" void kernel_launch(void* const* d_in, const int* in_sizes, int n_in,
                              void* d_out, int out_size, void* d_ws, size_t ws_size,
                              hipStream_t stream) {
    const float* x  = (const float*)d_in[0];
    const float* Wq = (const float*)d_in[1];
    const float* Wk = (const float*)d_in[2];
    const float* Wv = (const float*)d_in[3];
    float* out = (float*)d_out;

    char* ws = (char*)d_ws;
    const size_t MB = 1024 * 1024;

    if (ws_size >= 68 * MB) {
        // layout: wT[0,12) | xsp 2-split[12,28) | Q[28,44) | K 2-split[44,60) |
        //         V^T bf16 1-split[60,68)
        ushort* wtsp = (ushort*)(ws);
        ushort* xsp  = (ushort*)(ws + 12 * MB);
        float*  qf   = (float*)(ws + 28 * MB);
        ushort* ksp  = (ushort*)(ws + 44 * MB);
        ushort* vtsp = (ushort*)(ws + 60 * MB);

        split_x<<<4096, 256, 0, stream>>>(x, xsp);
        split_wT3<<<dim3(16, 16, 3), 256, 0, stream>>>(Wq, Wk, Wv, wtsp);
        proj_fused4<<<512, 256, 0, stream>>>(xsp, wtsp, qf, ksp, vtsp);
        attn_mfma7<<<512, 256, 0, stream>>>(qf, ksp, vtsp, out);
    } else {
        // fp32 fallback (48 MB)
        float* qws = (float*)d_ws;
        float* kws = qws + (size_t)M_TOT * DOUT;
        float* vws = kws + (size_t)M_TOT * DOUT;
        dim3 pgrid(M_TOT / 64, DOUT / 64);
        proj_f32<<<pgrid, 256, 0, stream>>>(x, Wq, qws);
        proj_f32<<<pgrid, 256, 0, stream>>>(x, Wk, kws);
        proj_f32<<<pgrid, 256, 0, stream>>>(x, Wv, vws);
        attn_f32<<<32 * 32, 256, 0, stream>>>(qws, kws, vws, out);
    }
}

// Round 11
// 133.394 us; speedup vs baseline: 30.7233x; 1.0753x over previous
//
#include <hip/hip_runtime.h>
#include <hip/hip_bf16.h>

// Problem constants: B=2, S=2048, D_IN=1024, D_OUT=1024, H=16, Dh=64
#define B 2
#define S 2048
#define DIN 1024
#define DOUT 1024
#define NH 16
#define DH 64
#define M_TOT (B * S)   // 4096

typedef __attribute__((ext_vector_type(8))) short bf16x8;
typedef __attribute__((ext_vector_type(8))) unsigned short u16x8;
typedef __attribute__((ext_vector_type(4))) float f32x4;
typedef __attribute__((ext_vector_type(16))) float f32x16;

#define ASTRIDE 4194304   // elements per 4096x1024 split array
#define WSTRIDE 1048576   // elements per 1024x1024 split array

__device__ __forceinline__ ushort f2bf(float x) {
    union { float f; unsigned u; } c; c.f = x;
    unsigned r = (c.u + 0x7FFFu + ((c.u >> 16) & 1u)) >> 16;
    return (ushort)r;
}
__device__ __forceinline__ float bf2f(ushort h) {
    union { unsigned u; float f; } c; c.u = ((unsigned)h) << 16;
    return c.f;
}
__device__ __forceinline__ f32x4 mfma16(bf16x8 a, bf16x8 b, f32x4 c) {
    return __builtin_amdgcn_mfma_f32_16x16x32_bf16(a, b, c, 0, 0, 0);
}
__device__ __forceinline__ f32x16 mfma32(bf16x8 a, bf16x8 b, f32x16 c) {
    return __builtin_amdgcn_mfma_f32_32x32x16_bf16(a, b, c, 0, 0, 0);
}
__device__ __forceinline__ unsigned cvt_pk(float lo, float hi) {
    unsigned r;
    asm("v_cvt_pk_bf16_f32 %0, %1, %2" : "=v"(r) : "v"(lo), "v"(hi));
    return r;
}
__device__ __forceinline__ float exp2fast(float x) {
    float r;
    asm("v_exp_f32 %0, %1" : "=v"(r) : "v"(x));
    return r;
}

// ===========================================================================
// MAIN PATH (ws >= 68 MB)
// ===========================================================================

// ---- prepass: x (fp32 [4096][1024]) -> 2-way bf16 splits ----
__global__ __launch_bounds__(256) void split_x(const float* __restrict__ x,
                                               ushort* __restrict__ xs) {
    const size_t gid = (size_t)blockIdx.x * 256 + threadIdx.x;
    const float4 v = *reinterpret_cast<const float4*>(x + gid * 4);
    const float in[4] = {v.x, v.y, v.z, v.w};
    ushort h0[4], h1[4];
#pragma unroll
    for (int e = 0; e < 4; ++e) {
        h0[e] = f2bf(in[e]);
        h1[e] = f2bf(in[e] - bf2f(h0[e]));
    }
    const size_t o = gid * 4;
    *reinterpret_cast<ushort4*>(xs + o)           = ushort4{h0[0], h0[1], h0[2], h0[3]};
    *reinterpret_cast<ushort4*>(xs + ASTRIDE + o) = ushort4{h1[0], h1[1], h1[2], h1[3]};
}

// ---- prepass: all three W -> W^T 2-way bf16 splits, wt[wi][sp][n][k] ----
__global__ __launch_bounds__(256) void split_wT3(const float* __restrict__ W0,
                                                 const float* __restrict__ W1,
                                                 const float* __restrict__ W2,
                                                 ushort* __restrict__ wt) {
    __shared__ float Ws[64][68];
    const int tid = threadIdx.x;
    const int k0 = blockIdx.x << 6;
    const int n0 = blockIdx.y << 6;
    const int wi = blockIdx.z;
    const float* W = (wi == 0) ? W0 : (wi == 1) ? W1 : W2;
    ushort* wto = wt + (size_t)wi * 2 * WSTRIDE;

    const int r = tid >> 2;
    const int cb = (tid & 3) << 2;
#pragma unroll
    for (int it = 0; it < 4; ++it) {
        const int c = cb + (it << 4);
        *reinterpret_cast<float4*>(&Ws[r][c]) =
            *reinterpret_cast<const float4*>(&W[(size_t)(k0 + r) * 1024 + n0 + c]);
    }
    __syncthreads();
    const int rn = tid >> 2;
    const int kc = (tid & 3) << 4;
    u16x8 o0[2], o1[2];
#pragma unroll
    for (int half = 0; half < 2; ++half)
#pragma unroll
        for (int i = 0; i < 8; ++i) {
            const float x = Ws[kc + (half << 3) + i][rn];
            const ushort a = f2bf(x);
            o0[half][i] = a;
            o1[half][i] = f2bf(x - bf2f(a));
        }
    const size_t base = (size_t)(n0 + rn) * 1024 + k0 + kc;
    *reinterpret_cast<u16x8*>(wto + base)               = o0[0];
    *reinterpret_cast<u16x8*>(wto + base + 8)           = o0[1];
    *reinterpret_cast<u16x8*>(wto + WSTRIDE + base)     = o1[0];
    *reinterpret_cast<u16x8*>(wto + WSTRIDE + base + 8) = o1[1];
}

// ---------------------------------------------------------------------------
// Fused QKV projection v5: the r8 proj_fused2 STRUCTURE (single 72 KB buffer,
// 2 barriers/step, 2 blocks/CU -- the measured-fast configuration) with the
// r10 MATH: Q/K 3-term (a0b0+a1b0+a0b1), V 2-term, and V^T computed directly
// via SWAPPED-OPERAND mfma16(bv, a) then stored bf16 1-split to vt[bh][d][s']
// with the granule permutation [0,2,1,3] folded into the store index.
// 128(M)x64(N) tile, BK=64. Grid 512 (32m x 16n), XCD-chunked.
// ---------------------------------------------------------------------------
__global__ __launch_bounds__(256, 2) void proj_fused5(const ushort* __restrict__ xsp,
                                                      const ushort* __restrict__ wtsp,
                                                      float* __restrict__ qf,
                                                      ushort* __restrict__ ksp,
                                                      ushort* __restrict__ vtsp) {
    __shared__ __align__(16) ushort SL[36864];   // 72 KB

    const int tid = threadIdx.x;
    const int lane = tid & 63;
    const int w = tid >> 6;
    const int swz = (blockIdx.x & 7) * 64 + (blockIdx.x >> 3);   // 512 blocks, bijective
    const int n0 = (swz & 15) << 6;
    const int m0 = (swz >> 4) << 7;   // 32 m-tiles of 128
    const int col = lane & 15;
    const int glane = lane >> 4;
    const int lrow = lane >> 3;
    const int sl8 = ((lane & 7) ^ lrow) << 3;

    f32x4 accq[2][4], acck[2][4], accv[2][4];   // [mi][nj]; accv is TRANSPOSED
#pragma unroll
    for (int mi = 0; mi < 2; ++mi)
#pragma unroll
        for (int nj = 0; nj < 4; ++nj) {
            accq[mi][nj] = f32x4{0.f, 0.f, 0.f, 0.f};
            acck[mi][nj] = f32x4{0.f, 0.f, 0.f, 0.f};
            accv[mi][nj] = f32x4{0.f, 0.f, 0.f, 0.f};
        }

    for (int k0 = 0; k0 < DIN; k0 += 64) {
        __syncthreads();   // previous step's LDS reads done
        // 72 staging units of 1 KB: A 2sp x 16 row-blocks, B 5 tiles x 8
#pragma unroll
        for (int i = 0; i < 18; ++i) {
            const int u = (i << 2) | w;          // 0..71
            const ushort* g;
            if (u < 32) {
                const int sp = u >> 4, rb = u & 15;
                g = xsp + (size_t)sp * ASTRIDE + (size_t)(m0 + (rb << 3) + lrow) * 1024 + k0 + sl8;
            } else {
                const int v = u - 32;            // 0..39
                const int bi = v >> 3;           // 0..4 = Wq0,Wq1,Wk0,Wk1,Wv0
                const int rb = v & 7;
                g = wtsp + (size_t)bi * WSTRIDE + (size_t)(n0 + (rb << 3) + lrow) * 1024 + k0 + sl8;
            }
            __builtin_amdgcn_global_load_lds(g, &SL[u * 512], 16, 0, 0);
        }
        __syncthreads();   // staging drained + visible

#pragma unroll
        for (int st = 0; st < 2; ++st) {
            const int sw = (((st << 2) | glane) ^ (col & 7)) << 3;
            bf16x8 a[2][2];   // [sp][mi]
#pragma unroll
            for (int sp = 0; sp < 2; ++sp)
#pragma unroll
                for (int mi = 0; mi < 2; ++mi) {
                    const int arow = (w << 5) + (mi << 4) + col;
                    a[sp][mi] = *reinterpret_cast<const bf16x8*>(&SL[sp * 8192 + arow * 64 + sw]);
                }
#pragma unroll
            for (int nj = 0; nj < 4; ++nj) {
                const int brow = (nj << 4) + col;
                const int bb = 16384 + brow * 64 + sw;
                const bf16x8 bq0 = *reinterpret_cast<const bf16x8*>(&SL[bb]);
                const bf16x8 bq1 = *reinterpret_cast<const bf16x8*>(&SL[bb + 4096]);
                const bf16x8 bk0 = *reinterpret_cast<const bf16x8*>(&SL[bb + 8192]);
                const bf16x8 bk1 = *reinterpret_cast<const bf16x8*>(&SL[bb + 12288]);
                const bf16x8 bv0 = *reinterpret_cast<const bf16x8*>(&SL[bb + 16384]);
#pragma unroll
                for (int mi = 0; mi < 2; ++mi) {
                    // Q, K: 3-term (a0b0 + a1b0 + a0b1)
                    accq[mi][nj] = mfma16(a[0][mi], bq0, accq[mi][nj]);
                    accq[mi][nj] = mfma16(a[1][mi], bq0, accq[mi][nj]);
                    accq[mi][nj] = mfma16(a[0][mi], bq1, accq[mi][nj]);
                    acck[mi][nj] = mfma16(a[0][mi], bk0, acck[mi][nj]);
                    acck[mi][nj] = mfma16(a[1][mi], bk0, acck[mi][nj]);
                    acck[mi][nj] = mfma16(a[0][mi], bk1, acck[mi][nj]);
                    // V^T: swapped operands -> out rows = d, out cols = s
                    accv[mi][nj] = mfma16(bv0, a[0][mi], accv[mi][nj]);
                    accv[mi][nj] = mfma16(bv0, a[1][mi], accv[mi][nj]);
                }
            }
        }
    }

    // ---- epilogue: Q fp32, K 2-split to [bh][s][d] ----
    const int b = m0 >> 11;
    const int h = n0 >> 6;
    const size_t bh_off = (size_t)(b * NH + h) * S * DH;
#pragma unroll
    for (int mi = 0; mi < 2; ++mi)
#pragma unroll
        for (int r = 0; r < 4; ++r) {
            const int srow = (m0 & (S - 1)) + (w << 5) + (mi << 4) + (glane << 2) + r;
#pragma unroll
            for (int nj = 0; nj < 4; ++nj) {
                const size_t o = bh_off + (size_t)srow * DH + (nj << 4) + col;
                qf[o] = accq[mi][nj][r];
                const float xk = acck[mi][nj][r];
                const ushort k0s = f2bf(xk);
                ksp[o] = k0s;
                ksp[ASTRIDE + o] = f2bf(xk - bf2f(k0s));
            }
        }

    // ---- V^T: direct register store to [bh][d][s'], granule-permuted ----
    const int cm = col >> 2;
    const int colp = (col & 3) | ((((cm & 1) << 1) | (cm >> 1)) << 2);
    const size_t vbh = (size_t)(b * NH + h) * DH * S;
#pragma unroll
    for (int mi = 0; mi < 2; ++mi) {
        const int s = (m0 & (S - 1)) + (w << 5) + (mi << 4) + colp;
#pragma unroll
        for (int nj = 0; nj < 4; ++nj)
#pragma unroll
            for (int r = 0; r < 4; ++r) {
                const int d = (nj << 4) + (glane << 2) + r;
                vtsp[vbh + (size_t)d * S + s] = f2bf(accv[mi][nj][r]);
            }
    }
}

// ---------------------------------------------------------------------------
// MFMA flash attention v7 (UNCHANGED, verified r9/r10): 32x32 swapped-QK,
// permutation-free P packing, K 2-split (5-term QK), V bf16 1-split,
// balanced (qt, 15-qt) CU pairing, double-buffered global_load_lds staging
// (48 KB LDS, 2 blocks/CU), tree softmax reductions.
// ---------------------------------------------------------------------------
__global__ __launch_bounds__(256, 2) void attn_mfma7(const float* __restrict__ Qf,
                                                     const ushort* __restrict__ ksp,
                                                     const ushort* __restrict__ vtsp,
                                                     float* __restrict__ out) {
    __shared__ __align__(16) ushort SB[2][12288];

    const int tid = threadIdx.x;
    const int lane = tid & 63;
    const int w = tid >> 6;

    const int xcd = blockIdx.x & 7;
    const int u_ = blockIdx.x >> 3;   // 0..63
    int bh, qt;
    if (u_ < 32) { bh = (xcd << 2) | (u_ >> 4);                 qt = 15 - (u_ & 15); }
    else         { const int v2 = u_ - 32; bh = (xcd << 2) | 2 | (v2 >> 4); qt = v2 & 15; }

    const int q0 = qt << 7;
    const int qw0 = q0 + (w << 5);
    const int hi = lane >> 5;
    const int ql = lane & 31;
    const int qg = qw0 + ql;
    const int lrow = lane >> 3;
    const int sl8 = ((lane & 7) ^ lrow) << 3;

    bf16x8 qb[3][4];
    {
        const float* qp = Qf + ((size_t)bh * S + qg) * DH + (hi << 3);
#pragma unroll
        for (int dc = 0; dc < 4; ++dc) {
            const float4 f0 = *reinterpret_cast<const float4*>(qp + (dc << 4));
            const float4 f1 = *reinterpret_cast<const float4*>(qp + (dc << 4) + 4);
            const float xs[8] = {f0.x, f0.y, f0.z, f0.w, f1.x, f1.y, f1.z, f1.w};
#pragma unroll
            for (int e = 0; e < 8; ++e) {
                const float x = xs[e] * 0.18033688011112042f;   // 1/8 * log2(e)
                const ushort h0 = f2bf(x);
                const float r1 = x - bf2f(h0);
                const ushort h1 = f2bf(r1);
                qb[0][dc][e] = (short)h0;
                qb[1][dc][e] = (short)h1;
                qb[2][dc][e] = (short)f2bf(r1 - bf2f(h1));
            }
        }
    }

    f32x16 O[2];
#pragma unroll
    for (int ds = 0; ds < 2; ++ds)
#pragma unroll
        for (int r = 0; r < 16; ++r) O[ds][r] = 0.f;
    float m_ = -INFINITY, l_ = 0.f;

    const size_t kbase = (size_t)bh * S * DH;
    const size_t vbase = (size_t)bh * DH * S;

#define ISSUE_KV(K0, BUF)                                                               \
    {                                                                                   \
        _Pragma("unroll")                                                               \
        for (int i = 0; i < 6; ++i) {                                                   \
            const int u = (i << 2) | w;                                                 \
            const ushort* gp;                                                           \
            if (u < 16) {                                                               \
                const int sp = u >> 3, rb = u & 7;                                      \
                gp = ksp + (size_t)sp * ASTRIDE + kbase +                               \
                     (size_t)((K0) + (rb << 3) + lrow) * DH + sl8;                      \
            } else {                                                                    \
                const int rb = u & 7;                                                   \
                gp = vtsp + vbase + (size_t)((rb << 3) + lrow) * S + (K0) + sl8;        \
            }                                                                           \
            __builtin_amdgcn_global_load_lds(gp, &SB[BUF][u * 512], 16, 0, 0);          \
        }                                                                               \
    }

    ISSUE_KV(0, 0);
    __syncthreads();

    const int ktmax = (q0 >> 6) + 1;
    for (int kt = 0; kt <= ktmax; ++kt) {
        const int k0 = kt << 6;
        const int cur = kt & 1;
        if (kt < ktmax) ISSUE_KV(k0 + 64, cur ^ 1);

        const bool active = (k0 <= qw0 + 31);
        if (active) {
            const ushort* KL = &SB[cur][0];
            const ushort* VL = &SB[cur][8192];

            f32x16 Sf[2];
#pragma unroll
            for (int ks = 0; ks < 2; ++ks)
#pragma unroll
                for (int r = 0; r < 16; ++r) Sf[ks][r] = 0.f;
#pragma unroll
            for (int ks = 0; ks < 2; ++ks) {
#pragma unroll
                for (int dc = 0; dc < 4; ++dc) {
                    const int row = (ks << 5) + ql;
                    const int eo = row * 64 + ((((dc << 1) | hi) ^ (row & 7)) << 3);
                    const bf16x8 ka = *reinterpret_cast<const bf16x8*>(&KL[eo]);
                    const bf16x8 kb = *reinterpret_cast<const bf16x8*>(&KL[4096 + eo]);
                    Sf[ks] = mfma32(ka, qb[0][dc], Sf[ks]);
                    Sf[ks] = mfma32(ka, qb[1][dc], Sf[ks]);
                    Sf[ks] = mfma32(ka, qb[2][dc], Sf[ks]);
                    Sf[ks] = mfma32(kb, qb[0][dc], Sf[ks]);
                    Sf[ks] = mfma32(kb, qb[1][dc], Sf[ks]);
                }
            }

            if (k0 + 63 > qw0) {
#pragma unroll
                for (int ks = 0; ks < 2; ++ks)
#pragma unroll
                    for (int r = 0; r < 16; ++r) {
                        const int kg = k0 + (ks << 5) + (r & 3) + ((r >> 2) << 3) + (hi << 2);
                        if (kg > qg) Sf[ks][r] = -1e30f;
                    }
            }

            float mx[8];
#pragma unroll
            for (int i = 0; i < 8; ++i)
                mx[i] = fmaxf(fmaxf(Sf[0][i], Sf[0][i + 8]),
                              fmaxf(Sf[1][i], Sf[1][i + 8]));
            float rm = fmaxf(fmaxf(fmaxf(mx[0], mx[1]), fmaxf(mx[2], mx[3])),
                             fmaxf(fmaxf(mx[4], mx[5]), fmaxf(mx[6], mx[7])));
            rm = fmaxf(rm, __shfl_xor(rm, 32));
            if (__any(rm > m_ + 8.f)) {
                const float nm = fmaxf(m_, rm);
                const float sc = exp2fast(m_ - nm);
                m_ = nm;
                l_ *= sc;
#pragma unroll
                for (int ds = 0; ds < 2; ++ds)
#pragma unroll
                    for (int r = 0; r < 16; ++r) O[ds][r] *= sc;
            }

            float rsa[4] = {0.f, 0.f, 0.f, 0.f};
            bf16x8 pb[4];
#pragma unroll
            for (int ks = 0; ks < 2; ++ks) {
                float p[16];
#pragma unroll
                for (int r = 0; r < 16; ++r) {
                    p[r] = exp2fast(Sf[ks][r] - m_);
                    rsa[r & 3] += p[r];
                }
#pragma unroll
                for (int c = 0; c < 2; ++c) {
                    union { unsigned u[4]; bf16x8 v; } pw;
                    pw.u[0] = cvt_pk(p[(c << 3) + 0], p[(c << 3) + 1]);
                    pw.u[1] = cvt_pk(p[(c << 3) + 2], p[(c << 3) + 3]);
                    pw.u[2] = cvt_pk(p[(c << 3) + 4], p[(c << 3) + 5]);
                    pw.u[3] = cvt_pk(p[(c << 3) + 6], p[(c << 3) + 7]);
                    pb[(ks << 1) + c] = pw.v;
                }
            }
            float rs = (rsa[0] + rsa[1]) + (rsa[2] + rsa[3]);
            rs += __shfl_xor(rs, 32);
            l_ += rs;

#pragma unroll
            for (int ds = 0; ds < 2; ++ds)
#pragma unroll
                for (int kc = 0; kc < 4; ++kc) {
                    const int row = (ds << 5) + ql;
                    const int eo = row * 64 + ((((kc << 1) | hi) ^ (row & 7)) << 3);
                    const bf16x8 va = *reinterpret_cast<const bf16x8*>(&VL[eo]);
                    O[ds] = mfma32(va, pb[kc], O[ds]);
                }
        }
        __syncthreads();
    }

    const float inv = 1.f / l_;
    const int b = bh >> 4, h = bh & (NH - 1);
    float* op = out + ((size_t)(b * S + qg)) * DOUT + h * DH;
#pragma unroll
    for (int ds = 0; ds < 2; ++ds)
#pragma unroll
        for (int rg = 0; rg < 4; ++rg) {
            float4 v;
            v.x = O[ds][(rg << 2) + 0] * inv;
            v.y = O[ds][(rg << 2) + 1] * inv;
            v.z = O[ds][(rg << 2) + 2] * inv;
            v.w = O[ds][(rg << 2) + 3] * inv;
            *reinterpret_cast<float4*>(&op[(ds << 5) + (rg << 3) + (hi << 2)]) = v;
        }
#undef ISSUE_KV
}

// ===========================================================================
// FALLBACK (fp32, ws >= 48 MB)
// ===========================================================================
__global__ __launch_bounds__(256) void proj_f32(const float* __restrict__ A,
                                                const float* __restrict__ W,
                                                float* __restrict__ outf) {
    __shared__ float As[16][68];
    __shared__ float Bs[16][68];
    const int tid = threadIdx.x;
    const int m0 = blockIdx.x * 64;
    const int n0 = blockIdx.y * 64;
    const int tm = tid >> 4, tn = tid & 15;
    const int la_r = tid >> 2, la_c = (tid & 3) << 2;
    const int lb_r = tid >> 4, lb_c = (tid & 15) << 2;

    float acc[4][4];
#pragma unroll
    for (int i = 0; i < 4; ++i)
#pragma unroll
        for (int j = 0; j < 4; ++j) acc[i][j] = 0.f;

    for (int k0 = 0; k0 < DIN; k0 += 16) {
        const float4 av = *reinterpret_cast<const float4*>(&A[(size_t)(m0 + la_r) * DIN + k0 + la_c]);
        const float4 bv = *reinterpret_cast<const float4*>(&W[(size_t)(k0 + lb_r) * DOUT + n0 + lb_c]);
        __syncthreads();
        As[la_c + 0][la_r] = av.x; As[la_c + 1][la_r] = av.y;
        As[la_c + 2][la_r] = av.z; As[la_c + 3][la_r] = av.w;
        *reinterpret_cast<float4*>(&Bs[lb_r][lb_c]) = bv;
        __syncthreads();
#pragma unroll
        for (int kk = 0; kk < 16; ++kk) {
            const float4 a = *reinterpret_cast<const float4*>(&As[kk][tm << 2]);
            const float4 b = *reinterpret_cast<const float4*>(&Bs[kk][tn << 2]);
            const float aa[4] = {a.x, a.y, a.z, a.w};
            const float bb[4] = {b.x, b.y, b.z, b.w};
#pragma unroll
            for (int i = 0; i < 4; ++i)
#pragma unroll
                for (int j = 0; j < 4; ++j) acc[i][j] += aa[i] * bb[j];
        }
    }
    const int b = m0 >> 11;
    const int s_base = (m0 & (S - 1)) + (tm << 2);
    const int h = n0 >> 6;
    const int dh = tn << 2;
    float* obase = outf + ((size_t)(b * NH + h) * S) * DH;
#pragma unroll
    for (int i = 0; i < 4; ++i) {
        float4 v;
        v.x = acc[i][0]; v.y = acc[i][1]; v.z = acc[i][2]; v.w = acc[i][3];
        *reinterpret_cast<float4*>(&obase[(size_t)(s_base + i) * DH + dh]) = v;
    }
}

__global__ __launch_bounds__(256) void attn_f32(const float* __restrict__ Q,
                                                const float* __restrict__ K,
                                                const float* __restrict__ V,
                                                float* __restrict__ out) {
    __shared__ float Qs[64][68];
    __shared__ float Ks[64][68];
    __shared__ float Vs[64][68];
    __shared__ float Ps[64][68];
    const int tid = threadIdx.x;
    const int bh = blockIdx.x & 31;
    const int qt = 31 - (blockIdx.x >> 5);
    const int q0 = qt << 6;
    const int tq = tid >> 4, tk = tid & 15;
    const int sr = tid >> 2, sc = (tid & 3) << 2;

    const float* qbase = Q + ((size_t)bh * S + q0) * DH;
    const float* kbase = K + (size_t)bh * S * DH;
    const float* vbase = V + (size_t)bh * S * DH;
#pragma unroll
    for (int it = 0; it < 4; ++it) {
        const int d0 = sc + (it << 4);
        const float4 v = *reinterpret_cast<const float4*>(&qbase[(size_t)sr * DH + d0]);
        Qs[d0 + 0][sr] = v.x; Qs[d0 + 1][sr] = v.y;
        Qs[d0 + 2][sr] = v.z; Qs[d0 + 3][sr] = v.w;
    }
    float C[4][4];
#pragma unroll
    for (int i = 0; i < 4; ++i)
#pragma unroll
        for (int j = 0; j < 4; ++j) C[i][j] = 0.f;
    float m[4] = {-1e30f, -1e30f, -1e30f, -1e30f};
    float l[4] = {0.f, 0.f, 0.f, 0.f};

    for (int kt = 0; kt <= qt; ++kt) {
        const int k0 = kt << 6;
        float4 kv[4], vv[4];
#pragma unroll
        for (int it = 0; it < 4; ++it) {
            const int d0 = sc + (it << 4);
            kv[it] = *reinterpret_cast<const float4*>(&kbase[(size_t)(k0 + sr) * DH + d0]);
            vv[it] = *reinterpret_cast<const float4*>(&vbase[(size_t)(k0 + sr) * DH + d0]);
        }
        __syncthreads();
#pragma unroll
        for (int it = 0; it < 4; ++it) {
            const int d0 = sc + (it << 4);
            Ks[d0 + 0][sr] = kv[it].x; Ks[d0 + 1][sr] = kv[it].y;
            Ks[d0 + 2][sr] = kv[it].z; Ks[d0 + 3][sr] = kv[it].w;
            *reinterpret_cast<float4*>(&Vs[sr][d0]) = vv[it];
        }
        __syncthreads();

        float s[4][4];
#pragma unroll
        for (int i = 0; i < 4; ++i)
#pragma unroll
            for (int j = 0; j < 4; ++j) s[i][j] = 0.f;
#pragma unroll 16
        for (int d = 0; d < 64; ++d) {
            const float4 qf4 = *reinterpret_cast<const float4*>(&Qs[d][tq << 2]);
            const float4 kf4 = *reinterpret_cast<const float4*>(&Ks[d][tk << 2]);
            const float qa[4] = {qf4.x, qf4.y, qf4.z, qf4.w};
            const float ka[4] = {kf4.x, kf4.y, kf4.z, kf4.w};
#pragma unroll
            for (int i = 0; i < 4; ++i)
#pragma unroll
                for (int j = 0; j < 4; ++j) s[i][j] += qa[i] * ka[j];
        }
        if (kt == qt) {
#pragma unroll
            for (int i = 0; i < 4; ++i) {
                const int qg = q0 + (tq << 2) + i;
#pragma unroll
                for (int j = 0; j < 4; ++j) {
                    const int kg = k0 + (tk << 2) + j;
                    s[i][j] = (kg <= qg) ? s[i][j] * 0.125f : -1e30f;
                }
            }
        } else {
#pragma unroll
            for (int i = 0; i < 4; ++i)
#pragma unroll
                for (int j = 0; j < 4; ++j) s[i][j] *= 0.125f;
        }
#pragma unroll
        for (int i = 0; i < 4; ++i) {
            float rm = fmaxf(fmaxf(s[i][0], s[i][1]), fmaxf(s[i][2], s[i][3]));
#pragma unroll
            for (int off = 1; off < 16; off <<= 1) rm = fmaxf(rm, __shfl_xor(rm, off));
            const float mn = fmaxf(m[i], rm);
            const float scale = __expf(m[i] - mn);
            float rs = 0.f;
#pragma unroll
            for (int j = 0; j < 4; ++j) {
                s[i][j] = __expf(s[i][j] - mn);
                rs += s[i][j];
            }
#pragma unroll
            for (int off = 1; off < 16; off <<= 1) rs += __shfl_xor(rs, off);
            l[i] = l[i] * scale + rs;
            m[i] = mn;
#pragma unroll
            for (int j = 0; j < 4; ++j) C[i][j] *= scale;
            *reinterpret_cast<float4*>(&Ps[(tq << 2) + i][tk << 2]) =
                make_float4(s[i][0], s[i][1], s[i][2], s[i][3]);
        }
        __syncthreads();
#pragma unroll 4
        for (int kc = 0; kc < 16; ++kc) {
            float4 pf[4], vf[4];
#pragma unroll
            for (int i = 0; i < 4; ++i)
                pf[i] = *reinterpret_cast<const float4*>(&Ps[(tq << 2) + i][kc << 2]);
#pragma unroll
            for (int j = 0; j < 4; ++j)
                vf[j] = *reinterpret_cast<const float4*>(&Vs[(kc << 2) + j][tk << 2]);
#pragma unroll
            for (int i = 0; i < 4; ++i) {
                const float pa[4] = {pf[i].x, pf[i].y, pf[i].z, pf[i].w};
#pragma unroll
                for (int j = 0; j < 4; ++j) {
                    C[i][j] += pa[0] * ((const float*)&vf[0])[j]
                             + pa[1] * ((const float*)&vf[1])[j]
                             + pa[2] * ((const float*)&vf[2])[j]
                             + pa[3] * ((const float*)&vf[3])[j];
                }
            }
        }
        __syncthreads();
    }
    const int b = bh >> 4, h = bh & (NH - 1);
#pragma unroll
    for (int i = 0; i < 4; ++i) {
        const int qg = q0 + (tq << 2) + i;
        const float inv = 1.f / l[i];
        float4 v;
        v.x = C[i][0] * inv; v.y = C[i][1] * inv;
        v.z = C[i][2] * inv; v.w = C[i][3] * inv;
        *reinterpret_cast<float4*>(&out[((size_t)(b * S + qg)) * DOUT + h * DH + (tk << 2)]) = v;
    }
}

// ===========================================================================
extern "C" void kernel_launch(void* const* d_in, const int* in_sizes, int n_in,
                              void* d_out, int out_size, void* d_ws, size_t ws_size,
                              hipStream_t stream) {
    const float* x  = (const float*)d_in[0];
    const float* Wq = (const float*)d_in[1];
    const float* Wk = (const float*)d_in[2];
    const float* Wv = (const float*)d_in[3];
    float* out = (float*)d_out;

    char* ws = (char*)d_ws;
    const size_t MB = 1024 * 1024;

    if (ws_size >= 68 * MB) {
        // layout: wT[0,12) | xsp 2-split[12,28) | Q[28,44) | K 2-split[44,60) |
        //         V^T bf16 1-split[60,68)
        ushort* wtsp = (ushort*)(ws);
        ushort* xsp  = (ushort*)(ws + 12 * MB);
        float*  qf   = (float*)(ws + 28 * MB);
        ushort* ksp  = (ushort*)(ws + 44 * MB);
        ushort* vtsp = (ushort*)(ws + 60 * MB);

        split_x<<<4096, 256, 0, stream>>>(x, xsp);
        split_wT3<<<dim3(16, 16, 3), 256, 0, stream>>>(Wq, Wk, Wv, wtsp);
        proj_fused5<<<512, 256, 0, stream>>>(xsp, wtsp, qf, ksp, vtsp);
        attn_mfma7<<<512, 256, 0, stream>>>(qf, ksp, vtsp, out);
    } else {
        // fp32 fallback (48 MB)
        float* qws = (float*)d_ws;
        float* kws = qws + (size_t)M_TOT * DOUT;
        float* vws = kws + (size_t)M_TOT * DOUT;
        dim3 pgrid(M_TOT / 64, DOUT / 64);
        proj_f32<<<pgrid, 256, 0, stream>>>(x, Wq, qws);
        proj_f32<<<pgrid, 256, 0, stream>>>(x, Wk, kws);
        proj_f32<<<pgrid, 256, 0, stream>>>(x, Wv, vws);
        attn_f32<<<32 * 32, 256, 0, stream>>>(qws, kws, vws, out);
    }
}

// Round 12
// 129.703 us; speedup vs baseline: 31.5975x; 1.0285x over previous
//
#include <hip/hip_runtime.h>
#include <hip/hip_bf16.h>

// Problem constants: B=2, S=2048, D_IN=1024, D_OUT=1024, H=16, Dh=64
#define B 2
#define S 2048
#define DIN 1024
#define DOUT 1024
#define NH 16
#define DH 64
#define M_TOT (B * S)   // 4096

typedef __attribute__((ext_vector_type(8))) short bf16x8;
typedef __attribute__((ext_vector_type(8))) unsigned short u16x8;
typedef __attribute__((ext_vector_type(4))) float f32x4;
typedef __attribute__((ext_vector_type(16))) float f32x16;

#define ASTRIDE 4194304   // elements per 4096x1024 split array
#define WSTRIDE 1048576   // elements per 1024x1024 split array

__device__ __forceinline__ ushort f2bf(float x) {
    union { float f; unsigned u; } c; c.f = x;
    unsigned r = (c.u + 0x7FFFu + ((c.u >> 16) & 1u)) >> 16;
    return (ushort)r;
}
__device__ __forceinline__ float bf2f(ushort h) {
    union { unsigned u; float f; } c; c.u = ((unsigned)h) << 16;
    return c.f;
}
__device__ __forceinline__ f32x4 mfma16(bf16x8 a, bf16x8 b, f32x4 c) {
    return __builtin_amdgcn_mfma_f32_16x16x32_bf16(a, b, c, 0, 0, 0);
}
__device__ __forceinline__ f32x16 mfma32(bf16x8 a, bf16x8 b, f32x16 c) {
    return __builtin_amdgcn_mfma_f32_32x32x16_bf16(a, b, c, 0, 0, 0);
}
__device__ __forceinline__ unsigned cvt_pk(float lo, float hi) {
    unsigned r;
    asm("v_cvt_pk_bf16_f32 %0, %1, %2" : "=v"(r) : "v"(lo), "v"(hi));
    return r;
}
__device__ __forceinline__ float exp2fast(float x) {
    float r;
    asm("v_exp_f32 %0, %1" : "=v"(r) : "v"(x));
    return r;
}

// ===========================================================================
// MAIN PATH (ws >= 68 MB)
// ===========================================================================

// ---- prepass: x (fp32 [4096][1024]) -> 2-way bf16 splits ----
__global__ __launch_bounds__(256) void split_x(const float* __restrict__ x,
                                               ushort* __restrict__ xs) {
    const size_t gid = (size_t)blockIdx.x * 256 + threadIdx.x;
    const float4 v = *reinterpret_cast<const float4*>(x + gid * 4);
    const float in[4] = {v.x, v.y, v.z, v.w};
    ushort h0[4], h1[4];
#pragma unroll
    for (int e = 0; e < 4; ++e) {
        h0[e] = f2bf(in[e]);
        h1[e] = f2bf(in[e] - bf2f(h0[e]));
    }
    const size_t o = gid * 4;
    *reinterpret_cast<ushort4*>(xs + o)           = ushort4{h0[0], h0[1], h0[2], h0[3]};
    *reinterpret_cast<ushort4*>(xs + ASTRIDE + o) = ushort4{h1[0], h1[1], h1[2], h1[3]};
}

// ---- prepass: all three W -> W^T 2-way bf16 splits, wt[wi][sp][n][k] ----
__global__ __launch_bounds__(256) void split_wT3(const float* __restrict__ W0,
                                                 const float* __restrict__ W1,
                                                 const float* __restrict__ W2,
                                                 ushort* __restrict__ wt) {
    __shared__ float Ws[64][68];
    const int tid = threadIdx.x;
    const int k0 = blockIdx.x << 6;
    const int n0 = blockIdx.y << 6;
    const int wi = blockIdx.z;
    const float* W = (wi == 0) ? W0 : (wi == 1) ? W1 : W2;
    ushort* wto = wt + (size_t)wi * 2 * WSTRIDE;

    const int r = tid >> 2;
    const int cb = (tid & 3) << 2;
#pragma unroll
    for (int it = 0; it < 4; ++it) {
        const int c = cb + (it << 4);
        *reinterpret_cast<float4*>(&Ws[r][c]) =
            *reinterpret_cast<const float4*>(&W[(size_t)(k0 + r) * 1024 + n0 + c]);
    }
    __syncthreads();
    const int rn = tid >> 2;
    const int kc = (tid & 3) << 4;
    u16x8 o0[2], o1[2];
#pragma unroll
    for (int half = 0; half < 2; ++half)
#pragma unroll
        for (int i = 0; i < 8; ++i) {
            const float x = Ws[kc + (half << 3) + i][rn];
            const ushort a = f2bf(x);
            o0[half][i] = a;
            o1[half][i] = f2bf(x - bf2f(a));
        }
    const size_t base = (size_t)(n0 + rn) * 1024 + k0 + kc;
    *reinterpret_cast<u16x8*>(wto + base)               = o0[0];
    *reinterpret_cast<u16x8*>(wto + base + 8)           = o0[1];
    *reinterpret_cast<u16x8*>(wto + WSTRIDE + base)     = o1[0];
    *reinterpret_cast<u16x8*>(wto + WSTRIDE + base + 8) = o1[1];
}

// ---------------------------------------------------------------------------
// Fused QKV projection v5 (UNCHANGED from round 11, verified): single 72 KB
// buffer, 2 barriers/step, 2 blocks/CU; Q/K 3-term, V 2-term; V^T via
// swapped-operand mfma16 with granule-permuted direct store.
// ---------------------------------------------------------------------------
__global__ __launch_bounds__(256, 2) void proj_fused5(const ushort* __restrict__ xsp,
                                                      const ushort* __restrict__ wtsp,
                                                      float* __restrict__ qf,
                                                      ushort* __restrict__ ksp,
                                                      ushort* __restrict__ vtsp) {
    __shared__ __align__(16) ushort SL[36864];   // 72 KB

    const int tid = threadIdx.x;
    const int lane = tid & 63;
    const int w = tid >> 6;
    const int swz = (blockIdx.x & 7) * 64 + (blockIdx.x >> 3);   // 512 blocks, bijective
    const int n0 = (swz & 15) << 6;
    const int m0 = (swz >> 4) << 7;   // 32 m-tiles of 128
    const int col = lane & 15;
    const int glane = lane >> 4;
    const int lrow = lane >> 3;
    const int sl8 = ((lane & 7) ^ lrow) << 3;

    f32x4 accq[2][4], acck[2][4], accv[2][4];   // [mi][nj]; accv is TRANSPOSED
#pragma unroll
    for (int mi = 0; mi < 2; ++mi)
#pragma unroll
        for (int nj = 0; nj < 4; ++nj) {
            accq[mi][nj] = f32x4{0.f, 0.f, 0.f, 0.f};
            acck[mi][nj] = f32x4{0.f, 0.f, 0.f, 0.f};
            accv[mi][nj] = f32x4{0.f, 0.f, 0.f, 0.f};
        }

    for (int k0 = 0; k0 < DIN; k0 += 64) {
        __syncthreads();   // previous step's LDS reads done
#pragma unroll
        for (int i = 0; i < 18; ++i) {
            const int u = (i << 2) | w;          // 0..71
            const ushort* g;
            if (u < 32) {
                const int sp = u >> 4, rb = u & 15;
                g = xsp + (size_t)sp * ASTRIDE + (size_t)(m0 + (rb << 3) + lrow) * 1024 + k0 + sl8;
            } else {
                const int v = u - 32;            // 0..39
                const int bi = v >> 3;           // 0..4 = Wq0,Wq1,Wk0,Wk1,Wv0
                const int rb = v & 7;
                g = wtsp + (size_t)bi * WSTRIDE + (size_t)(n0 + (rb << 3) + lrow) * 1024 + k0 + sl8;
            }
            __builtin_amdgcn_global_load_lds(g, &SL[u * 512], 16, 0, 0);
        }
        __syncthreads();   // staging drained + visible

#pragma unroll
        for (int st = 0; st < 2; ++st) {
            const int sw = (((st << 2) | glane) ^ (col & 7)) << 3;
            bf16x8 a[2][2];   // [sp][mi]
#pragma unroll
            for (int sp = 0; sp < 2; ++sp)
#pragma unroll
                for (int mi = 0; mi < 2; ++mi) {
                    const int arow = (w << 5) + (mi << 4) + col;
                    a[sp][mi] = *reinterpret_cast<const bf16x8*>(&SL[sp * 8192 + arow * 64 + sw]);
                }
#pragma unroll
            for (int nj = 0; nj < 4; ++nj) {
                const int brow = (nj << 4) + col;
                const int bb = 16384 + brow * 64 + sw;
                const bf16x8 bq0 = *reinterpret_cast<const bf16x8*>(&SL[bb]);
                const bf16x8 bq1 = *reinterpret_cast<const bf16x8*>(&SL[bb + 4096]);
                const bf16x8 bk0 = *reinterpret_cast<const bf16x8*>(&SL[bb + 8192]);
                const bf16x8 bk1 = *reinterpret_cast<const bf16x8*>(&SL[bb + 12288]);
                const bf16x8 bv0 = *reinterpret_cast<const bf16x8*>(&SL[bb + 16384]);
#pragma unroll
                for (int mi = 0; mi < 2; ++mi) {
                    accq[mi][nj] = mfma16(a[0][mi], bq0, accq[mi][nj]);
                    accq[mi][nj] = mfma16(a[1][mi], bq0, accq[mi][nj]);
                    accq[mi][nj] = mfma16(a[0][mi], bq1, accq[mi][nj]);
                    acck[mi][nj] = mfma16(a[0][mi], bk0, acck[mi][nj]);
                    acck[mi][nj] = mfma16(a[1][mi], bk0, acck[mi][nj]);
                    acck[mi][nj] = mfma16(a[0][mi], bk1, acck[mi][nj]);
                    accv[mi][nj] = mfma16(bv0, a[0][mi], accv[mi][nj]);
                    accv[mi][nj] = mfma16(bv0, a[1][mi], accv[mi][nj]);
                }
            }
        }
    }

    // ---- epilogue: Q fp32, K 2-split to [bh][s][d] ----
    const int b = m0 >> 11;
    const int h = n0 >> 6;
    const size_t bh_off = (size_t)(b * NH + h) * S * DH;
#pragma unroll
    for (int mi = 0; mi < 2; ++mi)
#pragma unroll
        for (int r = 0; r < 4; ++r) {
            const int srow = (m0 & (S - 1)) + (w << 5) + (mi << 4) + (glane << 2) + r;
#pragma unroll
            for (int nj = 0; nj < 4; ++nj) {
                const size_t o = bh_off + (size_t)srow * DH + (nj << 4) + col;
                qf[o] = accq[mi][nj][r];
                const float xk = acck[mi][nj][r];
                const ushort k0s = f2bf(xk);
                ksp[o] = k0s;
                ksp[ASTRIDE + o] = f2bf(xk - bf2f(k0s));
            }
        }

    // ---- V^T: direct register store to [bh][d][s'], granule-permuted ----
    const int cm = col >> 2;
    const int colp = (col & 3) | ((((cm & 1) << 1) | (cm >> 1)) << 2);
    const size_t vbh = (size_t)(b * NH + h) * DH * S;
#pragma unroll
    for (int mi = 0; mi < 2; ++mi) {
        const int s = (m0 & (S - 1)) + (w << 5) + (mi << 4) + colp;
#pragma unroll
        for (int nj = 0; nj < 4; ++nj)
#pragma unroll
            for (int r = 0; r < 4; ++r) {
                const int d = (nj << 4) + (glane << 2) + r;
                vtsp[vbh + (size_t)d * S + s] = f2bf(accv[mi][nj][r]);
            }
    }
}

// ---------------------------------------------------------------------------
// MFMA flash attention v8: occupancy-oriented restructure.
// QBLK=64, 2 waves/block (128 threads), grid 1024 -> 4 blocks/CU, 2-wave
// barriers, 4 independent instruction streams per CU. Single 24 KB buffer,
// split-barrier prefetch (r5-verified): QK -> bar -> issue K(t+1) -> softmax
// -> PV -> bar -> issue V(t+1). QK 4-term ((k0+k1)(q0+q1)); V 1-split.
// setprio(1) around MFMA clusters. Balanced CU pairing: per CU slot the 4
// blocks' qt are {15-j, 16+j} x 2 bh -> 66 tiles each.
// ---------------------------------------------------------------------------
__global__ __launch_bounds__(128, 2) void attn_mfma8(const float* __restrict__ Qf,
                                                     const ushort* __restrict__ ksp,
                                                     const ushort* __restrict__ vtsp,
                                                     float* __restrict__ out) {
    __shared__ __align__(16) ushort KL[2][4096];   // K splits, 16 KB
    __shared__ __align__(16) ushort VL[4096];      // V^T, 8 KB

    const int tid = threadIdx.x;
    const int lane = tid & 63;
    const int w = tid >> 6;                        // wave 0..1

    // balanced bijective mapping (1024 blocks): xcd | slot s_ | pass p_
    const int xcd = blockIdx.x & 7;
    const int u_ = blockIdx.x >> 3;                // 0..127
    const int s_ = u_ & 31, p_ = u_ >> 5;          // CU slot, pass
    const int bh = (xcd << 2) | ((s_ >> 4) << 1) | (p_ >> 1);
    const int j_ = s_ & 15;
    const int qt = (p_ & 1) ? (16 + j_) : (15 - j_);   // 0..31

    const int q0 = qt << 6;                        // 64-row q tile
    const int qw0 = q0 + (w << 5);                 // wave's 32 q rows
    const int hi = lane >> 5;
    const int ql = lane & 31;
    const int qg = qw0 + ql;
    const int lrow = lane >> 3;
    const int sl8 = ((lane & 7) ^ lrow) << 3;

    // ---- Q fragments: (1/8 * log2e) folded, 2 splits x 4 d-chunks ----
    bf16x8 qb[2][4];
    {
        const float* qp = Qf + ((size_t)bh * S + qg) * DH + (hi << 3);
#pragma unroll
        for (int dc = 0; dc < 4; ++dc) {
            const float4 f0 = *reinterpret_cast<const float4*>(qp + (dc << 4));
            const float4 f1 = *reinterpret_cast<const float4*>(qp + (dc << 4) + 4);
            const float xs[8] = {f0.x, f0.y, f0.z, f0.w, f1.x, f1.y, f1.z, f1.w};
#pragma unroll
            for (int e = 0; e < 8; ++e) {
                const float x = xs[e] * 0.18033688011112042f;   // 1/8 * log2(e)
                const ushort h0 = f2bf(x);
                qb[0][dc][e] = (short)h0;
                qb[1][dc][e] = (short)f2bf(x - bf2f(h0));
            }
        }
    }

    f32x16 O[2];
#pragma unroll
    for (int ds = 0; ds < 2; ++ds)
#pragma unroll
        for (int r = 0; r < 16; ++r) O[ds][r] = 0.f;
    float m_ = -INFINITY, l_ = 0.f;

    const size_t kbase = (size_t)bh * S * DH;
    const size_t vbase = (size_t)bh * DH * S;

    // K: 16 units of 1 KB (2 splits x 8 row-blocks); V: 8 units
#define ISSUE_K(K0)                                                                     \
    {                                                                                   \
        _Pragma("unroll")                                                               \
        for (int i = 0; i < 8; ++i) {                                                   \
            const int u = (i << 1) | w;                                                 \
            const int sp = u >> 3, rb = u & 7;                                          \
            const ushort* gp = ksp + (size_t)sp * ASTRIDE + kbase +                     \
                               (size_t)((K0) + (rb << 3) + lrow) * DH + sl8;            \
            __builtin_amdgcn_global_load_lds(gp, &KL[sp][rb << 9], 16, 0, 0);           \
        }                                                                               \
    }
#define ISSUE_V(K0)                                                                     \
    {                                                                                   \
        _Pragma("unroll")                                                               \
        for (int i = 0; i < 4; ++i) {                                                   \
            const int u = (i << 1) | w;                                                 \
            const ushort* gp = vtsp + vbase +                                           \
                               (size_t)((u << 3) + lrow) * S + (K0) + sl8;              \
            __builtin_amdgcn_global_load_lds(gp, &VL[u << 9], 16, 0, 0);                \
        }                                                                               \
    }

    ISSUE_K(0);
    ISSUE_V(0);
    __syncthreads();

    for (int kt = 0; kt <= qt; ++kt) {
        const int k0 = kt << 6;

        // ---- S^T = K Q^T (64k x 32q per wave, 4 split terms) ----
        f32x16 Sf[2];
#pragma unroll
        for (int ks = 0; ks < 2; ++ks)
#pragma unroll
            for (int r = 0; r < 16; ++r) Sf[ks][r] = 0.f;
        __builtin_amdgcn_s_setprio(1);
#pragma unroll
        for (int ks = 0; ks < 2; ++ks) {
#pragma unroll
            for (int dc = 0; dc < 4; ++dc) {
                const int row = (ks << 5) + ql;
                const int eo = row * 64 + ((((dc << 1) | hi) ^ (row & 7)) << 3);
                const bf16x8 ka = *reinterpret_cast<const bf16x8*>(&KL[0][eo]);
                const bf16x8 kb = *reinterpret_cast<const bf16x8*>(&KL[1][eo]);
                Sf[ks] = mfma32(ka, qb[0][dc], Sf[ks]);
                Sf[ks] = mfma32(ka, qb[1][dc], Sf[ks]);
                Sf[ks] = mfma32(kb, qb[0][dc], Sf[ks]);
                Sf[ks] = mfma32(kb, qb[1][dc], Sf[ks]);
            }
        }
        __builtin_amdgcn_s_setprio(0);

        __syncthreads();                 // all waves done reading K(t)
        if (kt < qt) ISSUE_K(k0 + 64);   // prefetch under softmax+PV

        // ---- causal mask (only near-diagonal tiles) ----
        if (k0 + 63 > qw0) {
#pragma unroll
            for (int ks = 0; ks < 2; ++ks)
#pragma unroll
                for (int r = 0; r < 16; ++r) {
                    const int kg = k0 + (ks << 5) + (r & 3) + ((r >> 2) << 3) + (hi << 2);
                    if (kg > qg) Sf[ks][r] = -1e30f;
                }
        }

        // ---- lane-local softmax, tree max, defer-max ----
        float mx[8];
#pragma unroll
        for (int i = 0; i < 8; ++i)
            mx[i] = fmaxf(fmaxf(Sf[0][i], Sf[0][i + 8]),
                          fmaxf(Sf[1][i], Sf[1][i + 8]));
        float rm = fmaxf(fmaxf(fmaxf(mx[0], mx[1]), fmaxf(mx[2], mx[3])),
                         fmaxf(fmaxf(mx[4], mx[5]), fmaxf(mx[6], mx[7])));
        rm = fmaxf(rm, __shfl_xor(rm, 32));
        if (__any(rm > m_ + 8.f)) {
            const float nm = fmaxf(m_, rm);
            const float sc = exp2fast(m_ - nm);
            m_ = nm;
            l_ *= sc;
#pragma unroll
            for (int ds = 0; ds < 2; ++ds)
#pragma unroll
                for (int r = 0; r < 16; ++r) O[ds][r] *= sc;
        }

        // ---- P = 2^(S - m), tree sum, in-order B-frag packing ----
        float rsa[4] = {0.f, 0.f, 0.f, 0.f};
        bf16x8 pb[4];
#pragma unroll
        for (int ks = 0; ks < 2; ++ks) {
            float p[16];
#pragma unroll
            for (int r = 0; r < 16; ++r) {
                p[r] = exp2fast(Sf[ks][r] - m_);
                rsa[r & 3] += p[r];
            }
#pragma unroll
            for (int c = 0; c < 2; ++c) {
                union { unsigned u[4]; bf16x8 v; } pw;
                pw.u[0] = cvt_pk(p[(c << 3) + 0], p[(c << 3) + 1]);
                pw.u[1] = cvt_pk(p[(c << 3) + 2], p[(c << 3) + 3]);
                pw.u[2] = cvt_pk(p[(c << 3) + 4], p[(c << 3) + 5]);
                pw.u[3] = cvt_pk(p[(c << 3) + 6], p[(c << 3) + 7]);
                pb[(ks << 1) + c] = pw.v;
            }
        }
        float rs = (rsa[0] + rsa[1]) + (rsa[2] + rsa[3]);
        rs += __shfl_xor(rs, 32);
        l_ += rs;

        // ---- O^T += V^T P^T ----
        __builtin_amdgcn_s_setprio(1);
#pragma unroll
        for (int ds = 0; ds < 2; ++ds)
#pragma unroll
            for (int kc = 0; kc < 4; ++kc) {
                const int row = (ds << 5) + ql;
                const int eo = row * 64 + ((((kc << 1) | hi) ^ (row & 7)) << 3);
                const bf16x8 va = *reinterpret_cast<const bf16x8*>(&VL[eo]);
                O[ds] = mfma32(va, pb[kc], O[ds]);
            }
        __builtin_amdgcn_s_setprio(0);

        __syncthreads();                 // all waves done reading V(t); K(t+1) drained
        if (kt < qt) ISSUE_V(k0 + 64);   // prefetch under next QK
    }

    // ---- epilogue: O^T[d, q] -> out[b, q, h*64 + d] ----
    const float inv = 1.f / l_;
    const int b = bh >> 4, h = bh & (NH - 1);
    float* op = out + ((size_t)(b * S + qg)) * DOUT + h * DH;
#pragma unroll
    for (int ds = 0; ds < 2; ++ds)
#pragma unroll
        for (int rg = 0; rg < 4; ++rg) {
            float4 v;
            v.x = O[ds][(rg << 2) + 0] * inv;
            v.y = O[ds][(rg << 2) + 1] * inv;
            v.z = O[ds][(rg << 2) + 2] * inv;
            v.w = O[ds][(rg << 2) + 3] * inv;
            *reinterpret_cast<float4*>(&op[(ds << 5) + (rg << 3) + (hi << 2)]) = v;
        }
#undef ISSUE_K
#undef ISSUE_V
}

// ===========================================================================
// FALLBACK (fp32, ws >= 48 MB)
// ===========================================================================
__global__ __launch_bounds__(256) void proj_f32(const float* __restrict__ A,
                                                const float* __restrict__ W,
                                                float* __restrict__ outf) {
    __shared__ float As[16][68];
    __shared__ float Bs[16][68];
    const int tid = threadIdx.x;
    const int m0 = blockIdx.x * 64;
    const int n0 = blockIdx.y * 64;
    const int tm = tid >> 4, tn = tid & 15;
    const int la_r = tid >> 2, la_c = (tid & 3) << 2;
    const int lb_r = tid >> 4, lb_c = (tid & 15) << 2;

    float acc[4][4];
#pragma unroll
    for (int i = 0; i < 4; ++i)
#pragma unroll
        for (int j = 0; j < 4; ++j) acc[i][j] = 0.f;

    for (int k0 = 0; k0 < DIN; k0 += 16) {
        const float4 av = *reinterpret_cast<const float4*>(&A[(size_t)(m0 + la_r) * DIN + k0 + la_c]);
        const float4 bv = *reinterpret_cast<const float4*>(&W[(size_t)(k0 + lb_r) * DOUT + n0 + lb_c]);
        __syncthreads();
        As[la_c + 0][la_r] = av.x; As[la_c + 1][la_r] = av.y;
        As[la_c + 2][la_r] = av.z; As[la_c + 3][la_r] = av.w;
        *reinterpret_cast<float4*>(&Bs[lb_r][lb_c]) = bv;
        __syncthreads();
#pragma unroll
        for (int kk = 0; kk < 16; ++kk) {
            const float4 a = *reinterpret_cast<const float4*>(&As[kk][tm << 2]);
            const float4 b = *reinterpret_cast<const float4*>(&Bs[kk][tn << 2]);
            const float aa[4] = {a.x, a.y, a.z, a.w};
            const float bb[4] = {b.x, b.y, b.z, b.w};
#pragma unroll
            for (int i = 0; i < 4; ++i)
#pragma unroll
                for (int j = 0; j < 4; ++j) acc[i][j] += aa[i] * bb[j];
        }
    }
    const int b = m0 >> 11;
    const int s_base = (m0 & (S - 1)) + (tm << 2);
    const int h = n0 >> 6;
    const int dh = tn << 2;
    float* obase = outf + ((size_t)(b * NH + h) * S) * DH;
#pragma unroll
    for (int i = 0; i < 4; ++i) {
        float4 v;
        v.x = acc[i][0]; v.y = acc[i][1]; v.z = acc[i][2]; v.w = acc[i][3];
        *reinterpret_cast<float4*>(&obase[(size_t)(s_base + i) * DH + dh]) = v;
    }
}

__global__ __launch_bounds__(256) void attn_f32(const float* __restrict__ Q,
                                                const float* __restrict__ K,
                                                const float* __restrict__ V,
                                                float* __restrict__ out) {
    __shared__ float Qs[64][68];
    __shared__ float Ks[64][68];
    __shared__ float Vs[64][68];
    __shared__ float Ps[64][68];
    const int tid = threadIdx.x;
    const int bh = blockIdx.x & 31;
    const int qt = 31 - (blockIdx.x >> 5);
    const int q0 = qt << 6;
    const int tq = tid >> 4, tk = tid & 15;
    const int sr = tid >> 2, sc = (tid & 3) << 2;

    const float* qbase = Q + ((size_t)bh * S + q0) * DH;
    const float* kbase = K + (size_t)bh * S * DH;
    const float* vbase = V + (size_t)bh * S * DH;
#pragma unroll
    for (int it = 0; it < 4; ++it) {
        const int d0 = sc + (it << 4);
        const float4 v = *reinterpret_cast<const float4*>(&qbase[(size_t)sr * DH + d0]);
        Qs[d0 + 0][sr] = v.x; Qs[d0 + 1][sr] = v.y;
        Qs[d0 + 2][sr] = v.z; Qs[d0 + 3][sr] = v.w;
    }
    float C[4][4];
#pragma unroll
    for (int i = 0; i < 4; ++i)
#pragma unroll
        for (int j = 0; j < 4; ++j) C[i][j] = 0.f;
    float m[4] = {-1e30f, -1e30f, -1e30f, -1e30f};
    float l[4] = {0.f, 0.f, 0.f, 0.f};

    for (int kt = 0; kt <= qt; ++kt) {
        const int k0 = kt << 6;
        float4 kv[4], vv[4];
#pragma unroll
        for (int it = 0; it < 4; ++it) {
            const int d0 = sc + (it << 4);
            kv[it] = *reinterpret_cast<const float4*>(&kbase[(size_t)(k0 + sr) * DH + d0]);
            vv[it] = *reinterpret_cast<const float4*>(&vbase[(size_t)(k0 + sr) * DH + d0]);
        }
        __syncthreads();
#pragma unroll
        for (int it = 0; it < 4; ++it) {
            const int d0 = sc + (it << 4);
            Ks[d0 + 0][sr] = kv[it].x; Ks[d0 + 1][sr] = kv[it].y;
            Ks[d0 + 2][sr] = kv[it].z; Ks[d0 + 3][sr] = kv[it].w;
            *reinterpret_cast<float4*>(&Vs[sr][d0]) = vv[it];
        }
        __syncthreads();

        float s[4][4];
#pragma unroll
        for (int i = 0; i < 4; ++i)
#pragma unroll
            for (int j = 0; j < 4; ++j) s[i][j] = 0.f;
#pragma unroll 16
        for (int d = 0; d < 64; ++d) {
            const float4 qf4 = *reinterpret_cast<const float4*>(&Qs[d][tq << 2]);
            const float4 kf4 = *reinterpret_cast<const float4*>(&Ks[d][tk << 2]);
            const float qa[4] = {qf4.x, qf4.y, qf4.z, qf4.w};
            const float ka[4] = {kf4.x, kf4.y, kf4.z, kf4.w};
#pragma unroll
            for (int i = 0; i < 4; ++i)
#pragma unroll
                for (int j = 0; j < 4; ++j) s[i][j] += qa[i] * ka[j];
        }
        if (kt == qt) {
#pragma unroll
            for (int i = 0; i < 4; ++i) {
                const int qg = q0 + (tq << 2) + i;
#pragma unroll
                for (int j = 0; j < 4; ++j) {
                    const int kg = k0 + (tk << 2) + j;
                    s[i][j] = (kg <= qg) ? s[i][j] * 0.125f : -1e30f;
                }
            }
        } else {
#pragma unroll
            for (int i = 0; i < 4; ++i)
#pragma unroll
                for (int j = 0; j < 4; ++j) s[i][j] *= 0.125f;
        }
#pragma unroll
        for (int i = 0; i < 4; ++i) {
            float rm = fmaxf(fmaxf(s[i][0], s[i][1]), fmaxf(s[i][2], s[i][3]));
#pragma unroll
            for (int off = 1; off < 16; off <<= 1) rm = fmaxf(rm, __shfl_xor(rm, off));
            const float mn = fmaxf(m[i], rm);
            const float scale = __expf(m[i] - mn);
            float rs = 0.f;
#pragma unroll
            for (int j = 0; j < 4; ++j) {
                s[i][j] = __expf(s[i][j] - mn);
                rs += s[i][j];
            }
#pragma unroll
            for (int off = 1; off < 16; off <<= 1) rs += __shfl_xor(rs, off);
            l[i] = l[i] * scale + rs;
            m[i] = mn;
#pragma unroll
            for (int j = 0; j < 4; ++j) C[i][j] *= scale;
            *reinterpret_cast<float4*>(&Ps[(tq << 2) + i][tk << 2]) =
                make_float4(s[i][0], s[i][1], s[i][2], s[i][3]);
        }
        __syncthreads();
#pragma unroll 4
        for (int kc = 0; kc < 16; ++kc) {
            float4 pf[4], vf[4];
#pragma unroll
            for (int i = 0; i < 4; ++i)
                pf[i] = *reinterpret_cast<const float4*>(&Ps[(tq << 2) + i][kc << 2]);
#pragma unroll
            for (int j = 0; j < 4; ++j)
                vf[j] = *reinterpret_cast<const float4*>(&Vs[(kc << 2) + j][tk << 2]);
#pragma unroll
            for (int i = 0; i < 4; ++i) {
                const float pa[4] = {pf[i].x, pf[i].y, pf[i].z, pf[i].w};
#pragma unroll
                for (int j = 0; j < 4; ++j) {
                    C[i][j] += pa[0] * ((const float*)&vf[0])[j]
                             + pa[1] * ((const float*)&vf[1])[j]
                             + pa[2] * ((const float*)&vf[2])[j]
                             + pa[3] * ((const float*)&vf[3])[j];
                }
            }
        }
        __syncthreads();
    }
    const int b = bh >> 4, h = bh & (NH - 1);
#pragma unroll
    for (int i = 0; i < 4; ++i) {
        const int qg = q0 + (tq << 2) + i;
        const float inv = 1.f / l[i];
        float4 v;
        v.x = C[i][0] * inv; v.y = C[i][1] * inv;
        v.z = C[i][2] * inv; v.w = C[i][3] * inv;
        *reinterpret_cast<float4*>(&out[((size_t)(b * S + qg)) * DOUT + h * DH + (tk << 2)]) = v;
    }
}

// ===========================================================================
extern "C" void kernel_launch(void* const* d_in, const int* in_sizes, int n_in,
                              void* d_out, int out_size, void* d_ws, size_t ws_size,
                              hipStream_t stream) {
    const float* x  = (const float*)d_in[0];
    const float* Wq = (const float*)d_in[1];
    const float* Wk = (const float*)d_in[2];
    const float* Wv = (const float*)d_in[3];
    float* out = (float*)d_out;

    char* ws = (char*)d_ws;
    const size_t MB = 1024 * 1024;

    if (ws_size >= 68 * MB) {
        // layout: wT[0,12) | xsp 2-split[12,28) | Q[28,44) | K 2-split[44,60) |
        //         V^T bf16 1-split[60,68)
        ushort* wtsp = (ushort*)(ws);
        ushort* xsp  = (ushort*)(ws + 12 * MB);
        float*  qf   = (float*)(ws + 28 * MB);
        ushort* ksp  = (ushort*)(ws + 44 * MB);
        ushort* vtsp = (ushort*)(ws + 60 * MB);

        split_x<<<4096, 256, 0, stream>>>(x, xsp);
        split_wT3<<<dim3(16, 16, 3), 256, 0, stream>>>(Wq, Wk, Wv, wtsp);
        proj_fused5<<<512, 256, 0, stream>>>(xsp, wtsp, qf, ksp, vtsp);
        attn_mfma8<<<1024, 128, 0, stream>>>(qf, ksp, vtsp, out);
    } else {
        // fp32 fallback (48 MB)
        float* qws = (float*)d_ws;
        float* kws = qws + (size_t)M_TOT * DOUT;
        float* vws = kws + (size_t)M_TOT * DOUT;
        dim3 pgrid(M_TOT / 64, DOUT / 64);
        proj_f32<<<pgrid, 256, 0, stream>>>(x, Wq, qws);
        proj_f32<<<pgrid, 256, 0, stream>>>(x, Wk, kws);
        proj_f32<<<pgrid, 256, 0, stream>>>(x, Wv, vws);
        attn_f32<<<32 * 32, 256, 0, stream>>>(qws, kws, vws, out);
    }
}